// Round 13
// baseline (6346.385 us; speedup 1.0000x reference)
//
#include <hip/hip_runtime.h>
#include <math.h>

// ---------------- constants ----------------
#define B_    16
#define NT_   197
#define NS_   202
#define HEADS_ 12
#define DEPTH_ 12
#define NCLS_ 100
#define MROW_ (B_ * NT_)      // 3152
#define SROW_ (B_ * NS_)      // 3232
#define CROW_ (MROW_ + SROW_) // 6384
#define PAD_  128             // GEMM-A row padding (global_load_lds has no row guard)

typedef __attribute__((ext_vector_type(8))) short short8v;
typedef __attribute__((ext_vector_type(4))) float f32x4;

// f32 -> bf16 bits (RNE)
__device__ __forceinline__ short f2bf(float f){
    unsigned u = __builtin_bit_cast(unsigned, f);
    unsigned r = (u + 0x7FFFu + ((u >> 16) & 1u)) >> 16;
    return (short)r;
}
__device__ __forceinline__ unsigned pk2(float a, float b){
    return (unsigned)(unsigned short)f2bf(a) | (((unsigned)(unsigned short)f2bf(b)) << 16);
}
__device__ __forceinline__ float bf2f(unsigned short s){
    unsigned u = ((unsigned)s) << 16;
    return __builtin_bit_cast(float, u);
}
__device__ __forceinline__ float4 ld4bf(const short* p){
    uint2 u = *(const uint2*)p;
    float4 r;
    r.x = bf2f((unsigned short)(u.x & 0xffff));
    r.y = bf2f((unsigned short)(u.x >> 16));
    r.z = bf2f((unsigned short)(u.y & 0xffff));
    r.w = bf2f((unsigned short)(u.y >> 16));
    return r;
}
// async global->LDS, 16B per lane; lds base must be wave-uniform
__device__ __forceinline__ void gld16(const short* g, short* l){
    __builtin_amdgcn_global_load_lds(
        (const __attribute__((address_space(1))) unsigned*)g,
        (__attribute__((address_space(3))) unsigned*)l, 16, 0, 0);
}

// ============ double block reduce (256 thr) — routing/head only ============
__device__ __forceinline__ double block_reduce_sum_d(double s, double* red, int lane, int wid){
#pragma unroll
    for (int off = 32; off; off >>= 1) s += __shfl_xor(s, off);
    if (lane == 0) red[wid] = s;
    __syncthreads();
    double S = red[0] + red[1] + red[2] + red[3];
    __syncthreads();
    return S;
}

// ============ weight convert f32 -> bf16 ============
__global__ void convert_w_k(const float* __restrict__ in, short* __restrict__ out, long n){
    long i = ((long)blockIdx.x * 256 + threadIdx.x) * 8;
    long stride = (long)gridDim.x * 256 * 8;
    for (; i < n; i += stride){
        float4 a = *(const float4*)(in + i);
        float4 b = *(const float4*)(in + i + 4);
        uint4 o4;
        o4.x = pk2(a.x, a.y); o4.y = pk2(a.z, a.w);
        o4.z = pk2(b.x, b.y); o4.w = pk2(b.z, b.w);
        *(uint4*)(out + i) = o4;
    }
}

// ============ bf16 MFMA GEMM, BK=32, global_load_lds staging (unchanged) ============
template<int EPI, int WB>
__global__ __launch_bounds__(256) void gemm_bf16(
    const short* __restrict__ A, const void* __restrict__ Wv,
    const float* __restrict__ bias, const float* __restrict__ Res,
    float* __restrict__ Cf, short* __restrict__ Cb, int M, int K, int N)
{
    __shared__ short As[128 * 32];
    __shared__ short Bs[128 * 32];
    const int t = threadIdx.x;
    const int lane = t & 63, wid = t >> 6;
    const int wr = wid >> 1, wc = wid & 1;
    const long row0 = (long)blockIdx.y * 128;
    const long col0 = (long)blockIdx.x * 128;

    f32x4 acc[4][4];
#pragma unroll
    for (int i = 0; i < 4; i++)
#pragma unroll
        for (int j = 0; j < 4; j++) acc[i][j] = (f32x4){0.f, 0.f, 0.f, 0.f};

    const int l15 = lane & 15, lkg = lane >> 4;
    const int lrow = lane >> 2;
    const int lcol = (lane & 3) * 8;

    for (int k0 = 0; k0 < K; k0 += 32){
#pragma unroll
        for (int i = 0; i < 2; i++){
            int rb = wid * 32 + i * 16;
            gld16(A + (row0 + rb + lrow) * K + k0 + lcol, &As[rb * 32]);
        }
        if (WB == 1){
            const short* Wb = (const short*)Wv;
#pragma unroll
            for (int i = 0; i < 2; i++){
                int rb = wid * 32 + i * 16;
                gld16(Wb + (col0 + rb + lrow) * K + k0 + lcol, &Bs[rb * 32]);
            }
        } else {
            const float* Wf = (const float*)Wv;
            const int bn = t >> 1, bh = t & 1;
            const float* Wp = Wf + (col0 + bn) * K + k0 + bh * 16;
            unsigned rr[8];
#pragma unroll
            for (int g = 0; g < 8; g++){
                float2 f = *(const float2*)(Wp + g * 2);
                rr[g] = pk2(f.x, f.y);
            }
            uint4 lo = {rr[0], rr[1], rr[2], rr[3]};
            uint4 hi = {rr[4], rr[5], rr[6], rr[7]};
            *(uint4*)(&Bs[bn * 32 + bh * 16])     = lo;
            *(uint4*)(&Bs[bn * 32 + bh * 16 + 8]) = hi;
        }
        __syncthreads();

        short8v a[4], b[4];
#pragma unroll
        for (int i = 0; i < 4; i++)
            a[i] = *(const short8v*)(&As[(wr * 64 + i * 16 + l15) * 32 + lkg * 8]);
#pragma unroll
        for (int j = 0; j < 4; j++)
            b[j] = *(const short8v*)(&Bs[(wc * 64 + j * 16 + l15) * 32 + lkg * 8]);
#pragma unroll
        for (int i = 0; i < 4; i++)
#pragma unroll
            for (int j = 0; j < 4; j++)
                acc[i][j] = __builtin_amdgcn_mfma_f32_16x16x32_bf16(a[i], b[j], acc[i][j], 0, 0, 0);
        __syncthreads();
    }

#pragma unroll
    for (int i = 0; i < 4; i++){
#pragma unroll
        for (int q = 0; q < 4; q++){
            long gr = row0 + wr * 64 + i * 16 + lkg * 4 + q;
            if (gr >= M) continue;
#pragma unroll
            for (int j = 0; j < 4; j++){
                long gc = col0 + wc * 64 + j * 16 + l15;
                float v = acc[i][j][q] + bias[gc];
                if (EPI == 1){
                    v = 0.5f * v * (1.f + erff(v * 0.70710678118654752f));
                    Cb[gr * N + gc] = f2bf(v);
                } else if (EPI == 2){
                    Cf[gr * N + gc] = v + Res[gr * N + gc];
                } else if (EPI == 3){
                    Cb[gr * N + gc] = f2bf(v);
                } else {
                    Cf[gr * N + gc] = v;
                }
            }
        }
    }
}

// ============ LayerNorm: wave-per-row (unchanged) ============
__global__ __launch_bounds__(256) void ln_k(const float* __restrict__ x,
    const float* __restrict__ w, const float* __restrict__ b,
    short* __restrict__ y, int M)
{
    const int lane = threadIdx.x & 63, wv = threadIdx.x >> 6;
    const int row = blockIdx.x * 4 + wv;
    if (row >= M) return;
    const float* xr = x + (long)row * 768;
    float v[12];
    float s = 0.f;
#pragma unroll
    for (int j = 0; j < 12; j++){ v[j] = xr[lane + j * 64]; s += v[j]; }
#pragma unroll
    for (int off = 32; off; off >>= 1) s += __shfl_xor(s, off);
    float m = s * (1.f / 768.f);
    float q = 0.f;
#pragma unroll
    for (int j = 0; j < 12; j++){ v[j] -= m; q += v[j] * v[j]; }
#pragma unroll
    for (int off = 32; off; off >>= 1) q += __shfl_xor(q, off);
    float rs = 1.f / sqrtf(q * (1.f / 768.f) + 1e-6f);
    short* yr = y + (long)row * 768;
#pragma unroll
    for (int j = 0; j < 12; j++)
        yr[lane + j * 64] = f2bf(v[j] * rs * w[lane + j * 64] + b[lane + j * 64]);
}

// ============ std MHA via MFMA v2: swapped QK^T, register P (no Ps LDS) ============
// S^T = mfma(K_frag, Q_frag): lane holds 52 scores for ONE query (q = lane&15).
// Softmax: per-lane + shfl_xor(16,32). P->PV A-frags via 8 shfl per k-chunk.
// LDS: Ks 30KB + Vs 29.7KB = 59.7KB -> 2 blocks/CU.
__global__ __launch_bounds__(512) void attn_mfma(
    const short* __restrict__ qkv0, short* __restrict__ o0, int N0,
    const short* __restrict__ qkv1, short* __restrict__ o1, int N1)
{
    __shared__ short Ks[208 * 72];
    __shared__ short Vs[64 * 232];
    const int bh = blockIdx.x;
    const int b = bh / HEADS_, h = bh % HEADS_;
    const int seg = blockIdx.y;
    const short* qkv = seg ? qkv1 : qkv0;
    short* o = seg ? o1 : o0;
    const int Ntok = seg ? N1 : N0;
    const int t = threadIdx.x, lane = t & 63, wid = t >> 6;
    const long rb = (long)b * Ntok;

    // ---- stage K rows + V transposed (bf16 input, straight copies) ----
    {
        const int r = t >> 2, c = (t & 3) * 16;
#pragma unroll
        for (int pass = 0; pass < 2; pass++){
            int m = r + pass * 128;
            if (m < 208){
                if (m < Ntok){
                    const short* kr = qkv + (rb + m) * 2304 + 768  + h * 64 + c;
                    const short* vr = qkv + (rb + m) * 2304 + 1536 + h * 64 + c;
                    *(uint4*)(&Ks[m * 72 + c])     = *(const uint4*)(kr);
                    *(uint4*)(&Ks[m * 72 + c + 8]) = *(const uint4*)(kr + 8);
#pragma unroll
                    for (int j = 0; j < 16; j++)
                        Vs[(c + j) * 232 + m] = vr[j];
                } else {
#pragma unroll
                    for (int j = 0; j < 16; j += 2)
                        *(unsigned*)(&Ks[m * 72 + c + j]) = 0u;
#pragma unroll
                    for (int j = 0; j < 16; j++)
                        Vs[(c + j) * 232 + m] = 0;
                }
            }
        }
        for (int i = t; i < 64 * 16; i += 512){
            int d = i >> 4, m = 208 + (i & 15);
            Vs[d * 232 + m] = 0;
        }
    }
    __syncthreads();

    const int l15 = lane & 15, lkg = lane >> 4;
    const int srcA = l15 + 16 * (2 * (lkg & 1));   // P-redistribution source lanes
    const int srcB = srcA + 16;
    const int tsel = lkg >> 1;                     // which tile of the pair this lane needs

    for (int s = wid; s < 13; s += 8){
        const int q0 = s * 16;
        // ---- Q frags (B-operand): lane l15 = query row ----
        short8v qf0, qf1;
        {
            int qrow = q0 + l15;
            if (qrow < Ntok){
                const short* qp = qkv + (rb + qrow) * 2304 + h * 64;
                qf0 = *(const short8v*)(qp + lkg * 8);
                qf1 = *(const short8v*)(qp + 32 + lkg * 8);
            } else {
                uint4 z = {0u,0u,0u,0u};
                qf0 = __builtin_bit_cast(short8v, z);
                qf1 = __builtin_bit_cast(short8v, z);
            }
        }
        // ---- swapped QK^T: sacc[j][reg] = S[key=j*16+lkg*4+reg][q=q0+l15] ----
        f32x4 sacc[13];
#pragma unroll
        for (int j = 0; j < 13; j++){
            short8v k0 = *(const short8v*)(&Ks[(j * 16 + l15) * 72 + lkg * 8]);
            short8v k1 = *(const short8v*)(&Ks[(j * 16 + l15) * 72 + 32 + lkg * 8]);
            f32x4 z = {0.f, 0.f, 0.f, 0.f};
            z = __builtin_amdgcn_mfma_f32_16x16x32_bf16(k0, qf0, z, 0, 0, 0);
            z = __builtin_amdgcn_mfma_f32_16x16x32_bf16(k1, qf1, z, 0, 0, 0);
            sacc[j][0] = z[0] * 0.125f; sacc[j][1] = z[1] * 0.125f;
            sacc[j][2] = z[2] * 0.125f; sacc[j][3] = z[3] * 0.125f;
        }
        // ---- mask invalid KEYS (key = j*16 + lkg*4 + reg) ----
#pragma unroll
        for (int j = 0; j < 13; j++){
            int kb = j * 16 + lkg * 4;
#pragma unroll
            for (int rr = 0; rr < 4; rr++)
                if (kb + rr >= Ntok) sacc[j][rr] = -1e30f;
        }
        // ---- softmax for query l15: per-lane over 52 + cross-lkg shfl ----
        float mx = -1e30f;
#pragma unroll
        for (int j = 0; j < 13; j++)
#pragma unroll
            for (int rr = 0; rr < 4; rr++) mx = fmaxf(mx, sacc[j][rr]);
        mx = fmaxf(mx, __shfl_xor(mx, 16));
        mx = fmaxf(mx, __shfl_xor(mx, 32));
        float sum = 0.f;
#pragma unroll
        for (int j = 0; j < 13; j++)
#pragma unroll
            for (int rr = 0; rr < 4; rr++){
                float e = expf(sacc[j][rr] - mx);
                sacc[j][rr] = e; sum += e;
            }
        sum += __shfl_xor(sum, 16);
        sum += __shfl_xor(sum, 32);
        float inv = 1.f / sum;
        // ---- pack P to bf16 pairs per tile (keys lkg*4+{0,1} / {2,3}) ----
        unsigned ulo[14], uhi[14];
#pragma unroll
        for (int j = 0; j < 13; j++){
            ulo[j] = pk2(sacc[j][0] * inv, sacc[j][1] * inv);
            uhi[j] = pk2(sacc[j][2] * inv, sacc[j][3] * inv);
        }
        ulo[13] = 0u; uhi[13] = 0u;   // nonexistent tile 13 (keys 208..223) = 0
        // ---- redistribute P into PV A-frags: keys kc*32+lkg*8..+8 for query l15 ----
        short8v pa[7];
#pragma unroll
        for (int kc = 0; kc < 7; kc++){
            unsigned a0t = __shfl(ulo[2*kc],     srcA), a1t = __shfl(uhi[2*kc],     srcA);
            unsigned a2t = __shfl(ulo[2*kc],     srcB), a3t = __shfl(uhi[2*kc],     srcB);
            unsigned b0t = __shfl(ulo[2*kc + 1], srcA), b1t = __shfl(uhi[2*kc + 1], srcA);
            unsigned b2t = __shfl(ulo[2*kc + 1], srcB), b3t = __shfl(uhi[2*kc + 1], srcB);
            uint4 w;
            w.x = tsel ? b0t : a0t;
            w.y = tsel ? b1t : a1t;
            w.z = tsel ? b2t : a2t;
            w.w = tsel ? b3t : a3t;
            pa[kc] = __builtin_bit_cast(short8v, w);
        }
        // ---- PV: C[q = lkg*4+rr][d = dj*16+l15] ----
#pragma unroll
        for (int dj = 0; dj < 4; dj++){
            f32x4 oacc = {0.f, 0.f, 0.f, 0.f};
#pragma unroll
            for (int kc = 0; kc < 7; kc++){
                short8v vb = *(const short8v*)(&Vs[(dj * 16 + l15) * 232 + kc * 32 + lkg * 8]);
                oacc = __builtin_amdgcn_mfma_f32_16x16x32_bf16(pa[kc], vb, oacc, 0, 0, 0);
            }
#pragma unroll
            for (int rr = 0; rr < 4; rr++){
                int q = q0 + lkg * 4 + rr;
                if (q < Ntok)
                    o[(rb + q) * 768 + h * 64 + dj * 16 + l15] = f2bf(oacc[rr]);
            }
        }
    }
}

// ============ deep attention — bf16 qkv input, f32 math (unchanged) ============
__global__ __launch_bounds__(256) void attn_deep_v2(
    const short* __restrict__ qkv, const float* __restrict__ prompts,
    const int* __restrict__ selm, short* __restrict__ o, int li)
{
    __shared__ float q[768];
    __shared__ float sc[256];
    __shared__ float red[256];
    const int b = blockIdx.x, n = blockIdx.y, t = threadIdx.x;
    const int lane = t & 63, w = t >> 6;
    const short* qr = qkv + (long)(b * NT_ + n) * 2304;
    q[t] = bf2f((unsigned short)qr[t]);
    q[t + 256] = bf2f((unsigned short)qr[t + 256]);
    q[t + 512] = bf2f((unsigned short)qr[t + 512]);
    __syncthreads();

    const float4 q0 = *(const float4*)(&q[lane * 4]);
    const float4 q1 = *(const float4*)(&q[256 + lane * 4]);
    const float4 q2 = *(const float4*)(&q[512 + lane * 4]);

    const float* kp = prompts + ((long)selm[b] * 6 + 2 * li) * 5 * 768;
    const float* vp = kp + 5 * 768;

    for (int m = w; m < 202; m += 4){
        float4 k0, k1, k2;
        if (m < 5){
            const float* kr = kp + (long)m * 768;
            k0 = *(const float4*)(kr + lane * 4);
            k1 = *(const float4*)(kr + 256 + lane * 4);
            k2 = *(const float4*)(kr + 512 + lane * 4);
        } else {
            const short* kr = qkv + (long)(b * NT_ + (m - 5)) * 2304 + 768;
            k0 = ld4bf(kr + lane * 4);
            k1 = ld4bf(kr + 256 + lane * 4);
            k2 = ld4bf(kr + 512 + lane * 4);
        }
        float a = q0.x*k0.x + q0.y*k0.y + q0.z*k0.z + q0.w*k0.w
                + q1.x*k1.x + q1.y*k1.y + q1.z*k1.z + q1.w*k1.w
                + q2.x*k2.x + q2.y*k2.y + q2.z*k2.z + q2.w*k2.w;
#pragma unroll
        for (int off = 32; off; off >>= 1) a += __shfl_xor(a, off);
        if (lane == 0) sc[m] = a * 0.125f;
    }
    __syncthreads();

    float s = (t < 202) ? sc[t] : -1e30f;
    red[t] = s; __syncthreads();
    for (int wd = 128; wd; wd >>= 1){ if (t < wd) red[t] = fmaxf(red[t], red[t+wd]); __syncthreads(); }
    float mx = red[0]; __syncthreads();
    float e = (t < 202) ? expf(s - mx) : 0.f;
    red[t] = e; __syncthreads();
    for (int wd = 128; wd; wd >>= 1){ if (t < wd) red[t] += red[t+wd]; __syncthreads(); }
    float inv = 1.f / red[0];
    __syncthreads();
    sc[t] = e * inv;
    __syncthreads();

    float a0 = 0.f, a1 = 0.f, a2 = 0.f;
    for (int m = 0; m < 5; m++){
        const float* vr = vp + (long)m * 768;
        float pm = sc[m];
        a0 += pm * vr[t]; a1 += pm * vr[t + 256]; a2 += pm * vr[t + 512];
    }
    for (int m = 5; m < 202; m++){
        const short* vr = qkv + (long)(b * NT_ + (m - 5)) * 2304 + 1536;
        float pm = sc[m];
        a0 += pm * bf2f((unsigned short)vr[t]);
        a1 += pm * bf2f((unsigned short)vr[t + 256]);
        a2 += pm * bf2f((unsigned short)vr[t + 512]);
    }
    short* ob = o + (long)b * NT_ * 768 + n;
    ob[(long)t * 197]         = f2bf(a0);
    ob[(long)(t + 256) * 197] = f2bf(a1);
    ob[(long)(t + 512) * 197] = f2bf(a2);
}

// ============ patch unfold (f32 -> bf16) ============
__global__ void unfold_k(const float* __restrict__ in, short* __restrict__ out){
    long i = (long)blockIdx.x * 256 + threadIdx.x;
    long total = (long)B_ * 196 * 768;
    if (i >= total) return;
    int f = (int)(i % 768); long rw = i / 768;
    int t = (int)(rw % 196); int b = (int)(rw / 196);
    int gy = t / 14, gx = t % 14;
    int c = f >> 8, rem = f & 255, py = rem >> 4, px = rem & 15;
    out[i] = f2bf(in[(((long)(b * 3 + c) * 224) + gy * 16 + py) * 224 + gx * 16 + px]);
}

// ============ assemble x0 = [cls+pos ; patches+pos] (f32) ============
__global__ void assemble_k(const float* __restrict__ pe, const float* __restrict__ cls,
    const float* __restrict__ pos, float* __restrict__ x0){
    long i = (long)blockIdx.x * 256 + threadIdx.x;
    long total = (long)B_ * NT_ * 768;
    if (i >= total) return;
    int d = (int)(i % 768); long rw = i / 768;
    int n = (int)(rw % NT_); int b = (int)(rw / NT_);
    float v;
    if (n == 0) v = cls[d] + pos[d];
    else        v = pe[((long)b * 196 + (n - 1)) * 768 + d] + pos[(long)n * 768 + d];
    x0[i] = v;
}

__global__ void copy_f(const float* __restrict__ a, float* __restrict__ b, long total){
    long i = (long)blockIdx.x * 256 + threadIdx.x;
    if (i < total) b[i] = a[i];
}

// ============ build sub-branch rows ============
__global__ void build_sub_k(const float* __restrict__ x0, const float* __restrict__ subp,
    const float* __restrict__ pos, float* __restrict__ xSub){
    long i = (long)blockIdx.x * 256 + threadIdx.x;
    long total = (long)B_ * NS_ * 768;
    if (i >= total) return;
    int d = (int)(i % 768); long rw = i / 768;
    int n = (int)(rw % NS_); int b = (int)(rw / NS_);
    float v;
    if (n == 0)      v = x0[((long)b * NT_) * 768 + d];
    else if (n <= 5) v = subp[(n - 1) * 768 + d] + pos[d];
    else             v = x0[((long)b * NT_ + (n - 5)) * 768 + d];
    xSub[i] = v;
}

// ============ routing (f64 internals) ============
__global__ __launch_bounds__(256) void select_k(
    const float* __restrict__ xA, const float* __restrict__ norm_w,
    const float* __restrict__ norm_b, const float* __restrict__ main_key,
    const float* __restrict__ sub_key, const int* __restrict__ task_id_p,
    int* __restrict__ selm, int* __restrict__ flag)
{
    __shared__ double red[4];
    int b = blockIdx.x, t = threadIdx.x, lane = t & 63, wid = t >> 6;
    const float* xr = xA + (long)b * NT_ * 768;
    double v0 = xr[t], v1 = xr[t + 256], v2 = xr[t + 512];
    double S = block_reduce_sum_d(v0 + v1 + v2, red, lane, wid);
    double m = S * (1.0 / 768.0);
    double d0 = v0 - m, d1 = v1 - m, d2 = v2 - m;
    double Q = block_reduce_sum_d(d0*d0 + d1*d1 + d2*d2, red, lane, wid);
    double rs = 1.0 / sqrt(Q * (1.0 / 768.0) + 1e-6);
    double q0 = d0 * rs * (double)norm_w[t]       + (double)norm_b[t];
    double q1 = d1 * rs * (double)norm_w[t + 256] + (double)norm_b[t + 256];
    double q2 = d2 * rs * (double)norm_w[t + 512] + (double)norm_b[t + 512];
    double qn = block_reduce_sum_d(q0*q0 + q1*q1 + q2*q2, red, lane, wid);
    double qinv = 1.0 / sqrt(fmax(qn, 1e-12));

    int tk = *task_id_p;
    int ncand = tk + 2;
    double best = -1e300; int bsel = 0;
    for (int c = 0; c < ncand; c++){
        const float* cr = (c <= tk) ? (main_key + (long)c * 768) : sub_key;
        double c0 = cr[t], c1 = cr[t + 256], c2 = cr[t + 512];
        double dotq = block_reduce_sum_d(q0*c0 + q1*c1 + q2*c2, red, lane, wid);
        double nc   = block_reduce_sum_d(c0*c0 + c1*c1 + c2*c2, red, lane, wid);
        double sim = dotq * qinv * (1.0 / sqrt(fmax(nc, 1e-12)));
        if (sim > best){ best = sim; bsel = c; }
    }
    if (t == 0){
        int isMain = (bsel <= tk) ? 1 : 0;
        selm[b] = isMain ? bsel : 0;
        flag[b] = isMain;
    }
}

// ============ final head (f64 internals, f32 out) ============
__global__ __launch_bounds__(256) void head_k(
    const float* __restrict__ xM, const float* __restrict__ xSub,
    const float* __restrict__ norm_w, const float* __restrict__ norm_b,
    const float* __restrict__ fc_w, const float* __restrict__ fc_b,
    const int* __restrict__ flag, float* __restrict__ out)
{
    __shared__ double vec[768];
    __shared__ double red[4];
    int b = blockIdx.x, t = threadIdx.x, lane = t & 63, wid = t >> 6;
    int isMain = flag[b];
    double a0 = 0.0, a1 = 0.0, a2 = 0.0;
    int nrows = isMain ? 1 : 5;
    for (int rI = 0; rI < nrows; rI++){
        const float* xr = isMain ? (xM + (long)b * NT_ * 768)
                                 : (xSub + ((long)b * NS_ + 1 + rI) * 768);
        double v0 = xr[t], v1 = xr[t + 256], v2 = xr[t + 512];
        double S = block_reduce_sum_d(v0 + v1 + v2, red, lane, wid);
        double m = S * (1.0 / 768.0);
        double d0 = v0 - m, d1 = v1 - m, d2 = v2 - m;
        double Q = block_reduce_sum_d(d0*d0 + d1*d1 + d2*d2, red, lane, wid);
        double rs = 1.0 / sqrt(Q * (1.0 / 768.0) + 1e-6);
        a0 += d0 * rs * (double)norm_w[t]       + (double)norm_b[t];
        a1 += d1 * rs * (double)norm_w[t + 256] + (double)norm_b[t + 256];
        a2 += d2 * rs * (double)norm_w[t + 512] + (double)norm_b[t + 512];
    }
    double scl = isMain ? 1.0 : 0.2;
    vec[t] = a0 * scl; vec[t + 256] = a1 * scl; vec[t + 512] = a2 * scl;
    __syncthreads();
    if (t < NCLS_){
        const float* wr = fc_w + (long)t * 768;
        double acc = (double)fc_b[t];
#pragma unroll 8
        for (int j = 0; j < 768; j++) acc += vec[j] * (double)wr[j];
        out[b * NCLS_ + t] = (float)acc;
    }
}

// ================= host-side =================
struct Params {
    const float *qkv_w, *qkv_b, *proj_w, *proj_b;
    const float *ln1_w, *ln1_b, *ln2_w, *ln2_b;
    const float *fc1_w, *fc1_b, *fc2_w, *fc2_b;
    const float *prompts; const int* selm;
    short *lnb, *attb, *hidb;
    short *qkvb;
    const short *qkv_wc, *proj_wc, *fc1_wc, *fc2_wc;
    bool cache;
};

template<int EPI>
static void launch_gemm(hipStream_t st, const short* A, const float* Wf, const short* Wc,
                        bool cache, const float* bias, const float* Res,
                        float* Cf, short* Cb, int M, int K, int N)
{
    dim3 g(N / 128, (M + 127) / 128);
    if (cache)
        gemm_bf16<EPI, 1><<<g, 256, 0, st>>>(A, (const void*)Wc, bias, Res, Cf, Cb, M, K, N);
    else
        gemm_bf16<EPI, 0><<<g, 256, 0, st>>>(A, (const void*)Wf, bias, Res, Cf, Cb, M, K, N);
}

// mode 0: concat (std attn both segments)  mode 1: main std  mode 2: main deep
static void run_layer(hipStream_t st, float* x, int M, int layer, int mode, int li,
                      const Params& P)
{
    int lnGrid = (M + 3) / 4;
    ln_k<<<lnGrid, 256, 0, st>>>(x, P.ln1_w + layer * 768, P.ln1_b + layer * 768, P.lnb, M);
    launch_gemm<3>(st, P.lnb, P.qkv_w + (long)layer * 2304 * 768,
        P.qkv_wc + (P.cache ? (long)layer * 2304 * 768 : 0), P.cache,
        P.qkv_b + layer * 2304, nullptr, nullptr, P.qkvb, M, 768, 2304);
    if (mode == 0){
        attn_mfma<<<dim3(B_ * HEADS_, 2), 512, 0, st>>>(
            P.qkvb, P.attb, NT_,
            P.qkvb + (long)MROW_ * 2304, P.attb + (long)MROW_ * 768, NS_);
    } else if (mode == 1){
        attn_mfma<<<dim3(B_ * HEADS_, 1), 512, 0, st>>>(
            P.qkvb, P.attb, NT_, P.qkvb, P.attb, NT_);
    } else {
        attn_deep_v2<<<dim3(B_, NT_), 256, 0, st>>>(P.qkvb, P.prompts, P.selm, P.attb, li);
    }
    launch_gemm<2>(st, P.attb, P.proj_w + (long)layer * 768 * 768,
        P.proj_wc + (P.cache ? (long)layer * 768 * 768 : 0), P.cache,
        P.proj_b + layer * 768, x, x, nullptr, M, 768, 768);
    ln_k<<<lnGrid, 256, 0, st>>>(x, P.ln2_w + layer * 768, P.ln2_b + layer * 768, P.lnb, M);
    launch_gemm<1>(st, P.lnb, P.fc1_w + (long)layer * 3072 * 768,
        P.fc1_wc + (P.cache ? (long)layer * 3072 * 768 : 0), P.cache,
        P.fc1_b + layer * 3072, nullptr, nullptr, P.hidb, M, 768, 3072);
    launch_gemm<2>(st, P.hidb, P.fc2_w + (long)layer * 768 * 3072,
        P.fc2_wc + (P.cache ? (long)layer * 768 * 3072 : 0), P.cache,
        P.fc2_b + layer * 768, x, x, nullptr, M, 3072, 768);
}

extern "C" void kernel_launch(void* const* d_in, const int* in_sizes, int n_in,
                              void* d_out, int out_size, void* d_ws, size_t ws_size,
                              hipStream_t stream)
{
    (void)in_sizes; (void)n_in; (void)out_size;
    const float* inputs   = (const float*)d_in[0];
    const int*   task_id  = (const int*)  d_in[1];
    const float* patch_w  = (const float*)d_in[2];
    const float* patch_b  = (const float*)d_in[3];
    const float* cls_tok  = (const float*)d_in[4];
    const float* pos      = (const float*)d_in[5];
    const float* qkv_w    = (const float*)d_in[6];
    const float* qkv_b    = (const float*)d_in[7];
    const float* proj_w   = (const float*)d_in[8];
    const float* proj_b   = (const float*)d_in[9];
    const float* ln1_w    = (const float*)d_in[10];
    const float* ln1_b    = (const float*)d_in[11];
    const float* ln2_w    = (const float*)d_in[12];
    const float* ln2_b    = (const float*)d_in[13];
    const float* fc1_w    = (const float*)d_in[14];
    const float* fc1_b    = (const float*)d_in[15];
    const float* fc2_w    = (const float*)d_in[16];
    const float* fc2_b    = (const float*)d_in[17];
    const float* norm_w   = (const float*)d_in[18];
    const float* norm_b   = (const float*)d_in[19];
    const float* fc_w     = (const float*)d_in[20];
    const float* fc_b     = (const float*)d_in[21];
    const float* main_key = (const float*)d_in[22];
    const float* sub_key  = (const float*)d_in[23];
    const float* m_prompts= (const float*)d_in[24];
    const float* s_prompt = (const float*)d_in[25];
    float* out = (float*)d_out;

    char* wsb = (char*)d_ws;
    size_t off = 0;
    auto allocB = [&](size_t bytes) -> void* {
        void* p = (void*)(wsb + off);
        off += (bytes + 255) & ~(size_t)255;
        return p;
    };
    float* x0   = (float*)allocB((size_t)MROW_ * 768 * 4);
    float* xC   = (float*)allocB((size_t)CROW_ * 768 * 4);
    float* xM   = (float*)allocB((size_t)MROW_ * 768 * 4);
    short* lnb  = (short*)allocB((size_t)(CROW_ + PAD_) * 768 * 2);
    short* attb = (short*)allocB((size_t)(CROW_ + PAD_) * 768 * 2);
    short* qkvb = (short*)allocB((size_t)(CROW_ + PAD_) * 2304 * 2);
    short* hidb = (short*)allocB((size_t)(CROW_ + PAD_) * 3072 * 2);
    float* peo  = (float*)allocB((size_t)3136 * 768 * 4);
    int*   selm = (int*)allocB(64);
    int*   flag = (int*)allocB(64);

    const size_t nQkv = (size_t)DEPTH_ * 2304 * 768;
    const size_t nProj = (size_t)DEPTH_ * 768 * 768;
    const size_t nFc1 = (size_t)DEPTH_ * 3072 * 768;
    const size_t nFc2 = (size_t)DEPTH_ * 768 * 3072;
    const size_t nPatch = (size_t)768 * 768;
    size_t cacheBytes = (nQkv + nProj + nFc1 + nFc2 + nPatch) * 2 + 5 * 256;
    bool cache = (ws_size >= off + cacheBytes + (1u << 20));
    short *qkv_wc = nullptr, *proj_wc = nullptr, *fc1_wc = nullptr, *fc2_wc = nullptr, *patch_wc = nullptr;
    if (cache){
        qkv_wc  = (short*)allocB(nQkv * 2);
        proj_wc = (short*)allocB(nProj * 2);
        fc1_wc  = (short*)allocB(nFc1 * 2);
        fc2_wc  = (short*)allocB(nFc2 * 2);
        patch_wc= (short*)allocB(nPatch * 2);
        convert_w_k<<<2048, 256, 0, stream>>>(qkv_w,  qkv_wc,  (long)nQkv);
        convert_w_k<<<1024, 256, 0, stream>>>(proj_w, proj_wc, (long)nProj);
        convert_w_k<<<2048, 256, 0, stream>>>(fc1_w,  fc1_wc,  (long)nFc1);
        convert_w_k<<<2048, 256, 0, stream>>>(fc2_w,  fc2_wc,  (long)nFc2);
        convert_w_k<<<256,  256, 0, stream>>>(patch_w, patch_wc, (long)nPatch);
    }

    Params P;
    P.qkv_w = qkv_w; P.qkv_b = qkv_b; P.proj_w = proj_w; P.proj_b = proj_b;
    P.ln1_w = ln1_w; P.ln1_b = ln1_b; P.ln2_w = ln2_w; P.ln2_b = ln2_b;
    P.fc1_w = fc1_w; P.fc1_b = fc1_b; P.fc2_w = fc2_w; P.fc2_b = fc2_b;
    P.prompts = m_prompts; P.selm = selm;
    P.lnb = lnb; P.attb = attb; P.hidb = hidb; P.qkvb = qkvb;
    P.qkv_wc = qkv_wc; P.proj_wc = proj_wc; P.fc1_wc = fc1_wc; P.fc2_wc = fc2_wc;
    P.cache = cache;

    const long XN = (long)MROW_ * 768;

    // -------- patch embed --------
    {
        long tot = (long)B_ * 196 * 768;
        short* un = hidb;
        unfold_k<<<(int)((tot + 255) / 256), 256, 0, stream>>>(inputs, un);
        launch_gemm<0>(stream, un, patch_w, patch_wc, cache, patch_b, nullptr,
                       peo, nullptr, 3136, 768, 768);
        assemble_k<<<(int)((XN + 255) / 256), 256, 0, stream>>>(peo, cls_tok, pos, x0);
        copy_f<<<(int)((XN + 255) / 256), 256, 0, stream>>>(x0, xC, XN);
        long st = (long)SROW_ * 768;
        build_sub_k<<<(int)((st + 255) / 256), 256, 0, stream>>>(x0, s_prompt, pos,
                                                                 xC + (long)MROW_ * 768);
    }

    // -------- concatenated pass A + sub branch --------
    for (int i = 0; i < DEPTH_; i++){
        run_layer(stream, xC, CROW_, i, 0, 0, P);
        if (i == 1)
            copy_f<<<(int)((XN + 255) / 256), 256, 0, stream>>>(xC, xM, XN);
    }

    // -------- routing --------
    select_k<<<16, 256, 0, stream>>>(xC, norm_w, norm_b, main_key, sub_key,
                                     task_id, selm, flag);

    // -------- main branch layers 2..11 (deep prompts at 2,3,4) --------
    for (int i = 2; i < DEPTH_; i++){
        int mode = (i >= 2 && i <= 4) ? 2 : 1;
        run_layer(stream, xM, MROW_, i, mode, i - 2, P);
    }

    // -------- heads + per-sample select --------
    head_k<<<16, 256, 0, stream>>>(xM, xC + (long)MROW_ * 768, norm_w, norm_b,
                                   fc_w, fc_b, flag, out);
}

// Round 14
// 5935.769 us; speedup vs baseline: 1.0692x; 1.0692x over previous
//
#include <hip/hip_runtime.h>
#include <math.h>

// ---------------- constants ----------------
#define B_    16
#define NT_   197
#define NS_   202
#define HEADS_ 12
#define DEPTH_ 12
#define NCLS_ 100
#define MROW_ (B_ * NT_)      // 3152
#define SROW_ (B_ * NS_)      // 3232
#define CROW_ (MROW_ + SROW_) // 6384
#define PAD_  128             // GEMM-A row padding (global_load_lds has no row guard)

typedef __attribute__((ext_vector_type(8))) short short8v;
typedef __attribute__((ext_vector_type(4))) float f32x4;

// f32 -> bf16 bits (RNE)
__device__ __forceinline__ short f2bf(float f){
    unsigned u = __builtin_bit_cast(unsigned, f);
    unsigned r = (u + 0x7FFFu + ((u >> 16) & 1u)) >> 16;
    return (short)r;
}
__device__ __forceinline__ unsigned pk2(float a, float b){
    return (unsigned)(unsigned short)f2bf(a) | (((unsigned)(unsigned short)f2bf(b)) << 16);
}
__device__ __forceinline__ float bf2f(unsigned short s){
    unsigned u = ((unsigned)s) << 16;
    return __builtin_bit_cast(float, u);
}
__device__ __forceinline__ float4 ld4bf(const short* p){
    uint2 u = *(const uint2*)p;
    float4 r;
    r.x = bf2f((unsigned short)(u.x & 0xffff));
    r.y = bf2f((unsigned short)(u.x >> 16));
    r.z = bf2f((unsigned short)(u.y & 0xffff));
    r.w = bf2f((unsigned short)(u.y >> 16));
    return r;
}
// async global->LDS, 16B per lane; lds base must be wave-uniform
__device__ __forceinline__ void gld16(const short* g, short* l){
    __builtin_amdgcn_global_load_lds(
        (const __attribute__((address_space(1))) unsigned*)g,
        (__attribute__((address_space(3))) unsigned*)l, 16, 0, 0);
}

// ============ double block reduce (256 thr) — routing/head only ============
__device__ __forceinline__ double block_reduce_sum_d(double s, double* red, int lane, int wid){
#pragma unroll
    for (int off = 32; off; off >>= 1) s += __shfl_xor(s, off);
    if (lane == 0) red[wid] = s;
    __syncthreads();
    double S = red[0] + red[1] + red[2] + red[3];
    __syncthreads();
    return S;
}

// ============ weight convert f32 -> bf16 ============
__global__ void convert_w_k(const float* __restrict__ in, short* __restrict__ out, long n){
    long i = ((long)blockIdx.x * 256 + threadIdx.x) * 8;
    long stride = (long)gridDim.x * 256 * 8;
    for (; i < n; i += stride){
        float4 a = *(const float4*)(in + i);
        float4 b = *(const float4*)(in + i + 4);
        uint4 o4;
        o4.x = pk2(a.x, a.y); o4.y = pk2(a.z, a.w);
        o4.z = pk2(b.x, b.y); o4.w = pk2(b.z, b.w);
        *(uint4*)(out + i) = o4;
    }
}

// ============ bf16 MFMA GEMM, BK=32, global_load_lds staging (round-12, verified) ============
template<int EPI, int WB>
__global__ __launch_bounds__(256) void gemm_bf16(
    const short* __restrict__ A, const void* __restrict__ Wv,
    const float* __restrict__ bias, const float* __restrict__ Res,
    float* __restrict__ Cf, short* __restrict__ Cb, int M, int K, int N)
{
    __shared__ short As[128 * 32];
    __shared__ short Bs[128 * 32];
    const int t = threadIdx.x;
    const int lane = t & 63, wid = t >> 6;
    const int wr = wid >> 1, wc = wid & 1;
    const long row0 = (long)blockIdx.y * 128;
    const long col0 = (long)blockIdx.x * 128;

    f32x4 acc[4][4];
#pragma unroll
    for (int i = 0; i < 4; i++)
#pragma unroll
        for (int j = 0; j < 4; j++) acc[i][j] = (f32x4){0.f, 0.f, 0.f, 0.f};

    const int l15 = lane & 15, lkg = lane >> 4;
    const int lrow = lane >> 2;
    const int lcol = (lane & 3) * 8;

    for (int k0 = 0; k0 < K; k0 += 32){
#pragma unroll
        for (int i = 0; i < 2; i++){
            int rb = wid * 32 + i * 16;
            gld16(A + (row0 + rb + lrow) * K + k0 + lcol, &As[rb * 32]);
        }
        if (WB == 1){
            const short* Wb = (const short*)Wv;
#pragma unroll
            for (int i = 0; i < 2; i++){
                int rb = wid * 32 + i * 16;
                gld16(Wb + (col0 + rb + lrow) * K + k0 + lcol, &Bs[rb * 32]);
            }
        } else {
            const float* Wf = (const float*)Wv;
            const int bn = t >> 1, bh = t & 1;
            const float* Wp = Wf + (col0 + bn) * K + k0 + bh * 16;
            unsigned rr[8];
#pragma unroll
            for (int g = 0; g < 8; g++){
                float2 f = *(const float2*)(Wp + g * 2);
                rr[g] = pk2(f.x, f.y);
            }
            uint4 lo = {rr[0], rr[1], rr[2], rr[3]};
            uint4 hi = {rr[4], rr[5], rr[6], rr[7]};
            *(uint4*)(&Bs[bn * 32 + bh * 16])     = lo;
            *(uint4*)(&Bs[bn * 32 + bh * 16 + 8]) = hi;
        }
        __syncthreads();

        short8v a[4], b[4];
#pragma unroll
        for (int i = 0; i < 4; i++)
            a[i] = *(const short8v*)(&As[(wr * 64 + i * 16 + l15) * 32 + lkg * 8]);
#pragma unroll
        for (int j = 0; j < 4; j++)
            b[j] = *(const short8v*)(&Bs[(wc * 64 + j * 16 + l15) * 32 + lkg * 8]);
#pragma unroll
        for (int i = 0; i < 4; i++)
#pragma unroll
            for (int j = 0; j < 4; j++)
                acc[i][j] = __builtin_amdgcn_mfma_f32_16x16x32_bf16(a[i], b[j], acc[i][j], 0, 0, 0);
        __syncthreads();
    }

#pragma unroll
    for (int i = 0; i < 4; i++){
#pragma unroll
        for (int q = 0; q < 4; q++){
            long gr = row0 + wr * 64 + i * 16 + lkg * 4 + q;
            if (gr >= M) continue;
#pragma unroll
            for (int j = 0; j < 4; j++){
                long gc = col0 + wc * 64 + j * 16 + l15;
                float v = acc[i][j][q] + bias[gc];
                if (EPI == 1){
                    v = 0.5f * v * (1.f + erff(v * 0.70710678118654752f));
                    Cb[gr * N + gc] = f2bf(v);
                } else if (EPI == 2){
                    Cf[gr * N + gc] = v + Res[gr * N + gc];
                } else if (EPI == 3){
                    Cb[gr * N + gc] = f2bf(v);
                } else {
                    Cf[gr * N + gc] = v;
                }
            }
        }
    }
}

// ============ LayerNorm: wave-per-row (unchanged) ============
__global__ __launch_bounds__(256) void ln_k(const float* __restrict__ x,
    const float* __restrict__ w, const float* __restrict__ b,
    short* __restrict__ y, int M)
{
    const int lane = threadIdx.x & 63, wv = threadIdx.x >> 6;
    const int row = blockIdx.x * 4 + wv;
    if (row >= M) return;
    const float* xr = x + (long)row * 768;
    float v[12];
    float s = 0.f;
#pragma unroll
    for (int j = 0; j < 12; j++){ v[j] = xr[lane + j * 64]; s += v[j]; }
#pragma unroll
    for (int off = 32; off; off >>= 1) s += __shfl_xor(s, off);
    float m = s * (1.f / 768.f);
    float q = 0.f;
#pragma unroll
    for (int j = 0; j < 12; j++){ v[j] -= m; q += v[j] * v[j]; }
#pragma unroll
    for (int off = 32; off; off >>= 1) q += __shfl_xor(q, off);
    float rs = 1.f / sqrtf(q * (1.f / 768.f) + 1e-6f);
    short* yr = y + (long)row * 768;
#pragma unroll
    for (int j = 0; j < 12; j++)
        yr[lane + j * 64] = f2bf(v[j] * rs * w[lane + j * 64] + b[lane + j * 64]);
}

// ============ std MHA via MFMA (round-12 verified body + tile-range args) ============
// seg picks (qkv, o, Ntok, tile range). Mode 0: two segments, full range.
// Mode 1: same segment twice, split tile ranges (more blocks -> better CU coverage).
__global__ __launch_bounds__(512) void attn_mfma(
    const short* __restrict__ qkv0, short* __restrict__ o0, int N0, int tb0, int te0,
    const short* __restrict__ qkv1, short* __restrict__ o1, int N1, int tb1, int te1)
{
    __shared__ short Ks[208 * 72];
    __shared__ short Vs[64 * 232];
    __shared__ short Ps[8 * 16 * 232];
    const int bh = blockIdx.x;
    const int b = bh / HEADS_, h = bh % HEADS_;
    const int seg = blockIdx.y;
    const short* qkv = seg ? qkv1 : qkv0;
    short* o = seg ? o1 : o0;
    const int Ntok = seg ? N1 : N0;
    const int tb = seg ? tb1 : tb0;
    const int te = seg ? te1 : te0;
    const int t = threadIdx.x, lane = t & 63, wid = t >> 6;
    const long rb = (long)b * Ntok;

    {
        const int r = t >> 2, c = (t & 3) * 16;
#pragma unroll
        for (int pass = 0; pass < 2; pass++){
            int m = r + pass * 128;
            if (m < 208){
                if (m < Ntok){
                    const short* kr = qkv + (rb + m) * 2304 + 768  + h * 64 + c;
                    const short* vr = qkv + (rb + m) * 2304 + 1536 + h * 64 + c;
                    *(uint4*)(&Ks[m * 72 + c])     = *(const uint4*)(kr);
                    *(uint4*)(&Ks[m * 72 + c + 8]) = *(const uint4*)(kr + 8);
#pragma unroll
                    for (int j = 0; j < 16; j++)
                        Vs[(c + j) * 232 + m] = vr[j];
                } else {
#pragma unroll
                    for (int j = 0; j < 16; j += 2)
                        *(unsigned*)(&Ks[m * 72 + c + j]) = 0u;
#pragma unroll
                    for (int j = 0; j < 16; j++)
                        Vs[(c + j) * 232 + m] = 0;
                }
            }
        }
        for (int i = t; i < 64 * 16; i += 512){
            int d = i >> 4, m = 208 + (i & 15);
            Vs[d * 232 + m] = 0;
        }
        for (int i = t; i < 8 * 16 * 16; i += 512){
            int w = i >> 8, rr = (i >> 4) & 15, m = 208 + (i & 15);
            Ps[(w * 16 + rr) * 232 + m] = 0;
        }
    }
    __syncthreads();

    const int l15 = lane & 15, lkg = lane >> 4;
    short* Pw = &Ps[wid * 16 * 232];

    for (int s = tb + wid; s < te; s += 8){
        const int q0 = s * 16;
        short8v a0, a1;
        {
            int qrow = q0 + l15;
            if (qrow < Ntok){
                const short* qp = qkv + (rb + qrow) * 2304 + h * 64;
                a0 = *(const short8v*)(qp + lkg * 8);
                a1 = *(const short8v*)(qp + 32 + lkg * 8);
            } else {
                uint4 z = {0u,0u,0u,0u};
                a0 = __builtin_bit_cast(short8v, z);
                a1 = __builtin_bit_cast(short8v, z);
            }
        }
        f32x4 sacc[13];
#pragma unroll
        for (int j = 0; j < 13; j++){
            short8v b0 = *(const short8v*)(&Ks[(j * 16 + l15) * 72 + lkg * 8]);
            short8v b1 = *(const short8v*)(&Ks[(j * 16 + l15) * 72 + 32 + lkg * 8]);
            f32x4 z = {0.f, 0.f, 0.f, 0.f};
            z = __builtin_amdgcn_mfma_f32_16x16x32_bf16(a0, b0, z, 0, 0, 0);
            z = __builtin_amdgcn_mfma_f32_16x16x32_bf16(a1, b1, z, 0, 0, 0);
            sacc[j][0] = z[0] * 0.125f; sacc[j][1] = z[1] * 0.125f;
            sacc[j][2] = z[2] * 0.125f; sacc[j][3] = z[3] * 0.125f;
        }
#pragma unroll
        for (int j = 0; j < 13; j++){
            if (j * 16 + l15 >= Ntok){
                sacc[j][0] = -1e30f; sacc[j][1] = -1e30f;
                sacc[j][2] = -1e30f; sacc[j][3] = -1e30f;
            }
        }
#pragma unroll
        for (int rr = 0; rr < 4; rr++){
            float mx = sacc[0][rr];
#pragma unroll
            for (int j = 1; j < 13; j++) mx = fmaxf(mx, sacc[j][rr]);
            mx = fmaxf(mx, __shfl_xor(mx, 1));
            mx = fmaxf(mx, __shfl_xor(mx, 2));
            mx = fmaxf(mx, __shfl_xor(mx, 4));
            mx = fmaxf(mx, __shfl_xor(mx, 8));
            float pv[13];
            float sum = 0.f;
#pragma unroll
            for (int j = 0; j < 13; j++){
                float e = expf(sacc[j][rr] - mx);
                pv[j] = e; sum += e;
            }
            sum += __shfl_xor(sum, 1);
            sum += __shfl_xor(sum, 2);
            sum += __shfl_xor(sum, 4);
            sum += __shfl_xor(sum, 8);
            float inv = 1.f / sum;
#pragma unroll
            for (int j = 0; j < 13; j++)
                Pw[(lkg * 4 + rr) * 232 + j * 16 + l15] = f2bf(pv[j] * inv);
        }
        short8v pa[7];
#pragma unroll
        for (int kc = 0; kc < 7; kc++)
            pa[kc] = *(const short8v*)(&Pw[l15 * 232 + kc * 32 + lkg * 8]);
#pragma unroll
        for (int dj = 0; dj < 4; dj++){
            f32x4 oacc = {0.f, 0.f, 0.f, 0.f};
#pragma unroll
            for (int kc = 0; kc < 7; kc++){
                short8v vb = *(const short8v*)(&Vs[(dj * 16 + l15) * 232 + kc * 32 + lkg * 8]);
                oacc = __builtin_amdgcn_mfma_f32_16x16x32_bf16(pa[kc], vb, oacc, 0, 0, 0);
            }
#pragma unroll
            for (int rr = 0; rr < 4; rr++){
                int q = q0 + lkg * 4 + rr;
                if (q < Ntok)
                    o[(rb + q) * 768 + h * 64 + dj * 16 + l15] = f2bf(oacc[rr]);
            }
        }
    }
}

// ============ deep attention v3: 4 queries/block (amortize K/V reads 4x) ============
// grid (B_, 50); wave w does softmax for query w; PV reads each V row once for 4 queries.
__global__ __launch_bounds__(256) void attn_deep_v3(
    const short* __restrict__ qkv, const float* __restrict__ prompts,
    const int* __restrict__ selm, short* __restrict__ o, int li)
{
    __shared__ float sc[4][208];
    const int b = blockIdx.x, g = blockIdx.y, t = threadIdx.x;
    const int lane = t & 63, w = t >> 6;
    const int n0 = g * 4;

    // 4 query rows in registers (clamped duplicates for n>=197; writes guarded)
    float4 q0[4], q1[4], q2[4];
#pragma unroll
    for (int qi = 0; qi < 4; qi++){
        int n = n0 + qi;
        int nn = (n < NT_) ? n : (NT_ - 1);
        const short* qr = qkv + (long)(b * NT_ + nn) * 2304;
        q0[qi] = ld4bf(qr + lane * 4);
        q1[qi] = ld4bf(qr + 256 + lane * 4);
        q2[qi] = ld4bf(qr + 512 + lane * 4);
    }

    const float* kp = prompts + ((long)selm[b] * 6 + 2 * li) * 5 * 768;
    const float* vp = kp + 5 * 768;

    // QK: wave-per-key, K row loaded once for 4 queries
    for (int m = w; m < 202; m += 4){
        float4 k0, k1, k2;
        if (m < 5){
            const float* kr = kp + (long)m * 768;
            k0 = *(const float4*)(kr + lane * 4);
            k1 = *(const float4*)(kr + 256 + lane * 4);
            k2 = *(const float4*)(kr + 512 + lane * 4);
        } else {
            const short* kr = qkv + (long)(b * NT_ + (m - 5)) * 2304 + 768;
            k0 = ld4bf(kr + lane * 4);
            k1 = ld4bf(kr + 256 + lane * 4);
            k2 = ld4bf(kr + 512 + lane * 4);
        }
        float a[4];
#pragma unroll
        for (int qi = 0; qi < 4; qi++){
            a[qi] = q0[qi].x*k0.x + q0[qi].y*k0.y + q0[qi].z*k0.z + q0[qi].w*k0.w
                  + q1[qi].x*k1.x + q1[qi].y*k1.y + q1[qi].z*k1.z + q1[qi].w*k1.w
                  + q2[qi].x*k2.x + q2[qi].y*k2.y + q2[qi].z*k2.z + q2[qi].w*k2.w;
        }
#pragma unroll
        for (int off = 32; off; off >>= 1){
#pragma unroll
            for (int qi = 0; qi < 4; qi++) a[qi] += __shfl_xor(a[qi], off);
        }
        if (lane == 0){
#pragma unroll
            for (int qi = 0; qi < 4; qi++) sc[qi][m] = a[qi] * 0.125f;
        }
    }
    __syncthreads();

    // softmax: wave w owns query w (lane covers m = lane + i*64)
    {
        float v[4];
#pragma unroll
        for (int i = 0; i < 4; i++){
            int m = lane + i * 64;
            v[i] = (m < 202) ? sc[w][m] : -1e30f;
        }
        float mx = fmaxf(fmaxf(v[0], v[1]), fmaxf(v[2], v[3]));
#pragma unroll
        for (int off = 32; off; off >>= 1) mx = fmaxf(mx, __shfl_xor(mx, off));
        float e[4], sum = 0.f;
#pragma unroll
        for (int i = 0; i < 4; i++){
            int m = lane + i * 64;
            e[i] = (m < 202) ? expf(v[i] - mx) : 0.f;
            sum += e[i];
        }
#pragma unroll
        for (int off = 32; off; off >>= 1) sum += __shfl_xor(sum, off);
        float inv = 1.f / sum;
#pragma unroll
        for (int i = 0; i < 4; i++){
            int m = lane + i * 64;
            if (m < 202) sc[w][m] = e[i] * inv;
        }
    }
    __syncthreads();

    // PV: thread t covers dims t,+256,+512; V row read once for 4 queries
    float a0[4] = {0.f,0.f,0.f,0.f}, a1[4] = {0.f,0.f,0.f,0.f}, a2[4] = {0.f,0.f,0.f,0.f};
    for (int m = 0; m < 5; m++){
        const float* vr = vp + (long)m * 768;
        float v0 = vr[t], v1 = vr[t + 256], v2 = vr[t + 512];
#pragma unroll
        for (int qi = 0; qi < 4; qi++){
            float pm = sc[qi][m];
            a0[qi] += pm * v0; a1[qi] += pm * v1; a2[qi] += pm * v2;
        }
    }
    for (int m = 5; m < 202; m++){
        const short* vr = qkv + (long)(b * NT_ + (m - 5)) * 2304 + 1536;
        float v0 = bf2f((unsigned short)vr[t]);
        float v1 = bf2f((unsigned short)vr[t + 256]);
        float v2 = bf2f((unsigned short)vr[t + 512]);
#pragma unroll
        for (int qi = 0; qi < 4; qi++){
            float pm = sc[qi][m];
            a0[qi] += pm * v0; a1[qi] += pm * v1; a2[qi] += pm * v2;
        }
    }
#pragma unroll
    for (int qi = 0; qi < 4; qi++){
        int n = n0 + qi;
        if (n < NT_){
            short* ob = o + (long)b * NT_ * 768 + n;   // transposed (scramble-folded) layout
            ob[(long)t * 197]         = f2bf(a0[qi]);
            ob[(long)(t + 256) * 197] = f2bf(a1[qi]);
            ob[(long)(t + 512) * 197] = f2bf(a2[qi]);
        }
    }
}

// ============ patch unfold (f32 -> bf16) ============
__global__ void unfold_k(const float* __restrict__ in, short* __restrict__ out){
    long i = (long)blockIdx.x * 256 + threadIdx.x;
    long total = (long)B_ * 196 * 768;
    if (i >= total) return;
    int f = (int)(i % 768); long rw = i / 768;
    int t = (int)(rw % 196); int b = (int)(rw / 196);
    int gy = t / 14, gx = t % 14;
    int c = f >> 8, rem = f & 255, py = rem >> 4, px = rem & 15;
    out[i] = f2bf(in[(((long)(b * 3 + c) * 224) + gy * 16 + py) * 224 + gx * 16 + px]);
}

// ============ assemble x0 = [cls+pos ; patches+pos] (f32) ============
__global__ void assemble_k(const float* __restrict__ pe, const float* __restrict__ cls,
    const float* __restrict__ pos, float* __restrict__ x0){
    long i = (long)blockIdx.x * 256 + threadIdx.x;
    long total = (long)B_ * NT_ * 768;
    if (i >= total) return;
    int d = (int)(i % 768); long rw = i / 768;
    int n = (int)(rw % NT_); int b = (int)(rw / NT_);
    float v;
    if (n == 0) v = cls[d] + pos[d];
    else        v = pe[((long)b * 196 + (n - 1)) * 768 + d] + pos[(long)n * 768 + d];
    x0[i] = v;
}

__global__ void copy_f(const float* __restrict__ a, float* __restrict__ b, long total){
    long i = (long)blockIdx.x * 256 + threadIdx.x;
    if (i < total) b[i] = a[i];
}

// ============ build sub-branch rows ============
__global__ void build_sub_k(const float* __restrict__ x0, const float* __restrict__ subp,
    const float* __restrict__ pos, float* __restrict__ xSub){
    long i = (long)blockIdx.x * 256 + threadIdx.x;
    long total = (long)B_ * NS_ * 768;
    if (i >= total) return;
    int d = (int)(i % 768); long rw = i / 768;
    int n = (int)(rw % NS_); int b = (int)(rw / NS_);
    float v;
    if (n == 0)      v = x0[((long)b * NT_) * 768 + d];
    else if (n <= 5) v = subp[(n - 1) * 768 + d] + pos[d];
    else             v = x0[((long)b * NT_ + (n - 5)) * 768 + d];
    xSub[i] = v;
}

// ============ routing (f64 internals) ============
__global__ __launch_bounds__(256) void select_k(
    const float* __restrict__ xA, const float* __restrict__ norm_w,
    const float* __restrict__ norm_b, const float* __restrict__ main_key,
    const float* __restrict__ sub_key, const int* __restrict__ task_id_p,
    int* __restrict__ selm, int* __restrict__ flag)
{
    __shared__ double red[4];
    int b = blockIdx.x, t = threadIdx.x, lane = t & 63, wid = t >> 6;
    const float* xr = xA + (long)b * NT_ * 768;
    double v0 = xr[t], v1 = xr[t + 256], v2 = xr[t + 512];
    double S = block_reduce_sum_d(v0 + v1 + v2, red, lane, wid);
    double m = S * (1.0 / 768.0);
    double d0 = v0 - m, d1 = v1 - m, d2 = v2 - m;
    double Q = block_reduce_sum_d(d0*d0 + d1*d1 + d2*d2, red, lane, wid);
    double rs = 1.0 / sqrt(Q * (1.0 / 768.0) + 1e-6);
    double q0 = d0 * rs * (double)norm_w[t]       + (double)norm_b[t];
    double q1 = d1 * rs * (double)norm_w[t + 256] + (double)norm_b[t + 256];
    double q2 = d2 * rs * (double)norm_w[t + 512] + (double)norm_b[t + 512];
    double qn = block_reduce_sum_d(q0*q0 + q1*q1 + q2*q2, red, lane, wid);
    double qinv = 1.0 / sqrt(fmax(qn, 1e-12));

    int tk = *task_id_p;
    int ncand = tk + 2;
    double best = -1e300; int bsel = 0;
    for (int c = 0; c < ncand; c++){
        const float* cr = (c <= tk) ? (main_key + (long)c * 768) : sub_key;
        double c0 = cr[t], c1 = cr[t + 256], c2 = cr[t + 512];
        double dotq = block_reduce_sum_d(q0*c0 + q1*c1 + q2*c2, red, lane, wid);
        double nc   = block_reduce_sum_d(c0*c0 + c1*c1 + c2*c2, red, lane, wid);
        double sim = dotq * qinv * (1.0 / sqrt(fmax(nc, 1e-12)));
        if (sim > best){ best = sim; bsel = c; }
    }
    if (t == 0){
        int isMain = (bsel <= tk) ? 1 : 0;
        selm[b] = isMain ? bsel : 0;
        flag[b] = isMain;
    }
}

// ============ final head (f64 internals, f32 out) ============
__global__ __launch_bounds__(256) void head_k(
    const float* __restrict__ xM, const float* __restrict__ xSub,
    const float* __restrict__ norm_w, const float* __restrict__ norm_b,
    const float* __restrict__ fc_w, const float* __restrict__ fc_b,
    const int* __restrict__ flag, float* __restrict__ out)
{
    __shared__ double vec[768];
    __shared__ double red[4];
    int b = blockIdx.x, t = threadIdx.x, lane = t & 63, wid = t >> 6;
    int isMain = flag[b];
    double a0 = 0.0, a1 = 0.0, a2 = 0.0;
    int nrows = isMain ? 1 : 5;
    for (int rI = 0; rI < nrows; rI++){
        const float* xr = isMain ? (xM + (long)b * NT_ * 768)
                                 : (xSub + ((long)b * NS_ + 1 + rI) * 768);
        double v0 = xr[t], v1 = xr[t + 256], v2 = xr[t + 512];
        double S = block_reduce_sum_d(v0 + v1 + v2, red, lane, wid);
        double m = S * (1.0 / 768.0);
        double d0 = v0 - m, d1 = v1 - m, d2 = v2 - m;
        double Q = block_reduce_sum_d(d0*d0 + d1*d1 + d2*d2, red, lane, wid);
        double rs = 1.0 / sqrt(Q * (1.0 / 768.0) + 1e-6);
        a0 += d0 * rs * (double)norm_w[t]       + (double)norm_b[t];
        a1 += d1 * rs * (double)norm_w[t + 256] + (double)norm_b[t + 256];
        a2 += d2 * rs * (double)norm_w[t + 512] + (double)norm_b[t + 512];
    }
    double scl = isMain ? 1.0 : 0.2;
    vec[t] = a0 * scl; vec[t + 256] = a1 * scl; vec[t + 512] = a2 * scl;
    __syncthreads();
    if (t < NCLS_){
        const float* wr = fc_w + (long)t * 768;
        double acc = (double)fc_b[t];
#pragma unroll 8
        for (int j = 0; j < 768; j++) acc += vec[j] * (double)wr[j];
        out[b * NCLS_ + t] = (float)acc;
    }
}

// ================= host-side =================
struct Params {
    const float *qkv_w, *qkv_b, *proj_w, *proj_b;
    const float *ln1_w, *ln1_b, *ln2_w, *ln2_b;
    const float *fc1_w, *fc1_b, *fc2_w, *fc2_b;
    const float *prompts; const int* selm;
    short *lnb, *attb, *hidb;
    short *qkvb;
    const short *qkv_wc, *proj_wc, *fc1_wc, *fc2_wc;
    bool cache;
};

template<int EPI>
static void launch_gemm(hipStream_t st, const short* A, const float* Wf, const short* Wc,
                        bool cache, const float* bias, const float* Res,
                        float* Cf, short* Cb, int M, int K, int N)
{
    dim3 g(N / 128, (M + 127) / 128);
    if (cache)
        gemm_bf16<EPI, 1><<<g, 256, 0, st>>>(A, (const void*)Wc, bias, Res, Cf, Cb, M, K, N);
    else
        gemm_bf16<EPI, 0><<<g, 256, 0, st>>>(A, (const void*)Wf, bias, Res, Cf, Cb, M, K, N);
}

// mode 0: concat (std attn both segments)  mode 1: main std  mode 2: main deep
static void run_layer(hipStream_t st, float* x, int M, int layer, int mode, int li,
                      const Params& P)
{
    int lnGrid = (M + 3) / 4;
    ln_k<<<lnGrid, 256, 0, st>>>(x, P.ln1_w + layer * 768, P.ln1_b + layer * 768, P.lnb, M);
    launch_gemm<3>(st, P.lnb, P.qkv_w + (long)layer * 2304 * 768,
        P.qkv_wc + (P.cache ? (long)layer * 2304 * 768 : 0), P.cache,
        P.qkv_b + layer * 2304, nullptr, nullptr, P.qkvb, M, 768, 2304);
    if (mode == 0){
        attn_mfma<<<dim3(B_ * HEADS_, 2), 512, 0, st>>>(
            P.qkvb, P.attb, NT_, 0, 13,
            P.qkvb + (long)MROW_ * 2304, P.attb + (long)MROW_ * 768, NS_, 0, 13);
    } else if (mode == 1){
        attn_mfma<<<dim3(B_ * HEADS_, 2), 512, 0, st>>>(
            P.qkvb, P.attb, NT_, 0, 7,
            P.qkvb, P.attb, NT_, 7, 13);
    } else {
        attn_deep_v3<<<dim3(B_, 50), 256, 0, st>>>(P.qkvb, P.prompts, P.selm, P.attb, li);
    }
    launch_gemm<2>(st, P.attb, P.proj_w + (long)layer * 768 * 768,
        P.proj_wc + (P.cache ? (long)layer * 768 * 768 : 0), P.cache,
        P.proj_b + layer * 768, x, x, nullptr, M, 768, 768);
    ln_k<<<lnGrid, 256, 0, st>>>(x, P.ln2_w + layer * 768, P.ln2_b + layer * 768, P.lnb, M);
    launch_gemm<1>(st, P.lnb, P.fc1_w + (long)layer * 3072 * 768,
        P.fc1_wc + (P.cache ? (long)layer * 3072 * 768 : 0), P.cache,
        P.fc1_b + layer * 3072, nullptr, nullptr, P.hidb, M, 768, 3072);
    launch_gemm<2>(st, P.hidb, P.fc2_w + (long)layer * 768 * 3072,
        P.fc2_wc + (P.cache ? (long)layer * 768 * 3072 : 0), P.cache,
        P.fc2_b + layer * 768, x, x, nullptr, M, 3072, 768);
}

extern "C" void kernel_launch(void* const* d_in, const int* in_sizes, int n_in,
                              void* d_out, int out_size, void* d_ws, size_t ws_size,
                              hipStream_t stream)
{
    (void)in_sizes; (void)n_in; (void)out_size;
    const float* inputs   = (const float*)d_in[0];
    const int*   task_id  = (const int*)  d_in[1];
    const float* patch_w  = (const float*)d_in[2];
    const float* patch_b  = (const float*)d_in[3];
    const float* cls_tok  = (const float*)d_in[4];
    const float* pos      = (const float*)d_in[5];
    const float* qkv_w    = (const float*)d_in[6];
    const float* qkv_b    = (const float*)d_in[7];
    const float* proj_w   = (const float*)d_in[8];
    const float* proj_b   = (const float*)d_in[9];
    const float* ln1_w    = (const float*)d_in[10];
    const float* ln1_b    = (const float*)d_in[11];
    const float* ln2_w    = (const float*)d_in[12];
    const float* ln2_b    = (const float*)d_in[13];
    const float* fc1_w    = (const float*)d_in[14];
    const float* fc1_b    = (const float*)d_in[15];
    const float* fc2_w    = (const float*)d_in[16];
    const float* fc2_b    = (const float*)d_in[17];
    const float* norm_w   = (const float*)d_in[18];
    const float* norm_b   = (const float*)d_in[19];
    const float* fc_w     = (const float*)d_in[20];
    const float* fc_b     = (const float*)d_in[21];
    const float* main_key = (const float*)d_in[22];
    const float* sub_key  = (const float*)d_in[23];
    const float* m_prompts= (const float*)d_in[24];
    const float* s_prompt = (const float*)d_in[25];
    float* out = (float*)d_out;

    char* wsb = (char*)d_ws;
    size_t off = 0;
    auto allocB = [&](size_t bytes) -> void* {
        void* p = (void*)(wsb + off);
        off += (bytes + 255) & ~(size_t)255;
        return p;
    };
    float* x0   = (float*)allocB((size_t)MROW_ * 768 * 4);
    float* xC   = (float*)allocB((size_t)CROW_ * 768 * 4);
    float* xM   = (float*)allocB((size_t)MROW_ * 768 * 4);
    short* lnb  = (short*)allocB((size_t)(CROW_ + PAD_) * 768 * 2);
    short* attb = (short*)allocB((size_t)(CROW_ + PAD_) * 768 * 2);
    short* qkvb = (short*)allocB((size_t)(CROW_ + PAD_) * 2304 * 2);
    short* hidb = (short*)allocB((size_t)(CROW_ + PAD_) * 3072 * 2);
    float* peo  = (float*)allocB((size_t)3136 * 768 * 4);
    int*   selm = (int*)allocB(64);
    int*   flag = (int*)allocB(64);

    const size_t nQkv = (size_t)DEPTH_ * 2304 * 768;
    const size_t nProj = (size_t)DEPTH_ * 768 * 768;
    const size_t nFc1 = (size_t)DEPTH_ * 3072 * 768;
    const size_t nFc2 = (size_t)DEPTH_ * 768 * 3072;
    const size_t nPatch = (size_t)768 * 768;
    size_t cacheBytes = (nQkv + nProj + nFc1 + nFc2 + nPatch) * 2 + 5 * 256;
    bool cache = (ws_size >= off + cacheBytes + (1u << 20));
    short *qkv_wc = nullptr, *proj_wc = nullptr, *fc1_wc = nullptr, *fc2_wc = nullptr, *patch_wc = nullptr;
    if (cache){
        qkv_wc  = (short*)allocB(nQkv * 2);
        proj_wc = (short*)allocB(nProj * 2);
        fc1_wc  = (short*)allocB(nFc1 * 2);
        fc2_wc  = (short*)allocB(nFc2 * 2);
        patch_wc= (short*)allocB(nPatch * 2);
        convert_w_k<<<2048, 256, 0, stream>>>(qkv_w,  qkv_wc,  (long)nQkv);
        convert_w_k<<<1024, 256, 0, stream>>>(proj_w, proj_wc, (long)nProj);
        convert_w_k<<<2048, 256, 0, stream>>>(fc1_w,  fc1_wc,  (long)nFc1);
        convert_w_k<<<2048, 256, 0, stream>>>(fc2_w,  fc2_wc,  (long)nFc2);
        convert_w_k<<<256,  256, 0, stream>>>(patch_w, patch_wc, (long)nPatch);
    }

    Params P;
    P.qkv_w = qkv_w; P.qkv_b = qkv_b; P.proj_w = proj_w; P.proj_b = proj_b;
    P.ln1_w = ln1_w; P.ln1_b = ln1_b; P.ln2_w = ln2_w; P.ln2_b = ln2_b;
    P.fc1_w = fc1_w; P.fc1_b = fc1_b; P.fc2_w = fc2_w; P.fc2_b = fc2_b;
    P.prompts = m_prompts; P.selm = selm;
    P.lnb = lnb; P.attb = attb; P.hidb = hidb; P.qkvb = qkvb;
    P.qkv_wc = qkv_wc; P.proj_wc = proj_wc; P.fc1_wc = fc1_wc; P.fc2_wc = fc2_wc;
    P.cache = cache;

    const long XN = (long)MROW_ * 768;

    // -------- patch embed --------
    {
        long tot = (long)B_ * 196 * 768;
        short* un = hidb;
        unfold_k<<<(int)((tot + 255) / 256), 256, 0, stream>>>(inputs, un);
        launch_gemm<0>(stream, un, patch_w, patch_wc, cache, patch_b, nullptr,
                       peo, nullptr, 3136, 768, 768);
        assemble_k<<<(int)((XN + 255) / 256), 256, 0, stream>>>(peo, cls_tok, pos, x0);
        copy_f<<<(int)((XN + 255) / 256), 256, 0, stream>>>(x0, xC, XN);
        long st = (long)SROW_ * 768;
        build_sub_k<<<(int)((st + 255) / 256), 256, 0, stream>>>(x0, s_prompt, pos,
                                                                 xC + (long)MROW_ * 768);
    }

    // -------- concatenated pass A + sub branch --------
    for (int i = 0; i < DEPTH_; i++){
        run_layer(stream, xC, CROW_, i, 0, 0, P);
        if (i == 1)
            copy_f<<<(int)((XN + 255) / 256), 256, 0, stream>>>(xC, xM, XN);
    }

    // -------- routing --------
    select_k<<<16, 256, 0, stream>>>(xC, norm_w, norm_b, main_key, sub_key,
                                     task_id, selm, flag);

    // -------- main branch layers 2..11 (deep prompts at 2,3,4) --------
    for (int i = 2; i < DEPTH_; i++){
        int mode = (i >= 2 && i <= 4) ? 2 : 1;
        run_layer(stream, xM, MROW_, i, mode, i - 2, P);
    }

    // -------- heads + per-sample select --------
    head_k<<<16, 256, 0, stream>>>(xM, xC + (long)MROW_ * 768, norm_w, norm_b,
                                   fc_w, fc_b, flag, out);
}

// Round 15
// 5434.503 us; speedup vs baseline: 1.1678x; 1.0922x over previous
//
#include <hip/hip_runtime.h>
#include <math.h>

// ---------------- constants ----------------
#define B_    16
#define NT_   197
#define NS_   202
#define HEADS_ 12
#define DEPTH_ 12
#define NCLS_ 100
#define MROW_ (B_ * NT_)      // 3152
#define SROW_ (B_ * NS_)      // 3232
#define CROW_ (MROW_ + SROW_) // 6384
#define PAD_  128             // GEMM-A row padding (global_load_lds has no row guard)

typedef __attribute__((ext_vector_type(8))) short short8v;
typedef __attribute__((ext_vector_type(4))) float f32x4;

// f32 -> bf16 bits (RNE)
__device__ __forceinline__ short f2bf(float f){
    unsigned u = __builtin_bit_cast(unsigned, f);
    unsigned r = (u + 0x7FFFu + ((u >> 16) & 1u)) >> 16;
    return (short)r;
}
__device__ __forceinline__ unsigned pk2(float a, float b){
    return (unsigned)(unsigned short)f2bf(a) | (((unsigned)(unsigned short)f2bf(b)) << 16);
}
__device__ __forceinline__ float bf2f(unsigned short s){
    unsigned u = ((unsigned)s) << 16;
    return __builtin_bit_cast(float, u);
}
__device__ __forceinline__ float4 ld4bf(const short* p){
    uint2 u = *(const uint2*)p;
    float4 r;
    r.x = bf2f((unsigned short)(u.x & 0xffff));
    r.y = bf2f((unsigned short)(u.x >> 16));
    r.z = bf2f((unsigned short)(u.y & 0xffff));
    r.w = bf2f((unsigned short)(u.y >> 16));
    return r;
}
// async global->LDS, 16B per lane; lds base must be wave-uniform
__device__ __forceinline__ void gld16(const short* g, short* l){
    __builtin_amdgcn_global_load_lds(
        (const __attribute__((address_space(1))) unsigned*)g,
        (__attribute__((address_space(3))) unsigned*)l, 16, 0, 0);
}

// ============ double block reduce (256 thr) — routing/head only ============
__device__ __forceinline__ double block_reduce_sum_d(double s, double* red, int lane, int wid){
#pragma unroll
    for (int off = 32; off; off >>= 1) s += __shfl_xor(s, off);
    if (lane == 0) red[wid] = s;
    __syncthreads();
    double S = red[0] + red[1] + red[2] + red[3];
    __syncthreads();
    return S;
}

// ============ weight convert f32 -> bf16 ============
__global__ void convert_w_k(const float* __restrict__ in, short* __restrict__ out, long n){
    long i = ((long)blockIdx.x * 256 + threadIdx.x) * 8;
    long stride = (long)gridDim.x * 256 * 8;
    for (; i < n; i += stride){
        float4 a = *(const float4*)(in + i);
        float4 b = *(const float4*)(in + i + 4);
        uint4 o4;
        o4.x = pk2(a.x, a.y); o4.y = pk2(a.z, a.w);
        o4.z = pk2(b.x, b.y); o4.w = pk2(b.z, b.w);
        *(uint4*)(out + i) = o4;
    }
}

// ============ bf16 MFMA GEMM, BK=64 (two linear 32-k half-buffers), gload_lds ============
// Same LDS addressing pattern per half as the verified BK=32 kernel; barriers halved.
// A: (M padded) x K bf16, no row guard. W: f32 (WB=0) or bf16 (WB=1).
// EPI 0: Cf f32. 1: GELU->Cb bf16. 2: Cf=Res+.. 3: bias->Cb bf16.  K%64==0, N%128==0.
template<int EPI, int WB>
__global__ __launch_bounds__(256) void gemm_bf16(
    const short* __restrict__ A, const void* __restrict__ Wv,
    const float* __restrict__ bias, const float* __restrict__ Res,
    float* __restrict__ Cf, short* __restrict__ Cb, int M, int K, int N)
{
    __shared__ short As0[128 * 32];
    __shared__ short As1[128 * 32];
    __shared__ short Bs0[128 * 32];
    __shared__ short Bs1[128 * 32];
    const int t = threadIdx.x;
    const int lane = t & 63, wid = t >> 6;
    const int wr = wid >> 1, wc = wid & 1;
    const long row0 = (long)blockIdx.y * 128;
    const long col0 = (long)blockIdx.x * 128;

    f32x4 acc[4][4];
#pragma unroll
    for (int i = 0; i < 4; i++)
#pragma unroll
        for (int j = 0; j < 4; j++) acc[i][j] = (f32x4){0.f, 0.f, 0.f, 0.f};

    const int l15 = lane & 15, lkg = lane >> 4;
    const int lrow = lane >> 2;
    const int lcol = (lane & 3) * 8;

    for (int k0 = 0; k0 < K; k0 += 64){
        // ---- A halves: 4 async 1KB loads per wave ----
#pragma unroll
        for (int i = 0; i < 2; i++){
            int rb = wid * 32 + i * 16;
            const short* gs = A + (row0 + rb + lrow) * K + k0 + lcol;
            gld16(gs,      &As0[rb * 32]);
            gld16(gs + 32, &As1[rb * 32]);
        }
        if (WB == 1){
            const short* Wb = (const short*)Wv;
#pragma unroll
            for (int i = 0; i < 2; i++){
                int rb = wid * 32 + i * 16;
                const short* gs = Wb + (col0 + rb + lrow) * K + k0 + lcol;
                gld16(gs,      &Bs0[rb * 32]);
                gld16(gs + 32, &Bs1[rb * 32]);
            }
        } else {
            const float* Wf = (const float*)Wv;
            const int bn = t >> 1, bh = t & 1;
#pragma unroll
            for (int half = 0; half < 2; half++){
                const float* Wp = Wf + (col0 + bn) * K + k0 + half * 32 + bh * 16;
                unsigned rr[8];
#pragma unroll
                for (int g = 0; g < 8; g++){
                    float2 f = *(const float2*)(Wp + g * 2);
                    rr[g] = pk2(f.x, f.y);
                }
                uint4 lo = {rr[0], rr[1], rr[2], rr[3]};
                uint4 hi = {rr[4], rr[5], rr[6], rr[7]};
                short* Bsh = half ? Bs1 : Bs0;
                *(uint4*)(&Bsh[bn * 32 + bh * 16])     = lo;
                *(uint4*)(&Bsh[bn * 32 + bh * 16 + 8]) = hi;
            }
        }
        __syncthreads();

        // ---- half 0 (k0..k0+32) then half 1 — same accumulation order as BK=32 ----
        {
            short8v a[4], b[4];
#pragma unroll
            for (int i = 0; i < 4; i++)
                a[i] = *(const short8v*)(&As0[(wr * 64 + i * 16 + l15) * 32 + lkg * 8]);
#pragma unroll
            for (int j = 0; j < 4; j++)
                b[j] = *(const short8v*)(&Bs0[(wc * 64 + j * 16 + l15) * 32 + lkg * 8]);
#pragma unroll
            for (int i = 0; i < 4; i++)
#pragma unroll
                for (int j = 0; j < 4; j++)
                    acc[i][j] = __builtin_amdgcn_mfma_f32_16x16x32_bf16(a[i], b[j], acc[i][j], 0, 0, 0);
        }
        {
            short8v a[4], b[4];
#pragma unroll
            for (int i = 0; i < 4; i++)
                a[i] = *(const short8v*)(&As1[(wr * 64 + i * 16 + l15) * 32 + lkg * 8]);
#pragma unroll
            for (int j = 0; j < 4; j++)
                b[j] = *(const short8v*)(&Bs1[(wc * 64 + j * 16 + l15) * 32 + lkg * 8]);
#pragma unroll
            for (int i = 0; i < 4; i++)
#pragma unroll
                for (int j = 0; j < 4; j++)
                    acc[i][j] = __builtin_amdgcn_mfma_f32_16x16x32_bf16(a[i], b[j], acc[i][j], 0, 0, 0);
        }
        __syncthreads();
    }

#pragma unroll
    for (int i = 0; i < 4; i++){
#pragma unroll
        for (int q = 0; q < 4; q++){
            long gr = row0 + wr * 64 + i * 16 + lkg * 4 + q;
            if (gr >= M) continue;
#pragma unroll
            for (int j = 0; j < 4; j++){
                long gc = col0 + wc * 64 + j * 16 + l15;
                float v = acc[i][j][q] + bias[gc];
                if (EPI == 1){
                    v = 0.5f * v * (1.f + erff(v * 0.70710678118654752f));
                    Cb[gr * N + gc] = f2bf(v);
                } else if (EPI == 2){
                    Cf[gr * N + gc] = v + Res[gr * N + gc];
                } else if (EPI == 3){
                    Cb[gr * N + gc] = f2bf(v);
                } else {
                    Cf[gr * N + gc] = v;
                }
            }
        }
    }
}

// ============ LayerNorm: wave-per-row (unchanged) ============
__global__ __launch_bounds__(256) void ln_k(const float* __restrict__ x,
    const float* __restrict__ w, const float* __restrict__ b,
    short* __restrict__ y, int M)
{
    const int lane = threadIdx.x & 63, wv = threadIdx.x >> 6;
    const int row = blockIdx.x * 4 + wv;
    if (row >= M) return;
    const float* xr = x + (long)row * 768;
    float v[12];
    float s = 0.f;
#pragma unroll
    for (int j = 0; j < 12; j++){ v[j] = xr[lane + j * 64]; s += v[j]; }
#pragma unroll
    for (int off = 32; off; off >>= 1) s += __shfl_xor(s, off);
    float m = s * (1.f / 768.f);
    float q = 0.f;
#pragma unroll
    for (int j = 0; j < 12; j++){ v[j] -= m; q += v[j] * v[j]; }
#pragma unroll
    for (int off = 32; off; off >>= 1) q += __shfl_xor(q, off);
    float rs = 1.f / sqrtf(q * (1.f / 768.f) + 1e-6f);
    short* yr = y + (long)row * 768;
#pragma unroll
    for (int j = 0; j < 12; j++)
        yr[lane + j * 64] = f2bf(v[j] * rs * w[lane + j * 64] + b[lane + j * 64]);
}

// ============ std MHA via MFMA (round-12 verified body + tile-range args) ============
__global__ __launch_bounds__(512) void attn_mfma(
    const short* __restrict__ qkv0, short* __restrict__ o0, int N0, int tb0, int te0,
    const short* __restrict__ qkv1, short* __restrict__ o1, int N1, int tb1, int te1)
{
    __shared__ short Ks[208 * 72];
    __shared__ short Vs[64 * 232];
    __shared__ short Ps[8 * 16 * 232];
    const int bh = blockIdx.x;
    const int b = bh / HEADS_, h = bh % HEADS_;
    const int seg = blockIdx.y;
    const short* qkv = seg ? qkv1 : qkv0;
    short* o = seg ? o1 : o0;
    const int Ntok = seg ? N1 : N0;
    const int tb = seg ? tb1 : tb0;
    const int te = seg ? te1 : te0;
    const int t = threadIdx.x, lane = t & 63, wid = t >> 6;
    const long rb = (long)b * Ntok;

    {
        const int r = t >> 2, c = (t & 3) * 16;
#pragma unroll
        for (int pass = 0; pass < 2; pass++){
            int m = r + pass * 128;
            if (m < 208){
                if (m < Ntok){
                    const short* kr = qkv + (rb + m) * 2304 + 768  + h * 64 + c;
                    const short* vr = qkv + (rb + m) * 2304 + 1536 + h * 64 + c;
                    *(uint4*)(&Ks[m * 72 + c])     = *(const uint4*)(kr);
                    *(uint4*)(&Ks[m * 72 + c + 8]) = *(const uint4*)(kr + 8);
#pragma unroll
                    for (int j = 0; j < 16; j++)
                        Vs[(c + j) * 232 + m] = vr[j];
                } else {
#pragma unroll
                    for (int j = 0; j < 16; j += 2)
                        *(unsigned*)(&Ks[m * 72 + c + j]) = 0u;
#pragma unroll
                    for (int j = 0; j < 16; j++)
                        Vs[(c + j) * 232 + m] = 0;
                }
            }
        }
        for (int i = t; i < 64 * 16; i += 512){
            int d = i >> 4, m = 208 + (i & 15);
            Vs[d * 232 + m] = 0;
        }
        for (int i = t; i < 8 * 16 * 16; i += 512){
            int w = i >> 8, rr = (i >> 4) & 15, m = 208 + (i & 15);
            Ps[(w * 16 + rr) * 232 + m] = 0;
        }
    }
    __syncthreads();

    const int l15 = lane & 15, lkg = lane >> 4;
    short* Pw = &Ps[wid * 16 * 232];

    for (int s = tb + wid; s < te; s += 8){
        const int q0 = s * 16;
        short8v a0, a1;
        {
            int qrow = q0 + l15;
            if (qrow < Ntok){
                const short* qp = qkv + (rb + qrow) * 2304 + h * 64;
                a0 = *(const short8v*)(qp + lkg * 8);
                a1 = *(const short8v*)(qp + 32 + lkg * 8);
            } else {
                uint4 z = {0u,0u,0u,0u};
                a0 = __builtin_bit_cast(short8v, z);
                a1 = __builtin_bit_cast(short8v, z);
            }
        }
        f32x4 sacc[13];
#pragma unroll
        for (int j = 0; j < 13; j++){
            short8v b0 = *(const short8v*)(&Ks[(j * 16 + l15) * 72 + lkg * 8]);
            short8v b1 = *(const short8v*)(&Ks[(j * 16 + l15) * 72 + 32 + lkg * 8]);
            f32x4 z = {0.f, 0.f, 0.f, 0.f};
            z = __builtin_amdgcn_mfma_f32_16x16x32_bf16(a0, b0, z, 0, 0, 0);
            z = __builtin_amdgcn_mfma_f32_16x16x32_bf16(a1, b1, z, 0, 0, 0);
            sacc[j][0] = z[0] * 0.125f; sacc[j][1] = z[1] * 0.125f;
            sacc[j][2] = z[2] * 0.125f; sacc[j][3] = z[3] * 0.125f;
        }
#pragma unroll
        for (int j = 0; j < 13; j++){
            if (j * 16 + l15 >= Ntok){
                sacc[j][0] = -1e30f; sacc[j][1] = -1e30f;
                sacc[j][2] = -1e30f; sacc[j][3] = -1e30f;
            }
        }
#pragma unroll
        for (int rr = 0; rr < 4; rr++){
            float mx = sacc[0][rr];
#pragma unroll
            for (int j = 1; j < 13; j++) mx = fmaxf(mx, sacc[j][rr]);
            mx = fmaxf(mx, __shfl_xor(mx, 1));
            mx = fmaxf(mx, __shfl_xor(mx, 2));
            mx = fmaxf(mx, __shfl_xor(mx, 4));
            mx = fmaxf(mx, __shfl_xor(mx, 8));
            float pv[13];
            float sum = 0.f;
#pragma unroll
            for (int j = 0; j < 13; j++){
                float e = expf(sacc[j][rr] - mx);
                pv[j] = e; sum += e;
            }
            sum += __shfl_xor(sum, 1);
            sum += __shfl_xor(sum, 2);
            sum += __shfl_xor(sum, 4);
            sum += __shfl_xor(sum, 8);
            float inv = 1.f / sum;
#pragma unroll
            for (int j = 0; j < 13; j++)
                Pw[(lkg * 4 + rr) * 232 + j * 16 + l15] = f2bf(pv[j] * inv);
        }
        short8v pa[7];
#pragma unroll
        for (int kc = 0; kc < 7; kc++)
            pa[kc] = *(const short8v*)(&Pw[l15 * 232 + kc * 32 + lkg * 8]);
#pragma unroll
        for (int dj = 0; dj < 4; dj++){
            f32x4 oacc = {0.f, 0.f, 0.f, 0.f};
#pragma unroll
            for (int kc = 0; kc < 7; kc++){
                short8v vb = *(const short8v*)(&Vs[(dj * 16 + l15) * 232 + kc * 32 + lkg * 8]);
                oacc = __builtin_amdgcn_mfma_f32_16x16x32_bf16(pa[kc], vb, oacc, 0, 0, 0);
            }
#pragma unroll
            for (int rr = 0; rr < 4; rr++){
                int q = q0 + lkg * 4 + rr;
                if (q < Ntok)
                    o[(rb + q) * 768 + h * 64 + dj * 16 + l15] = f2bf(oacc[rr]);
            }
        }
    }
}

// ============ deep attention v3: 4 queries/block (round-14 winner, unchanged) ============
__global__ __launch_bounds__(256) void attn_deep_v3(
    const short* __restrict__ qkv, const float* __restrict__ prompts,
    const int* __restrict__ selm, short* __restrict__ o, int li)
{
    __shared__ float sc[4][208];
    const int b = blockIdx.x, g = blockIdx.y, t = threadIdx.x;
    const int lane = t & 63, w = t >> 6;
    const int n0 = g * 4;

    float4 q0[4], q1[4], q2[4];
#pragma unroll
    for (int qi = 0; qi < 4; qi++){
        int n = n0 + qi;
        int nn = (n < NT_) ? n : (NT_ - 1);
        const short* qr = qkv + (long)(b * NT_ + nn) * 2304;
        q0[qi] = ld4bf(qr + lane * 4);
        q1[qi] = ld4bf(qr + 256 + lane * 4);
        q2[qi] = ld4bf(qr + 512 + lane * 4);
    }

    const float* kp = prompts + ((long)selm[b] * 6 + 2 * li) * 5 * 768;
    const float* vp = kp + 5 * 768;

    for (int m = w; m < 202; m += 4){
        float4 k0, k1, k2;
        if (m < 5){
            const float* kr = kp + (long)m * 768;
            k0 = *(const float4*)(kr + lane * 4);
            k1 = *(const float4*)(kr + 256 + lane * 4);
            k2 = *(const float4*)(kr + 512 + lane * 4);
        } else {
            const short* kr = qkv + (long)(b * NT_ + (m - 5)) * 2304 + 768;
            k0 = ld4bf(kr + lane * 4);
            k1 = ld4bf(kr + 256 + lane * 4);
            k2 = ld4bf(kr + 512 + lane * 4);
        }
        float a[4];
#pragma unroll
        for (int qi = 0; qi < 4; qi++){
            a[qi] = q0[qi].x*k0.x + q0[qi].y*k0.y + q0[qi].z*k0.z + q0[qi].w*k0.w
                  + q1[qi].x*k1.x + q1[qi].y*k1.y + q1[qi].z*k1.z + q1[qi].w*k1.w
                  + q2[qi].x*k2.x + q2[qi].y*k2.y + q2[qi].z*k2.z + q2[qi].w*k2.w;
        }
#pragma unroll
        for (int off = 32; off; off >>= 1){
#pragma unroll
            for (int qi = 0; qi < 4; qi++) a[qi] += __shfl_xor(a[qi], off);
        }
        if (lane == 0){
#pragma unroll
            for (int qi = 0; qi < 4; qi++) sc[qi][m] = a[qi] * 0.125f;
        }
    }
    __syncthreads();

    {
        float v[4];
#pragma unroll
        for (int i = 0; i < 4; i++){
            int m = lane + i * 64;
            v[i] = (m < 202) ? sc[w][m] : -1e30f;
        }
        float mx = fmaxf(fmaxf(v[0], v[1]), fmaxf(v[2], v[3]));
#pragma unroll
        for (int off = 32; off; off >>= 1) mx = fmaxf(mx, __shfl_xor(mx, off));
        float e[4], sum = 0.f;
#pragma unroll
        for (int i = 0; i < 4; i++){
            int m = lane + i * 64;
            e[i] = (m < 202) ? expf(v[i] - mx) : 0.f;
            sum += e[i];
        }
#pragma unroll
        for (int off = 32; off; off >>= 1) sum += __shfl_xor(sum, off);
        float inv = 1.f / sum;
#pragma unroll
        for (int i = 0; i < 4; i++){
            int m = lane + i * 64;
            if (m < 202) sc[w][m] = e[i] * inv;
        }
    }
    __syncthreads();

    float a0[4] = {0.f,0.f,0.f,0.f}, a1[4] = {0.f,0.f,0.f,0.f}, a2[4] = {0.f,0.f,0.f,0.f};
    for (int m = 0; m < 5; m++){
        const float* vr = vp + (long)m * 768;
        float v0 = vr[t], v1 = vr[t + 256], v2 = vr[t + 512];
#pragma unroll
        for (int qi = 0; qi < 4; qi++){
            float pm = sc[qi][m];
            a0[qi] += pm * v0; a1[qi] += pm * v1; a2[qi] += pm * v2;
        }
    }
    for (int m = 5; m < 202; m++){
        const short* vr = qkv + (long)(b * NT_ + (m - 5)) * 2304 + 1536;
        float v0 = bf2f((unsigned short)vr[t]);
        float v1 = bf2f((unsigned short)vr[t + 256]);
        float v2 = bf2f((unsigned short)vr[t + 512]);
#pragma unroll
        for (int qi = 0; qi < 4; qi++){
            float pm = sc[qi][m];
            a0[qi] += pm * v0; a1[qi] += pm * v1; a2[qi] += pm * v2;
        }
    }
#pragma unroll
    for (int qi = 0; qi < 4; qi++){
        int n = n0 + qi;
        if (n < NT_){
            short* ob = o + (long)b * NT_ * 768 + n;
            ob[(long)t * 197]         = f2bf(a0[qi]);
            ob[(long)(t + 256) * 197] = f2bf(a1[qi]);
            ob[(long)(t + 512) * 197] = f2bf(a2[qi]);
        }
    }
}

// ============ patch unfold (f32 -> bf16) ============
__global__ void unfold_k(const float* __restrict__ in, short* __restrict__ out){
    long i = (long)blockIdx.x * 256 + threadIdx.x;
    long total = (long)B_ * 196 * 768;
    if (i >= total) return;
    int f = (int)(i % 768); long rw = i / 768;
    int t = (int)(rw % 196); int b = (int)(rw / 196);
    int gy = t / 14, gx = t % 14;
    int c = f >> 8, rem = f & 255, py = rem >> 4, px = rem & 15;
    out[i] = f2bf(in[(((long)(b * 3 + c) * 224) + gy * 16 + py) * 224 + gx * 16 + px]);
}

// ============ assemble x0 = [cls+pos ; patches+pos] (f32) ============
__global__ void assemble_k(const float* __restrict__ pe, const float* __restrict__ cls,
    const float* __restrict__ pos, float* __restrict__ x0){
    long i = (long)blockIdx.x * 256 + threadIdx.x;
    long total = (long)B_ * NT_ * 768;
    if (i >= total) return;
    int d = (int)(i % 768); long rw = i / 768;
    int n = (int)(rw % NT_); int b = (int)(rw / NT_);
    float v;
    if (n == 0) v = cls[d] + pos[d];
    else        v = pe[((long)b * 196 + (n - 1)) * 768 + d] + pos[(long)n * 768 + d];
    x0[i] = v;
}

__global__ void copy_f(const float* __restrict__ a, float* __restrict__ b, long total){
    long i = (long)blockIdx.x * 256 + threadIdx.x;
    if (i < total) b[i] = a[i];
}

// ============ build sub-branch rows ============
__global__ void build_sub_k(const float* __restrict__ x0, const float* __restrict__ subp,
    const float* __restrict__ pos, float* __restrict__ xSub){
    long i = (long)blockIdx.x * 256 + threadIdx.x;
    long total = (long)B_ * NS_ * 768;
    if (i >= total) return;
    int d = (int)(i % 768); long rw = i / 768;
    int n = (int)(rw % NS_); int b = (int)(rw / NS_);
    float v;
    if (n == 0)      v = x0[((long)b * NT_) * 768 + d];
    else if (n <= 5) v = subp[(n - 1) * 768 + d] + pos[d];
    else             v = x0[((long)b * NT_ + (n - 5)) * 768 + d];
    xSub[i] = v;
}

// ============ routing (f64 internals) ============
__global__ __launch_bounds__(256) void select_k(
    const float* __restrict__ xA, const float* __restrict__ norm_w,
    const float* __restrict__ norm_b, const float* __restrict__ main_key,
    const float* __restrict__ sub_key, const int* __restrict__ task_id_p,
    int* __restrict__ selm, int* __restrict__ flag)
{
    __shared__ double red[4];
    int b = blockIdx.x, t = threadIdx.x, lane = t & 63, wid = t >> 6;
    const float* xr = xA + (long)b * NT_ * 768;
    double v0 = xr[t], v1 = xr[t + 256], v2 = xr[t + 512];
    double S = block_reduce_sum_d(v0 + v1 + v2, red, lane, wid);
    double m = S * (1.0 / 768.0);
    double d0 = v0 - m, d1 = v1 - m, d2 = v2 - m;
    double Q = block_reduce_sum_d(d0*d0 + d1*d1 + d2*d2, red, lane, wid);
    double rs = 1.0 / sqrt(Q * (1.0 / 768.0) + 1e-6);
    double q0 = d0 * rs * (double)norm_w[t]       + (double)norm_b[t];
    double q1 = d1 * rs * (double)norm_w[t + 256] + (double)norm_b[t + 256];
    double q2 = d2 * rs * (double)norm_w[t + 512] + (double)norm_b[t + 512];
    double qn = block_reduce_sum_d(q0*q0 + q1*q1 + q2*q2, red, lane, wid);
    double qinv = 1.0 / sqrt(fmax(qn, 1e-12));

    int tk = *task_id_p;
    int ncand = tk + 2;
    double best = -1e300; int bsel = 0;
    for (int c = 0; c < ncand; c++){
        const float* cr = (c <= tk) ? (main_key + (long)c * 768) : sub_key;
        double c0 = cr[t], c1 = cr[t + 256], c2 = cr[t + 512];
        double dotq = block_reduce_sum_d(q0*c0 + q1*c1 + q2*c2, red, lane, wid);
        double nc   = block_reduce_sum_d(c0*c0 + c1*c1 + c2*c2, red, lane, wid);
        double sim = dotq * qinv * (1.0 / sqrt(fmax(nc, 1e-12)));
        if (sim > best){ best = sim; bsel = c; }
    }
    if (t == 0){
        int isMain = (bsel <= tk) ? 1 : 0;
        selm[b] = isMain ? bsel : 0;
        flag[b] = isMain;
    }
}

// ============ final head (f64 internals, f32 out) ============
__global__ __launch_bounds__(256) void head_k(
    const float* __restrict__ xM, const float* __restrict__ xSub,
    const float* __restrict__ norm_w, const float* __restrict__ norm_b,
    const float* __restrict__ fc_w, const float* __restrict__ fc_b,
    const int* __restrict__ flag, float* __restrict__ out)
{
    __shared__ double vec[768];
    __shared__ double red[4];
    int b = blockIdx.x, t = threadIdx.x, lane = t & 63, wid = t >> 6;
    int isMain = flag[b];
    double a0 = 0.0, a1 = 0.0, a2 = 0.0;
    int nrows = isMain ? 1 : 5;
    for (int rI = 0; rI < nrows; rI++){
        const float* xr = isMain ? (xM + (long)b * NT_ * 768)
                                 : (xSub + ((long)b * NS_ + 1 + rI) * 768);
        double v0 = xr[t], v1 = xr[t + 256], v2 = xr[t + 512];
        double S = block_reduce_sum_d(v0 + v1 + v2, red, lane, wid);
        double m = S * (1.0 / 768.0);
        double d0 = v0 - m, d1 = v1 - m, d2 = v2 - m;
        double Q = block_reduce_sum_d(d0*d0 + d1*d1 + d2*d2, red, lane, wid);
        double rs = 1.0 / sqrt(Q * (1.0 / 768.0) + 1e-6);
        a0 += d0 * rs * (double)norm_w[t]       + (double)norm_b[t];
        a1 += d1 * rs * (double)norm_w[t + 256] + (double)norm_b[t + 256];
        a2 += d2 * rs * (double)norm_w[t + 512] + (double)norm_b[t + 512];
    }
    double scl = isMain ? 1.0 : 0.2;
    vec[t] = a0 * scl; vec[t + 256] = a1 * scl; vec[t + 512] = a2 * scl;
    __syncthreads();
    if (t < NCLS_){
        const float* wr = fc_w + (long)t * 768;
        double acc = (double)fc_b[t];
#pragma unroll 8
        for (int j = 0; j < 768; j++) acc += vec[j] * (double)wr[j];
        out[b * NCLS_ + t] = (float)acc;
    }
}

// ================= host-side =================
struct Params {
    const float *qkv_w, *qkv_b, *proj_w, *proj_b;
    const float *ln1_w, *ln1_b, *ln2_w, *ln2_b;
    const float *fc1_w, *fc1_b, *fc2_w, *fc2_b;
    const float *prompts; const int* selm;
    short *lnb, *attb, *hidb;
    short *qkvb;
    const short *qkv_wc, *proj_wc, *fc1_wc, *fc2_wc;
    bool cache;
};

template<int EPI>
static void launch_gemm(hipStream_t st, const short* A, const float* Wf, const short* Wc,
                        bool cache, const float* bias, const float* Res,
                        float* Cf, short* Cb, int M, int K, int N)
{
    dim3 g(N / 128, (M + 127) / 128);
    if (cache)
        gemm_bf16<EPI, 1><<<g, 256, 0, st>>>(A, (const void*)Wc, bias, Res, Cf, Cb, M, K, N);
    else
        gemm_bf16<EPI, 0><<<g, 256, 0, st>>>(A, (const void*)Wf, bias, Res, Cf, Cb, M, K, N);
}

// mode 0: concat (std attn both segments)  mode 1: main std  mode 2: main deep
static void run_layer(hipStream_t st, float* x, int M, int layer, int mode, int li,
                      const Params& P)
{
    int lnGrid = (M + 3) / 4;
    ln_k<<<lnGrid, 256, 0, st>>>(x, P.ln1_w + layer * 768, P.ln1_b + layer * 768, P.lnb, M);
    launch_gemm<3>(st, P.lnb, P.qkv_w + (long)layer * 2304 * 768,
        P.qkv_wc + (P.cache ? (long)layer * 2304 * 768 : 0), P.cache,
        P.qkv_b + layer * 2304, nullptr, nullptr, P.qkvb, M, 768, 2304);
    if (mode == 0){
        attn_mfma<<<dim3(B_ * HEADS_, 2), 512, 0, st>>>(
            P.qkvb, P.attb, NT_, 0, 13,
            P.qkvb + (long)MROW_ * 2304, P.attb + (long)MROW_ * 768, NS_, 0, 13);
    } else if (mode == 1){
        attn_mfma<<<dim3(B_ * HEADS_, 2), 512, 0, st>>>(
            P.qkvb, P.attb, NT_, 0, 7,
            P.qkvb, P.attb, NT_, 7, 13);
    } else {
        attn_deep_v3<<<dim3(B_, 50), 256, 0, st>>>(P.qkvb, P.prompts, P.selm, P.attb, li);
    }
    launch_gemm<2>(st, P.attb, P.proj_w + (long)layer * 768 * 768,
        P.proj_wc + (P.cache ? (long)layer * 768 * 768 : 0), P.cache,
        P.proj_b + layer * 768, x, x, nullptr, M, 768, 768);
    ln_k<<<lnGrid, 256, 0, st>>>(x, P.ln2_w + layer * 768, P.ln2_b + layer * 768, P.lnb, M);
    launch_gemm<1>(st, P.lnb, P.fc1_w + (long)layer * 3072 * 768,
        P.fc1_wc + (P.cache ? (long)layer * 3072 * 768 : 0), P.cache,
        P.fc1_b + layer * 3072, nullptr, nullptr, P.hidb, M, 768, 3072);
    launch_gemm<2>(st, P.hidb, P.fc2_w + (long)layer * 768 * 3072,
        P.fc2_wc + (P.cache ? (long)layer * 768 * 3072 : 0), P.cache,
        P.fc2_b + layer * 768, x, x, nullptr, M, 3072, 768);
}

extern "C" void kernel_launch(void* const* d_in, const int* in_sizes, int n_in,
                              void* d_out, int out_size, void* d_ws, size_t ws_size,
                              hipStream_t stream)
{
    (void)in_sizes; (void)n_in; (void)out_size;
    const float* inputs   = (const float*)d_in[0];
    const int*   task_id  = (const int*)  d_in[1];
    const float* patch_w  = (const float*)d_in[2];
    const float* patch_b  = (const float*)d_in[3];
    const float* cls_tok  = (const float*)d_in[4];
    const float* pos      = (const float*)d_in[5];
    const float* qkv_w    = (const float*)d_in[6];
    const float* qkv_b    = (const float*)d_in[7];
    const float* proj_w   = (const float*)d_in[8];
    const float* proj_b   = (const float*)d_in[9];
    const float* ln1_w    = (const float*)d_in[10];
    const float* ln1_b    = (const float*)d_in[11];
    const float* ln2_w    = (const float*)d_in[12];
    const float* ln2_b    = (const float*)d_in[13];
    const float* fc1_w    = (const float*)d_in[14];
    const float* fc1_b    = (const float*)d_in[15];
    const float* fc2_w    = (const float*)d_in[16];
    const float* fc2_b    = (const float*)d_in[17];
    const float* norm_w   = (const float*)d_in[18];
    const float* norm_b   = (const float*)d_in[19];
    const float* fc_w     = (const float*)d_in[20];
    const float* fc_b     = (const float*)d_in[21];
    const float* main_key = (const float*)d_in[22];
    const float* sub_key  = (const float*)d_in[23];
    const float* m_prompts= (const float*)d_in[24];
    const float* s_prompt = (const float*)d_in[25];
    float* out = (float*)d_out;

    char* wsb = (char*)d_ws;
    size_t off = 0;
    auto allocB = [&](size_t bytes) -> void* {
        void* p = (void*)(wsb + off);
        off += (bytes + 255) & ~(size_t)255;
        return p;
    };
    float* x0   = (float*)allocB((size_t)MROW_ * 768 * 4);
    float* xC   = (float*)allocB((size_t)CROW_ * 768 * 4);
    float* xM   = (float*)allocB((size_t)MROW_ * 768 * 4);
    short* lnb  = (short*)allocB((size_t)(CROW_ + PAD_) * 768 * 2);
    short* attb = (short*)allocB((size_t)(CROW_ + PAD_) * 768 * 2);
    short* qkvb = (short*)allocB((size_t)(CROW_ + PAD_) * 2304 * 2);
    short* hidb = (short*)allocB((size_t)(CROW_ + PAD_) * 3072 * 2);
    float* peo  = (float*)allocB((size_t)3136 * 768 * 4);
    int*   selm = (int*)allocB(64);
    int*   flag = (int*)allocB(64);

    const size_t nQkv = (size_t)DEPTH_ * 2304 * 768;
    const size_t nProj = (size_t)DEPTH_ * 768 * 768;
    const size_t nFc1 = (size_t)DEPTH_ * 3072 * 768;
    const size_t nFc2 = (size_t)DEPTH_ * 768 * 3072;
    const size_t nPatch = (size_t)768 * 768;
    size_t cacheBytes = (nQkv + nProj + nFc1 + nFc2 + nPatch) * 2 + 5 * 256;
    bool cache = (ws_size >= off + cacheBytes + (1u << 20));
    short *qkv_wc = nullptr, *proj_wc = nullptr, *fc1_wc = nullptr, *fc2_wc = nullptr, *patch_wc = nullptr;
    if (cache){
        qkv_wc  = (short*)allocB(nQkv * 2);
        proj_wc = (short*)allocB(nProj * 2);
        fc1_wc  = (short*)allocB(nFc1 * 2);
        fc2_wc  = (short*)allocB(nFc2 * 2);
        patch_wc= (short*)allocB(nPatch * 2);
        convert_w_k<<<2048, 256, 0, stream>>>(qkv_w,  qkv_wc,  (long)nQkv);
        convert_w_k<<<1024, 256, 0, stream>>>(proj_w, proj_wc, (long)nProj);
        convert_w_k<<<2048, 256, 0, stream>>>(fc1_w,  fc1_wc,  (long)nFc1);
        convert_w_k<<<2048, 256, 0, stream>>>(fc2_w,  fc2_wc,  (long)nFc2);
        convert_w_k<<<256,  256, 0, stream>>>(patch_w, patch_wc, (long)nPatch);
    }

    Params P;
    P.qkv_w = qkv_w; P.qkv_b = qkv_b; P.proj_w = proj_w; P.proj_b = proj_b;
    P.ln1_w = ln1_w; P.ln1_b = ln1_b; P.ln2_w = ln2_w; P.ln2_b = ln2_b;
    P.fc1_w = fc1_w; P.fc1_b = fc1_b; P.fc2_w = fc2_w; P.fc2_b = fc2_b;
    P.prompts = m_prompts; P.selm = selm;
    P.lnb = lnb; P.attb = attb; P.hidb = hidb; P.qkvb = qkvb;
    P.qkv_wc = qkv_wc; P.proj_wc = proj_wc; P.fc1_wc = fc1_wc; P.fc2_wc = fc2_wc;
    P.cache = cache;

    const long XN = (long)MROW_ * 768;

    // -------- patch embed --------
    {
        long tot = (long)B_ * 196 * 768;
        short* un = hidb;
        unfold_k<<<(int)((tot + 255) / 256), 256, 0, stream>>>(inputs, un);
        launch_gemm<0>(stream, un, patch_w, patch_wc, cache, patch_b, nullptr,
                       peo, nullptr, 3136, 768, 768);
        assemble_k<<<(int)((XN + 255) / 256), 256, 0, stream>>>(peo, cls_tok, pos, x0);
        copy_f<<<(int)((XN + 255) / 256), 256, 0, stream>>>(x0, xC, XN);
        long st = (long)SROW_ * 768;
        build_sub_k<<<(int)((st + 255) / 256), 256, 0, stream>>>(x0, s_prompt, pos,
                                                                 xC + (long)MROW_ * 768);
    }

    // -------- concatenated pass A + sub branch --------
    for (int i = 0; i < DEPTH_; i++){
        run_layer(stream, xC, CROW_, i, 0, 0, P);
        if (i == 1)
            copy_f<<<(int)((XN + 255) / 256), 256, 0, stream>>>(xC, xM, XN);
    }

    // -------- routing --------
    select_k<<<16, 256, 0, stream>>>(xC, norm_w, norm_b, main_key, sub_key,
                                     task_id, selm, flag);

    // -------- main branch layers 2..11 (deep prompts at 2,3,4) --------
    for (int i = 2; i < DEPTH_; i++){
        int mode = (i >= 2 && i <= 4) ? 2 : 1;
        run_layer(stream, xM, MROW_, i, mode, i - 2, P);
    }

    // -------- heads + per-sample select --------
    head_k<<<16, 256, 0, stream>>>(xM, xC + (long)MROW_ * 768, norm_w, norm_b,
                                   fc_w, fc_b, flag, out);
}

// Round 16
// 5342.883 us; speedup vs baseline: 1.1878x; 1.0171x over previous
//
#include <hip/hip_runtime.h>
#include <math.h>

// ---------------- constants ----------------
#define B_    16
#define NT_   197
#define NS_   202
#define HEADS_ 12
#define DEPTH_ 12
#define NCLS_ 100
#define MROW_ (B_ * NT_)      // 3152
#define SROW_ (B_ * NS_)      // 3232
#define CROW_ (MROW_ + SROW_) // 6384
#define PAD_  128             // GEMM-A row padding (global_load_lds has no row guard)
#define TAILC_ 96             // concat tail rows: 16 CLS + 16*5 sub-prompt rows
#define TAILM_ 16             // main tail rows: 16 CLS

typedef __attribute__((ext_vector_type(8))) short short8v;
typedef __attribute__((ext_vector_type(4))) float f32x4;

// f32 -> bf16 bits (RNE)
__device__ __forceinline__ short f2bf(float f){
    unsigned u = __builtin_bit_cast(unsigned, f);
    unsigned r = (u + 0x7FFFu + ((u >> 16) & 1u)) >> 16;
    return (short)r;
}
__device__ __forceinline__ unsigned pk2(float a, float b){
    return (unsigned)(unsigned short)f2bf(a) | (((unsigned)(unsigned short)f2bf(b)) << 16);
}
__device__ __forceinline__ float bf2f(unsigned short s){
    unsigned u = ((unsigned)s) << 16;
    return __builtin_bit_cast(float, u);
}
__device__ __forceinline__ float4 ld4bf(const short* p){
    uint2 u = *(const uint2*)p;
    float4 r;
    r.x = bf2f((unsigned short)(u.x & 0xffff));
    r.y = bf2f((unsigned short)(u.x >> 16));
    r.z = bf2f((unsigned short)(u.y & 0xffff));
    r.w = bf2f((unsigned short)(u.y >> 16));
    return r;
}
// async global->LDS, 16B per lane; lds base must be wave-uniform
__device__ __forceinline__ void gld16(const short* g, short* l){
    __builtin_amdgcn_global_load_lds(
        (const __attribute__((address_space(1))) unsigned*)g,
        (__attribute__((address_space(3))) unsigned*)l, 16, 0, 0);
}

// ============ double block reduce (256 thr) — routing/head only ============
__device__ __forceinline__ double block_reduce_sum_d(double s, double* red, int lane, int wid){
#pragma unroll
    for (int off = 32; off; off >>= 1) s += __shfl_xor(s, off);
    if (lane == 0) red[wid] = s;
    __syncthreads();
    double S = red[0] + red[1] + red[2] + red[3];
    __syncthreads();
    return S;
}

// ============ weight convert f32 -> bf16 ============
__global__ void convert_w_k(const float* __restrict__ in, short* __restrict__ out, long n){
    long i = ((long)blockIdx.x * 256 + threadIdx.x) * 8;
    long stride = (long)gridDim.x * 256 * 8;
    for (; i < n; i += stride){
        float4 a = *(const float4*)(in + i);
        float4 b = *(const float4*)(in + i + 4);
        uint4 o4;
        o4.x = pk2(a.x, a.y); o4.y = pk2(a.z, a.w);
        o4.z = pk2(b.x, b.y); o4.w = pk2(b.z, b.w);
        *(uint4*)(out + i) = o4;
    }
}

// ============ bf16 MFMA GEMM, BK=64 (round-15 winner, unchanged) ============
template<int EPI, int WB>
__global__ __launch_bounds__(256) void gemm_bf16(
    const short* __restrict__ A, const void* __restrict__ Wv,
    const float* __restrict__ bias, const float* __restrict__ Res,
    float* __restrict__ Cf, short* __restrict__ Cb, int M, int K, int N)
{
    __shared__ short As0[128 * 32];
    __shared__ short As1[128 * 32];
    __shared__ short Bs0[128 * 32];
    __shared__ short Bs1[128 * 32];
    const int t = threadIdx.x;
    const int lane = t & 63, wid = t >> 6;
    const int wr = wid >> 1, wc = wid & 1;
    const long row0 = (long)blockIdx.y * 128;
    const long col0 = (long)blockIdx.x * 128;

    f32x4 acc[4][4];
#pragma unroll
    for (int i = 0; i < 4; i++)
#pragma unroll
        for (int j = 0; j < 4; j++) acc[i][j] = (f32x4){0.f, 0.f, 0.f, 0.f};

    const int l15 = lane & 15, lkg = lane >> 4;
    const int lrow = lane >> 2;
    const int lcol = (lane & 3) * 8;

    for (int k0 = 0; k0 < K; k0 += 64){
#pragma unroll
        for (int i = 0; i < 2; i++){
            int rb = wid * 32 + i * 16;
            const short* gs = A + (row0 + rb + lrow) * K + k0 + lcol;
            gld16(gs,      &As0[rb * 32]);
            gld16(gs + 32, &As1[rb * 32]);
        }
        if (WB == 1){
            const short* Wb = (const short*)Wv;
#pragma unroll
            for (int i = 0; i < 2; i++){
                int rb = wid * 32 + i * 16;
                const short* gs = Wb + (col0 + rb + lrow) * K + k0 + lcol;
                gld16(gs,      &Bs0[rb * 32]);
                gld16(gs + 32, &Bs1[rb * 32]);
            }
        } else {
            const float* Wf = (const float*)Wv;
            const int bn = t >> 1, bh = t & 1;
#pragma unroll
            for (int half = 0; half < 2; half++){
                const float* Wp = Wf + (col0 + bn) * K + k0 + half * 32 + bh * 16;
                unsigned rr[8];
#pragma unroll
                for (int g = 0; g < 8; g++){
                    float2 f = *(const float2*)(Wp + g * 2);
                    rr[g] = pk2(f.x, f.y);
                }
                uint4 lo = {rr[0], rr[1], rr[2], rr[3]};
                uint4 hi = {rr[4], rr[5], rr[6], rr[7]};
                short* Bsh = half ? Bs1 : Bs0;
                *(uint4*)(&Bsh[bn * 32 + bh * 16])     = lo;
                *(uint4*)(&Bsh[bn * 32 + bh * 16 + 8]) = hi;
            }
        }
        __syncthreads();

        {
            short8v a[4], b[4];
#pragma unroll
            for (int i = 0; i < 4; i++)
                a[i] = *(const short8v*)(&As0[(wr * 64 + i * 16 + l15) * 32 + lkg * 8]);
#pragma unroll
            for (int j = 0; j < 4; j++)
                b[j] = *(const short8v*)(&Bs0[(wc * 64 + j * 16 + l15) * 32 + lkg * 8]);
#pragma unroll
            for (int i = 0; i < 4; i++)
#pragma unroll
                for (int j = 0; j < 4; j++)
                    acc[i][j] = __builtin_amdgcn_mfma_f32_16x16x32_bf16(a[i], b[j], acc[i][j], 0, 0, 0);
        }
        {
            short8v a[4], b[4];
#pragma unroll
            for (int i = 0; i < 4; i++)
                a[i] = *(const short8v*)(&As1[(wr * 64 + i * 16 + l15) * 32 + lkg * 8]);
#pragma unroll
            for (int j = 0; j < 4; j++)
                b[j] = *(const short8v*)(&Bs1[(wc * 64 + j * 16 + l15) * 32 + lkg * 8]);
#pragma unroll
            for (int i = 0; i < 4; i++)
#pragma unroll
                for (int j = 0; j < 4; j++)
                    acc[i][j] = __builtin_amdgcn_mfma_f32_16x16x32_bf16(a[i], b[j], acc[i][j], 0, 0, 0);
        }
        __syncthreads();
    }

#pragma unroll
    for (int i = 0; i < 4; i++){
#pragma unroll
        for (int q = 0; q < 4; q++){
            long gr = row0 + wr * 64 + i * 16 + lkg * 4 + q;
            if (gr >= M) continue;
#pragma unroll
            for (int j = 0; j < 4; j++){
                long gc = col0 + wc * 64 + j * 16 + l15;
                float v = acc[i][j][q] + bias[gc];
                if (EPI == 1){
                    v = 0.5f * v * (1.f + erff(v * 0.70710678118654752f));
                    Cb[gr * N + gc] = f2bf(v);
                } else if (EPI == 2){
                    Cf[gr * N + gc] = v + Res[gr * N + gc];
                } else if (EPI == 3){
                    Cb[gr * N + gc] = f2bf(v);
                } else {
                    Cf[gr * N + gc] = v;
                }
            }
        }
    }
}

// ============ LayerNorm: wave-per-row (unchanged) ============
__global__ __launch_bounds__(256) void ln_k(const float* __restrict__ x,
    const float* __restrict__ w, const float* __restrict__ b,
    short* __restrict__ y, int M)
{
    const int lane = threadIdx.x & 63, wv = threadIdx.x >> 6;
    const int row = blockIdx.x * 4 + wv;
    if (row >= M) return;
    const float* xr = x + (long)row * 768;
    float v[12];
    float s = 0.f;
#pragma unroll
    for (int j = 0; j < 12; j++){ v[j] = xr[lane + j * 64]; s += v[j]; }
#pragma unroll
    for (int off = 32; off; off >>= 1) s += __shfl_xor(s, off);
    float m = s * (1.f / 768.f);
    float q = 0.f;
#pragma unroll
    for (int j = 0; j < 12; j++){ v[j] -= m; q += v[j] * v[j]; }
#pragma unroll
    for (int off = 32; off; off >>= 1) q += __shfl_xor(q, off);
    float rs = 1.f / sqrtf(q * (1.f / 768.f) + 1e-6f);
    short* yr = y + (long)row * 768;
#pragma unroll
    for (int j = 0; j < 12; j++)
        yr[lane + j * 64] = f2bf(v[j] * rs * w[lane + j * 64] + b[lane + j * 64]);
}

// ============ std MHA via MFMA (unchanged) ============
__global__ __launch_bounds__(512) void attn_mfma(
    const short* __restrict__ qkv0, short* __restrict__ o0, int N0, int tb0, int te0,
    const short* __restrict__ qkv1, short* __restrict__ o1, int N1, int tb1, int te1)
{
    __shared__ short Ks[208 * 72];
    __shared__ short Vs[64 * 232];
    __shared__ short Ps[8 * 16 * 232];
    const int bh = blockIdx.x;
    const int b = bh / HEADS_, h = bh % HEADS_;
    const int seg = blockIdx.y;
    const short* qkv = seg ? qkv1 : qkv0;
    short* o = seg ? o1 : o0;
    const int Ntok = seg ? N1 : N0;
    const int tb = seg ? tb1 : tb0;
    const int te = seg ? te1 : te0;
    const int t = threadIdx.x, lane = t & 63, wid = t >> 6;
    const long rb = (long)b * Ntok;

    {
        const int r = t >> 2, c = (t & 3) * 16;
#pragma unroll
        for (int pass = 0; pass < 2; pass++){
            int m = r + pass * 128;
            if (m < 208){
                if (m < Ntok){
                    const short* kr = qkv + (rb + m) * 2304 + 768  + h * 64 + c;
                    const short* vr = qkv + (rb + m) * 2304 + 1536 + h * 64 + c;
                    *(uint4*)(&Ks[m * 72 + c])     = *(const uint4*)(kr);
                    *(uint4*)(&Ks[m * 72 + c + 8]) = *(const uint4*)(kr + 8);
#pragma unroll
                    for (int j = 0; j < 16; j++)
                        Vs[(c + j) * 232 + m] = vr[j];
                } else {
#pragma unroll
                    for (int j = 0; j < 16; j += 2)
                        *(unsigned*)(&Ks[m * 72 + c + j]) = 0u;
#pragma unroll
                    for (int j = 0; j < 16; j++)
                        Vs[(c + j) * 232 + m] = 0;
                }
            }
        }
        for (int i = t; i < 64 * 16; i += 512){
            int d = i >> 4, m = 208 + (i & 15);
            Vs[d * 232 + m] = 0;
        }
        for (int i = t; i < 8 * 16 * 16; i += 512){
            int w = i >> 8, rr = (i >> 4) & 15, m = 208 + (i & 15);
            Ps[(w * 16 + rr) * 232 + m] = 0;
        }
    }
    __syncthreads();

    const int l15 = lane & 15, lkg = lane >> 4;
    short* Pw = &Ps[wid * 16 * 232];

    for (int s = tb + wid; s < te; s += 8){
        const int q0 = s * 16;
        short8v a0, a1;
        {
            int qrow = q0 + l15;
            if (qrow < Ntok){
                const short* qp = qkv + (rb + qrow) * 2304 + h * 64;
                a0 = *(const short8v*)(qp + lkg * 8);
                a1 = *(const short8v*)(qp + 32 + lkg * 8);
            } else {
                uint4 z = {0u,0u,0u,0u};
                a0 = __builtin_bit_cast(short8v, z);
                a1 = __builtin_bit_cast(short8v, z);
            }
        }
        f32x4 sacc[13];
#pragma unroll
        for (int j = 0; j < 13; j++){
            short8v b0 = *(const short8v*)(&Ks[(j * 16 + l15) * 72 + lkg * 8]);
            short8v b1 = *(const short8v*)(&Ks[(j * 16 + l15) * 72 + 32 + lkg * 8]);
            f32x4 z = {0.f, 0.f, 0.f, 0.f};
            z = __builtin_amdgcn_mfma_f32_16x16x32_bf16(a0, b0, z, 0, 0, 0);
            z = __builtin_amdgcn_mfma_f32_16x16x32_bf16(a1, b1, z, 0, 0, 0);
            sacc[j][0] = z[0] * 0.125f; sacc[j][1] = z[1] * 0.125f;
            sacc[j][2] = z[2] * 0.125f; sacc[j][3] = z[3] * 0.125f;
        }
#pragma unroll
        for (int j = 0; j < 13; j++){
            if (j * 16 + l15 >= Ntok){
                sacc[j][0] = -1e30f; sacc[j][1] = -1e30f;
                sacc[j][2] = -1e30f; sacc[j][3] = -1e30f;
            }
        }
#pragma unroll
        for (int rr = 0; rr < 4; rr++){
            float mx = sacc[0][rr];
#pragma unroll
            for (int j = 1; j < 13; j++) mx = fmaxf(mx, sacc[j][rr]);
            mx = fmaxf(mx, __shfl_xor(mx, 1));
            mx = fmaxf(mx, __shfl_xor(mx, 2));
            mx = fmaxf(mx, __shfl_xor(mx, 4));
            mx = fmaxf(mx, __shfl_xor(mx, 8));
            float pv[13];
            float sum = 0.f;
#pragma unroll
            for (int j = 0; j < 13; j++){
                float e = expf(sacc[j][rr] - mx);
                pv[j] = e; sum += e;
            }
            sum += __shfl_xor(sum, 1);
            sum += __shfl_xor(sum, 2);
            sum += __shfl_xor(sum, 4);
            sum += __shfl_xor(sum, 8);
            float inv = 1.f / sum;
#pragma unroll
            for (int j = 0; j < 13; j++)
                Pw[(lkg * 4 + rr) * 232 + j * 16 + l15] = f2bf(pv[j] * inv);
        }
        short8v pa[7];
#pragma unroll
        for (int kc = 0; kc < 7; kc++)
            pa[kc] = *(const short8v*)(&Pw[l15 * 232 + kc * 32 + lkg * 8]);
#pragma unroll
        for (int dj = 0; dj < 4; dj++){
            f32x4 oacc = {0.f, 0.f, 0.f, 0.f};
#pragma unroll
            for (int kc = 0; kc < 7; kc++){
                short8v vb = *(const short8v*)(&Vs[(dj * 16 + l15) * 232 + kc * 32 + lkg * 8]);
                oacc = __builtin_amdgcn_mfma_f32_16x16x32_bf16(pa[kc], vb, oacc, 0, 0, 0);
            }
#pragma unroll
            for (int rr = 0; rr < 4; rr++){
                int q = q0 + lkg * 4 + rr;
                if (q < Ntok)
                    o[(rb + q) * 768 + h * 64 + dj * 16 + l15] = f2bf(oacc[rr]);
            }
        }
    }
}

// ============ deep attention v3 (unchanged) ============
__global__ __launch_bounds__(256) void attn_deep_v3(
    const short* __restrict__ qkv, const float* __restrict__ prompts,
    const int* __restrict__ selm, short* __restrict__ o, int li)
{
    __shared__ float sc[4][208];
    const int b = blockIdx.x, g = blockIdx.y, t = threadIdx.x;
    const int lane = t & 63, w = t >> 6;
    const int n0 = g * 4;

    float4 q0[4], q1[4], q2[4];
#pragma unroll
    for (int qi = 0; qi < 4; qi++){
        int n = n0 + qi;
        int nn = (n < NT_) ? n : (NT_ - 1);
        const short* qr = qkv + (long)(b * NT_ + nn) * 2304;
        q0[qi] = ld4bf(qr + lane * 4);
        q1[qi] = ld4bf(qr + 256 + lane * 4);
        q2[qi] = ld4bf(qr + 512 + lane * 4);
    }

    const float* kp = prompts + ((long)selm[b] * 6 + 2 * li) * 5 * 768;
    const float* vp = kp + 5 * 768;

    for (int m = w; m < 202; m += 4){
        float4 k0, k1, k2;
        if (m < 5){
            const float* kr = kp + (long)m * 768;
            k0 = *(const float4*)(kr + lane * 4);
            k1 = *(const float4*)(kr + 256 + lane * 4);
            k2 = *(const float4*)(kr + 512 + lane * 4);
        } else {
            const short* kr = qkv + (long)(b * NT_ + (m - 5)) * 2304 + 768;
            k0 = ld4bf(kr + lane * 4);
            k1 = ld4bf(kr + 256 + lane * 4);
            k2 = ld4bf(kr + 512 + lane * 4);
        }
        float a[4];
#pragma unroll
        for (int qi = 0; qi < 4; qi++){
            a[qi] = q0[qi].x*k0.x + q0[qi].y*k0.y + q0[qi].z*k0.z + q0[qi].w*k0.w
                  + q1[qi].x*k1.x + q1[qi].y*k1.y + q1[qi].z*k1.z + q1[qi].w*k1.w
                  + q2[qi].x*k2.x + q2[qi].y*k2.y + q2[qi].z*k2.z + q2[qi].w*k2.w;
        }
#pragma unroll
        for (int off = 32; off; off >>= 1){
#pragma unroll
            for (int qi = 0; qi < 4; qi++) a[qi] += __shfl_xor(a[qi], off);
        }
        if (lane == 0){
#pragma unroll
            for (int qi = 0; qi < 4; qi++) sc[qi][m] = a[qi] * 0.125f;
        }
    }
    __syncthreads();

    {
        float v[4];
#pragma unroll
        for (int i = 0; i < 4; i++){
            int m = lane + i * 64;
            v[i] = (m < 202) ? sc[w][m] : -1e30f;
        }
        float mx = fmaxf(fmaxf(v[0], v[1]), fmaxf(v[2], v[3]));
#pragma unroll
        for (int off = 32; off; off >>= 1) mx = fmaxf(mx, __shfl_xor(mx, off));
        float e[4], sum = 0.f;
#pragma unroll
        for (int i = 0; i < 4; i++){
            int m = lane + i * 64;
            e[i] = (m < 202) ? expf(v[i] - mx) : 0.f;
            sum += e[i];
        }
#pragma unroll
        for (int off = 32; off; off >>= 1) sum += __shfl_xor(sum, off);
        float inv = 1.f / sum;
#pragma unroll
        for (int i = 0; i < 4; i++){
            int m = lane + i * 64;
            if (m < 202) sc[w][m] = e[i] * inv;
        }
    }
    __syncthreads();

    float a0[4] = {0.f,0.f,0.f,0.f}, a1[4] = {0.f,0.f,0.f,0.f}, a2[4] = {0.f,0.f,0.f,0.f};
    for (int m = 0; m < 5; m++){
        const float* vr = vp + (long)m * 768;
        float v0 = vr[t], v1 = vr[t + 256], v2 = vr[t + 512];
#pragma unroll
        for (int qi = 0; qi < 4; qi++){
            float pm = sc[qi][m];
            a0[qi] += pm * v0; a1[qi] += pm * v1; a2[qi] += pm * v2;
        }
    }
    for (int m = 5; m < 202; m++){
        const short* vr = qkv + (long)(b * NT_ + (m - 5)) * 2304 + 1536;
        float v0 = bf2f((unsigned short)vr[t]);
        float v1 = bf2f((unsigned short)vr[t + 256]);
        float v2 = bf2f((unsigned short)vr[t + 512]);
#pragma unroll
        for (int qi = 0; qi < 4; qi++){
            float pm = sc[qi][m];
            a0[qi] += pm * v0; a1[qi] += pm * v1; a2[qi] += pm * v2;
        }
    }
#pragma unroll
    for (int qi = 0; qi < 4; qi++){
        int n = n0 + qi;
        if (n < NT_){
            short* ob = o + (long)b * NT_ * 768 + n;
            ob[(long)t * 197]         = f2bf(a0[qi]);
            ob[(long)(t + 256) * 197] = f2bf(a1[qi]);
            ob[(long)(t + 512) * 197] = f2bf(a2[qi]);
        }
    }
}

// ============ tail gathers: mode 0 = concat (16 CLS + 80 sub), mode 1 = main CLS ============
__device__ __forceinline__ long tail_src_row(int r, int mode){
    if (mode == 1) return (long)r * NT_;
    if (r < 16)    return (long)r * NT_;
    int j = r - 16;
    return (long)MROW_ + (long)(j / 5) * NS_ + 1 + (j % 5);
}
__global__ void gather_tail_f(const float* __restrict__ src, float* __restrict__ dst,
                              int nrows, int mode){
    long i = (long)blockIdx.x * 256 + threadIdx.x;
    long total = (long)nrows * 768;
    if (i >= total) return;
    int r = (int)(i / 768), d = (int)(i % 768);
    dst[i] = src[tail_src_row(r, mode) * 768 + d];
}
__global__ void gather_tail_b(const short* __restrict__ src, short* __restrict__ dst,
                              int nrows, int mode){
    long i = (long)blockIdx.x * 256 + threadIdx.x;
    long total = (long)nrows * 768;
    if (i >= total) return;
    int r = (int)(i / 768), d = (int)(i % 768);
    dst[i] = src[tail_src_row(r, mode) * 768 + d];
}

// ============ patch unfold (f32 -> bf16) ============
__global__ void unfold_k(const float* __restrict__ in, short* __restrict__ out){
    long i = (long)blockIdx.x * 256 + threadIdx.x;
    long total = (long)B_ * 196 * 768;
    if (i >= total) return;
    int f = (int)(i % 768); long rw = i / 768;
    int t = (int)(rw % 196); int b = (int)(rw / 196);
    int gy = t / 14, gx = t % 14;
    int c = f >> 8, rem = f & 255, py = rem >> 4, px = rem & 15;
    out[i] = f2bf(in[(((long)(b * 3 + c) * 224) + gy * 16 + py) * 224 + gx * 16 + px]);
}

// ============ assemble x0 = [cls+pos ; patches+pos] (f32) ============
__global__ void assemble_k(const float* __restrict__ pe, const float* __restrict__ cls,
    const float* __restrict__ pos, float* __restrict__ x0){
    long i = (long)blockIdx.x * 256 + threadIdx.x;
    long total = (long)B_ * NT_ * 768;
    if (i >= total) return;
    int d = (int)(i % 768); long rw = i / 768;
    int n = (int)(rw % NT_); int b = (int)(rw / NT_);
    float v;
    if (n == 0) v = cls[d] + pos[d];
    else        v = pe[((long)b * 196 + (n - 1)) * 768 + d] + pos[(long)n * 768 + d];
    x0[i] = v;
}

__global__ void copy_f(const float* __restrict__ a, float* __restrict__ b, long total){
    long i = (long)blockIdx.x * 256 + threadIdx.x;
    if (i < total) b[i] = a[i];
}

// ============ build sub-branch rows ============
__global__ void build_sub_k(const float* __restrict__ x0, const float* __restrict__ subp,
    const float* __restrict__ pos, float* __restrict__ xSub){
    long i = (long)blockIdx.x * 256 + threadIdx.x;
    long total = (long)B_ * NS_ * 768;
    if (i >= total) return;
    int d = (int)(i % 768); long rw = i / 768;
    int n = (int)(rw % NS_); int b = (int)(rw / NS_);
    float v;
    if (n == 0)      v = x0[((long)b * NT_) * 768 + d];
    else if (n <= 5) v = subp[(n - 1) * 768 + d] + pos[d];
    else             v = x0[((long)b * NT_ + (n - 5)) * 768 + d];
    xSub[i] = v;
}

// ============ routing (f64 internals) — reads compact tail buffer, row b ============
__global__ __launch_bounds__(256) void select_k(
    const float* __restrict__ xT, const float* __restrict__ norm_w,
    const float* __restrict__ norm_b, const float* __restrict__ main_key,
    const float* __restrict__ sub_key, const int* __restrict__ task_id_p,
    int* __restrict__ selm, int* __restrict__ flag)
{
    __shared__ double red[4];
    int b = blockIdx.x, t = threadIdx.x, lane = t & 63, wid = t >> 6;
    const float* xr = xT + (long)b * 768;
    double v0 = xr[t], v1 = xr[t + 256], v2 = xr[t + 512];
    double S = block_reduce_sum_d(v0 + v1 + v2, red, lane, wid);
    double m = S * (1.0 / 768.0);
    double d0 = v0 - m, d1 = v1 - m, d2 = v2 - m;
    double Q = block_reduce_sum_d(d0*d0 + d1*d1 + d2*d2, red, lane, wid);
    double rs = 1.0 / sqrt(Q * (1.0 / 768.0) + 1e-6);
    double q0 = d0 * rs * (double)norm_w[t]       + (double)norm_b[t];
    double q1 = d1 * rs * (double)norm_w[t + 256] + (double)norm_b[t + 256];
    double q2 = d2 * rs * (double)norm_w[t + 512] + (double)norm_b[t + 512];
    double qn = block_reduce_sum_d(q0*q0 + q1*q1 + q2*q2, red, lane, wid);
    double qinv = 1.0 / sqrt(fmax(qn, 1e-12));

    int tk = *task_id_p;
    int ncand = tk + 2;
    double best = -1e300; int bsel = 0;
    for (int c = 0; c < ncand; c++){
        const float* cr = (c <= tk) ? (main_key + (long)c * 768) : sub_key;
        double c0 = cr[t], c1 = cr[t + 256], c2 = cr[t + 512];
        double dotq = block_reduce_sum_d(q0*c0 + q1*c1 + q2*c2, red, lane, wid);
        double nc   = block_reduce_sum_d(c0*c0 + c1*c1 + c2*c2, red, lane, wid);
        double sim = dotq * qinv * (1.0 / sqrt(fmax(nc, 1e-12)));
        if (sim > best){ best = sim; bsel = c; }
    }
    if (t == 0){
        int isMain = (bsel <= tk) ? 1 : 0;
        selm[b] = isMain ? bsel : 0;
        flag[b] = isMain;
    }
}

// ============ final head (f64 internals) — reads compact tail buffers ============
__global__ __launch_bounds__(256) void head_k(
    const float* __restrict__ xMT, const float* __restrict__ xT,
    const float* __restrict__ norm_w, const float* __restrict__ norm_b,
    const float* __restrict__ fc_w, const float* __restrict__ fc_b,
    const int* __restrict__ flag, float* __restrict__ out)
{
    __shared__ double vec[768];
    __shared__ double red[4];
    int b = blockIdx.x, t = threadIdx.x, lane = t & 63, wid = t >> 6;
    int isMain = flag[b];
    double a0 = 0.0, a1 = 0.0, a2 = 0.0;
    int nrows = isMain ? 1 : 5;
    for (int rI = 0; rI < nrows; rI++){
        const float* xr = isMain ? (xMT + (long)b * 768)
                                 : (xT + (long)(16 + b * 5 + rI) * 768);
        double v0 = xr[t], v1 = xr[t + 256], v2 = xr[t + 512];
        double S = block_reduce_sum_d(v0 + v1 + v2, red, lane, wid);
        double m = S * (1.0 / 768.0);
        double d0 = v0 - m, d1 = v1 - m, d2 = v2 - m;
        double Q = block_reduce_sum_d(d0*d0 + d1*d1 + d2*d2, red, lane, wid);
        double rs = 1.0 / sqrt(Q * (1.0 / 768.0) + 1e-6);
        a0 += d0 * rs * (double)norm_w[t]       + (double)norm_b[t];
        a1 += d1 * rs * (double)norm_w[t + 256] + (double)norm_b[t + 256];
        a2 += d2 * rs * (double)norm_w[t + 512] + (double)norm_b[t + 512];
    }
    double scl = isMain ? 1.0 : 0.2;
    vec[t] = a0 * scl; vec[t + 256] = a1 * scl; vec[t + 512] = a2 * scl;
    __syncthreads();
    if (t < NCLS_){
        const float* wr = fc_w + (long)t * 768;
        double acc = (double)fc_b[t];
#pragma unroll 8
        for (int j = 0; j < 768; j++) acc += vec[j] * (double)wr[j];
        out[b * NCLS_ + t] = (float)acc;
    }
}

// ================= host-side =================
struct Params {
    const float *qkv_w, *qkv_b, *proj_w, *proj_b;
    const float *ln1_w, *ln1_b, *ln2_w, *ln2_b;
    const float *fc1_w, *fc1_b, *fc2_w, *fc2_b;
    const float *prompts; const int* selm;
    short *lnb, *attb, *hidb;
    short *qkvb;
    const short *qkv_wc, *proj_wc, *fc1_wc, *fc2_wc;
    bool cache;
    // tail scratch
    float *xT, *xMT;
    short *attbT, *lnbT, *hidT;
};

template<int EPI>
static void launch_gemm(hipStream_t st, const short* A, const float* Wf, const short* Wc,
                        bool cache, const float* bias, const float* Res,
                        float* Cf, short* Cb, int M, int K, int N)
{
    dim3 g(N / 128, (M + 127) / 128);
    if (cache)
        gemm_bf16<EPI, 1><<<g, 256, 0, st>>>(A, (const void*)Wc, bias, Res, Cf, Cb, M, K, N);
    else
        gemm_bf16<EPI, 0><<<g, 256, 0, st>>>(A, (const void*)Wf, bias, Res, Cf, Cb, M, K, N);
}

// mode 0: concat (std attn both segments)  mode 1: main std  mode 2: main deep
static void run_layer(hipStream_t st, float* x, int M, int layer, int mode, int li,
                      const Params& P)
{
    int lnGrid = (M + 3) / 4;
    ln_k<<<lnGrid, 256, 0, st>>>(x, P.ln1_w + layer * 768, P.ln1_b + layer * 768, P.lnb, M);
    launch_gemm<3>(st, P.lnb, P.qkv_w + (long)layer * 2304 * 768,
        P.qkv_wc + (P.cache ? (long)layer * 2304 * 768 : 0), P.cache,
        P.qkv_b + layer * 2304, nullptr, nullptr, P.qkvb, M, 768, 2304);
    if (mode == 0){
        attn_mfma<<<dim3(B_ * HEADS_, 2), 512, 0, st>>>(
            P.qkvb, P.attb, NT_, 0, 13,
            P.qkvb + (long)MROW_ * 2304, P.attb + (long)MROW_ * 768, NS_, 0, 13);
    } else if (mode == 1){
        attn_mfma<<<dim3(B_ * HEADS_, 2), 512, 0, st>>>(
            P.qkvb, P.attb, NT_, 0, 7,
            P.qkvb, P.attb, NT_, 7, 13);
    } else {
        attn_deep_v3<<<dim3(B_, 50), 256, 0, st>>>(P.qkvb, P.prompts, P.selm, P.attb, li);
    }
    launch_gemm<2>(st, P.attb, P.proj_w + (long)layer * 768 * 768,
        P.proj_wc + (P.cache ? (long)layer * 768 * 768 : 0), P.cache,
        P.proj_b + layer * 768, x, x, nullptr, M, 768, 768);
    ln_k<<<lnGrid, 256, 0, st>>>(x, P.ln2_w + layer * 768, P.ln2_b + layer * 768, P.lnb, M);
    launch_gemm<1>(st, P.lnb, P.fc1_w + (long)layer * 3072 * 768,
        P.fc1_wc + (P.cache ? (long)layer * 3072 * 768 : 0), P.cache,
        P.fc1_b + layer * 3072, nullptr, nullptr, P.hidb, M, 768, 3072);
    launch_gemm<2>(st, P.hidb, P.fc2_w + (long)layer * 768 * 3072,
        P.fc2_wc + (P.cache ? (long)layer * 768 * 3072 : 0), P.cache,
        P.fc2_b + layer * 768, x, x, nullptr, M, 3072, 768);
}

// last layer: ln1+qkv full, attention q-tile 0 only, then compact tail MLP.
// gmode 0 = concat (Mtail=96, result in P.xT); 1 = main (Mtail=16, result in P.xMT).
static void run_layer_tail(hipStream_t st, float* x, int M, int layer, int gmode,
                           const Params& P)
{
    int lnGrid = (M + 3) / 4;
    ln_k<<<lnGrid, 256, 0, st>>>(x, P.ln1_w + layer * 768, P.ln1_b + layer * 768, P.lnb, M);
    launch_gemm<3>(st, P.lnb, P.qkv_w + (long)layer * 2304 * 768,
        P.qkv_wc + (P.cache ? (long)layer * 2304 * 768 : 0), P.cache,
        P.qkv_b + layer * 2304, nullptr, nullptr, P.qkvb, M, 768, 2304);
    if (gmode == 0){
        attn_mfma<<<dim3(B_ * HEADS_, 2), 512, 0, st>>>(
            P.qkvb, P.attb, NT_, 0, 1,
            P.qkvb + (long)MROW_ * 2304, P.attb + (long)MROW_ * 768, NS_, 0, 1);
    } else {
        attn_mfma<<<dim3(B_ * HEADS_, 1), 512, 0, st>>>(
            P.qkvb, P.attb, NT_, 0, 1,
            P.qkvb, P.attb, NT_, 0, 1);
    }
    const int Mt = (gmode == 0) ? TAILC_ : TAILM_;
    float* xt = (gmode == 0) ? P.xT : P.xMT;
    long tot = (long)Mt * 768;
    gather_tail_f<<<(int)((tot + 255) / 256), 256, 0, st>>>(x, xt, Mt, gmode);
    gather_tail_b<<<(int)((tot + 255) / 256), 256, 0, st>>>(P.attb, P.attbT, Mt, gmode);
    launch_gemm<2>(st, P.attbT, P.proj_w + (long)layer * 768 * 768,
        P.proj_wc + (P.cache ? (long)layer * 768 * 768 : 0), P.cache,
        P.proj_b + layer * 768, xt, xt, nullptr, Mt, 768, 768);
    ln_k<<<(Mt + 3) / 4, 256, 0, st>>>(xt, P.ln2_w + layer * 768, P.ln2_b + layer * 768,
                                       P.lnbT, Mt);
    launch_gemm<1>(st, P.lnbT, P.fc1_w + (long)layer * 3072 * 768,
        P.fc1_wc + (P.cache ? (long)layer * 3072 * 768 : 0), P.cache,
        P.fc1_b + layer * 3072, nullptr, nullptr, P.hidT, Mt, 768, 3072);
    launch_gemm<2>(st, P.hidT, P.fc2_w + (long)layer * 768 * 3072,
        P.fc2_wc + (P.cache ? (long)layer * 768 * 3072 : 0), P.cache,
        P.fc2_b + layer * 768, xt, xt, nullptr, Mt, 3072, 768);
}

extern "C" void kernel_launch(void* const* d_in, const int* in_sizes, int n_in,
                              void* d_out, int out_size, void* d_ws, size_t ws_size,
                              hipStream_t stream)
{
    (void)in_sizes; (void)n_in; (void)out_size;
    const float* inputs   = (const float*)d_in[0];
    const int*   task_id  = (const int*)  d_in[1];
    const float* patch_w  = (const float*)d_in[2];
    const float* patch_b  = (const float*)d_in[3];
    const float* cls_tok  = (const float*)d_in[4];
    const float* pos      = (const float*)d_in[5];
    const float* qkv_w    = (const float*)d_in[6];
    const float* qkv_b    = (const float*)d_in[7];
    const float* proj_w   = (const float*)d_in[8];
    const float* proj_b   = (const float*)d_in[9];
    const float* ln1_w    = (const float*)d_in[10];
    const float* ln1_b    = (const float*)d_in[11];
    const float* ln2_w    = (const float*)d_in[12];
    const float* ln2_b    = (const float*)d_in[13];
    const float* fc1_w    = (const float*)d_in[14];
    const float* fc1_b    = (const float*)d_in[15];
    const float* fc2_w    = (const float*)d_in[16];
    const float* fc2_b    = (const float*)d_in[17];
    const float* norm_w   = (const float*)d_in[18];
    const float* norm_b   = (const float*)d_in[19];
    const float* fc_w     = (const float*)d_in[20];
    const float* fc_b     = (const float*)d_in[21];
    const float* main_key = (const float*)d_in[22];
    const float* sub_key  = (const float*)d_in[23];
    const float* m_prompts= (const float*)d_in[24];
    const float* s_prompt = (const float*)d_in[25];
    float* out = (float*)d_out;

    char* wsb = (char*)d_ws;
    size_t off = 0;
    auto allocB = [&](size_t bytes) -> void* {
        void* p = (void*)(wsb + off);
        off += (bytes + 255) & ~(size_t)255;
        return p;
    };
    float* x0   = (float*)allocB((size_t)MROW_ * 768 * 4);
    float* xC   = (float*)allocB((size_t)CROW_ * 768 * 4);
    float* xM   = (float*)allocB((size_t)MROW_ * 768 * 4);
    short* lnb  = (short*)allocB((size_t)(CROW_ + PAD_) * 768 * 2);
    short* attb = (short*)allocB((size_t)(CROW_ + PAD_) * 768 * 2);
    short* qkvb = (short*)allocB((size_t)(CROW_ + PAD_) * 2304 * 2);
    short* hidb = (short*)allocB((size_t)(CROW_ + PAD_) * 3072 * 2);
    float* peo  = (float*)allocB((size_t)3136 * 768 * 4);
    // tail buffers
    float* xT    = (float*)allocB((size_t)TAILC_ * 768 * 4);
    float* xMT   = (float*)allocB((size_t)TAILM_ * 768 * 4);
    short* attbT = (short*)allocB((size_t)(TAILC_ + PAD_) * 768 * 2);
    short* lnbT  = (short*)allocB((size_t)(TAILC_ + PAD_) * 768 * 2);
    short* hidT  = (short*)allocB((size_t)(TAILC_ + PAD_) * 3072 * 2);
    int*   selm = (int*)allocB(64);
    int*   flag = (int*)allocB(64);

    const size_t nQkv = (size_t)DEPTH_ * 2304 * 768;
    const size_t nProj = (size_t)DEPTH_ * 768 * 768;
    const size_t nFc1 = (size_t)DEPTH_ * 3072 * 768;
    const size_t nFc2 = (size_t)DEPTH_ * 768 * 3072;
    const size_t nPatch = (size_t)768 * 768;
    size_t cacheBytes = (nQkv + nProj + nFc1 + nFc2 + nPatch) * 2 + 5 * 256;
    bool cache = (ws_size >= off + cacheBytes + (1u << 20));
    short *qkv_wc = nullptr, *proj_wc = nullptr, *fc1_wc = nullptr, *fc2_wc = nullptr, *patch_wc = nullptr;
    if (cache){
        qkv_wc  = (short*)allocB(nQkv * 2);
        proj_wc = (short*)allocB(nProj * 2);
        fc1_wc  = (short*)allocB(nFc1 * 2);
        fc2_wc  = (short*)allocB(nFc2 * 2);
        patch_wc= (short*)allocB(nPatch * 2);
        convert_w_k<<<2048, 256, 0, stream>>>(qkv_w,  qkv_wc,  (long)nQkv);
        convert_w_k<<<1024, 256, 0, stream>>>(proj_w, proj_wc, (long)nProj);
        convert_w_k<<<2048, 256, 0, stream>>>(fc1_w,  fc1_wc,  (long)nFc1);
        convert_w_k<<<2048, 256, 0, stream>>>(fc2_w,  fc2_wc,  (long)nFc2);
        convert_w_k<<<256,  256, 0, stream>>>(patch_w, patch_wc, (long)nPatch);
    }

    Params P;
    P.qkv_w = qkv_w; P.qkv_b = qkv_b; P.proj_w = proj_w; P.proj_b = proj_b;
    P.ln1_w = ln1_w; P.ln1_b = ln1_b; P.ln2_w = ln2_w; P.ln2_b = ln2_b;
    P.fc1_w = fc1_w; P.fc1_b = fc1_b; P.fc2_w = fc2_w; P.fc2_b = fc2_b;
    P.prompts = m_prompts; P.selm = selm;
    P.lnb = lnb; P.attb = attb; P.hidb = hidb; P.qkvb = qkvb;
    P.qkv_wc = qkv_wc; P.proj_wc = proj_wc; P.fc1_wc = fc1_wc; P.fc2_wc = fc2_wc;
    P.cache = cache;
    P.xT = xT; P.xMT = xMT; P.attbT = attbT; P.lnbT = lnbT; P.hidT = hidT;

    const long XN = (long)MROW_ * 768;

    // -------- patch embed --------
    {
        long tot = (long)B_ * 196 * 768;
        short* un = hidb;
        unfold_k<<<(int)((tot + 255) / 256), 256, 0, stream>>>(inputs, un);
        launch_gemm<0>(stream, un, patch_w, patch_wc, cache, patch_b, nullptr,
                       peo, nullptr, 3136, 768, 768);
        assemble_k<<<(int)((XN + 255) / 256), 256, 0, stream>>>(peo, cls_tok, pos, x0);
        copy_f<<<(int)((XN + 255) / 256), 256, 0, stream>>>(x0, xC, XN);
        long st = (long)SROW_ * 768;
        build_sub_k<<<(int)((st + 255) / 256), 256, 0, stream>>>(x0, s_prompt, pos,
                                                                 xC + (long)MROW_ * 768);
    }

    // -------- concatenated pass A + sub branch (last layer: tail-only MLP) --------
    for (int i = 0; i < DEPTH_ - 1; i++){
        run_layer(stream, xC, CROW_, i, 0, 0, P);
        if (i == 1)
            copy_f<<<(int)((XN + 255) / 256), 256, 0, stream>>>(xC, xM, XN);
    }
    run_layer_tail(stream, xC, CROW_, DEPTH_ - 1, 0, P);   // -> xT (96 rows)

    // -------- routing (pass-A CLS from compact tail) --------
    select_k<<<16, 256, 0, stream>>>(xT, norm_w, norm_b, main_key, sub_key,
                                     task_id, selm, flag);

    // -------- main branch layers 2..11 (deep prompts at 2,3,4; last = tail) --------
    for (int i = 2; i < DEPTH_ - 1; i++){
        int mode = (i >= 2 && i <= 4) ? 2 : 1;
        run_layer(stream, xM, MROW_, i, mode, i - 2, P);
    }
    run_layer_tail(stream, xM, MROW_, DEPTH_ - 1, 1, P);   // -> xMT (16 rows)

    // -------- heads + per-sample select --------
    head_k<<<16, 256, 0, stream>>>(xMT, xT, norm_w, norm_b, fc_w, fc_b, flag, out);
}

// Round 17
// 5240.685 us; speedup vs baseline: 1.2110x; 1.0195x over previous
//
#include <hip/hip_runtime.h>
#include <math.h>

// ---------------- constants ----------------
#define B_    16
#define NT_   197
#define NS_   202
#define HEADS_ 12
#define DEPTH_ 12
#define NCLS_ 100
#define MROW_ (B_ * NT_)      // 3152
#define SROW_ (B_ * NS_)      // 3232
#define CROW_ (MROW_ + SROW_) // 6384
#define PAD_  128             // GEMM-A row padding (global_load_lds has no row guard)
#define TAILC_ 96             // concat tail rows: 16 CLS + 16*5 sub-prompt rows
#define TAILM_ 16             // main tail rows: 16 CLS

typedef __attribute__((ext_vector_type(8))) short short8v;
typedef __attribute__((ext_vector_type(4))) float f32x4;

// f32 -> bf16 bits (RNE)
__device__ __forceinline__ short f2bf(float f){
    unsigned u = __builtin_bit_cast(unsigned, f);
    unsigned r = (u + 0x7FFFu + ((u >> 16) & 1u)) >> 16;
    return (short)r;
}
__device__ __forceinline__ unsigned pk2(float a, float b){
    return (unsigned)(unsigned short)f2bf(a) | (((unsigned)(unsigned short)f2bf(b)) << 16);
}
__device__ __forceinline__ float bf2f(unsigned short s){
    unsigned u = ((unsigned)s) << 16;
    return __builtin_bit_cast(float, u);
}
__device__ __forceinline__ float4 ld4bf(const short* p){
    uint2 u = *(const uint2*)p;
    float4 r;
    r.x = bf2f((unsigned short)(u.x & 0xffff));
    r.y = bf2f((unsigned short)(u.x >> 16));
    r.z = bf2f((unsigned short)(u.y & 0xffff));
    r.w = bf2f((unsigned short)(u.y >> 16));
    return r;
}
// async global->LDS, 16B per lane; lds base must be wave-uniform
__device__ __forceinline__ void gld16(const short* g, short* l){
    __builtin_amdgcn_global_load_lds(
        (const __attribute__((address_space(1))) unsigned*)g,
        (__attribute__((address_space(3))) unsigned*)l, 16, 0, 0);
}

// ============ double block reduce (256 thr) — routing/head only ============
__device__ __forceinline__ double block_reduce_sum_d(double s, double* red, int lane, int wid){
#pragma unroll
    for (int off = 32; off; off >>= 1) s += __shfl_xor(s, off);
    if (lane == 0) red[wid] = s;
    __syncthreads();
    double S = red[0] + red[1] + red[2] + red[3];
    __syncthreads();
    return S;
}

// ============ weight convert f32 -> bf16 ============
__global__ void convert_w_k(const float* __restrict__ in, short* __restrict__ out, long n){
    long i = ((long)blockIdx.x * 256 + threadIdx.x) * 8;
    long stride = (long)gridDim.x * 256 * 8;
    for (; i < n; i += stride){
        float4 a = *(const float4*)(in + i);
        float4 b = *(const float4*)(in + i + 4);
        uint4 o4;
        o4.x = pk2(a.x, a.y); o4.y = pk2(a.z, a.w);
        o4.z = pk2(b.x, b.y); o4.w = pk2(b.z, b.w);
        *(uint4*)(out + i) = o4;
    }
}

// ============ bf16 MFMA GEMM, BK=64 (round-15 winner, unchanged) ============
template<int EPI, int WB>
__global__ __launch_bounds__(256) void gemm_bf16(
    const short* __restrict__ A, const void* __restrict__ Wv,
    const float* __restrict__ bias, const float* __restrict__ Res,
    float* __restrict__ Cf, short* __restrict__ Cb, int M, int K, int N)
{
    __shared__ short As0[128 * 32];
    __shared__ short As1[128 * 32];
    __shared__ short Bs0[128 * 32];
    __shared__ short Bs1[128 * 32];
    const int t = threadIdx.x;
    const int lane = t & 63, wid = t >> 6;
    const int wr = wid >> 1, wc = wid & 1;
    const long row0 = (long)blockIdx.y * 128;
    const long col0 = (long)blockIdx.x * 128;

    f32x4 acc[4][4];
#pragma unroll
    for (int i = 0; i < 4; i++)
#pragma unroll
        for (int j = 0; j < 4; j++) acc[i][j] = (f32x4){0.f, 0.f, 0.f, 0.f};

    const int l15 = lane & 15, lkg = lane >> 4;
    const int lrow = lane >> 2;
    const int lcol = (lane & 3) * 8;

    for (int k0 = 0; k0 < K; k0 += 64){
#pragma unroll
        for (int i = 0; i < 2; i++){
            int rb = wid * 32 + i * 16;
            const short* gs = A + (row0 + rb + lrow) * K + k0 + lcol;
            gld16(gs,      &As0[rb * 32]);
            gld16(gs + 32, &As1[rb * 32]);
        }
        if (WB == 1){
            const short* Wb = (const short*)Wv;
#pragma unroll
            for (int i = 0; i < 2; i++){
                int rb = wid * 32 + i * 16;
                const short* gs = Wb + (col0 + rb + lrow) * K + k0 + lcol;
                gld16(gs,      &Bs0[rb * 32]);
                gld16(gs + 32, &Bs1[rb * 32]);
            }
        } else {
            const float* Wf = (const float*)Wv;
            const int bn = t >> 1, bh = t & 1;
#pragma unroll
            for (int half = 0; half < 2; half++){
                const float* Wp = Wf + (col0 + bn) * K + k0 + half * 32 + bh * 16;
                unsigned rr[8];
#pragma unroll
                for (int g = 0; g < 8; g++){
                    float2 f = *(const float2*)(Wp + g * 2);
                    rr[g] = pk2(f.x, f.y);
                }
                uint4 lo = {rr[0], rr[1], rr[2], rr[3]};
                uint4 hi = {rr[4], rr[5], rr[6], rr[7]};
                short* Bsh = half ? Bs1 : Bs0;
                *(uint4*)(&Bsh[bn * 32 + bh * 16])     = lo;
                *(uint4*)(&Bsh[bn * 32 + bh * 16 + 8]) = hi;
            }
        }
        __syncthreads();

        {
            short8v a[4], b[4];
#pragma unroll
            for (int i = 0; i < 4; i++)
                a[i] = *(const short8v*)(&As0[(wr * 64 + i * 16 + l15) * 32 + lkg * 8]);
#pragma unroll
            for (int j = 0; j < 4; j++)
                b[j] = *(const short8v*)(&Bs0[(wc * 64 + j * 16 + l15) * 32 + lkg * 8]);
#pragma unroll
            for (int i = 0; i < 4; i++)
#pragma unroll
                for (int j = 0; j < 4; j++)
                    acc[i][j] = __builtin_amdgcn_mfma_f32_16x16x32_bf16(a[i], b[j], acc[i][j], 0, 0, 0);
        }
        {
            short8v a[4], b[4];
#pragma unroll
            for (int i = 0; i < 4; i++)
                a[i] = *(const short8v*)(&As1[(wr * 64 + i * 16 + l15) * 32 + lkg * 8]);
#pragma unroll
            for (int j = 0; j < 4; j++)
                b[j] = *(const short8v*)(&Bs1[(wc * 64 + j * 16 + l15) * 32 + lkg * 8]);
#pragma unroll
            for (int i = 0; i < 4; i++)
#pragma unroll
                for (int j = 0; j < 4; j++)
                    acc[i][j] = __builtin_amdgcn_mfma_f32_16x16x32_bf16(a[i], b[j], acc[i][j], 0, 0, 0);
        }
        __syncthreads();
    }

#pragma unroll
    for (int i = 0; i < 4; i++){
#pragma unroll
        for (int q = 0; q < 4; q++){
            long gr = row0 + wr * 64 + i * 16 + lkg * 4 + q;
            if (gr >= M) continue;
#pragma unroll
            for (int j = 0; j < 4; j++){
                long gc = col0 + wc * 64 + j * 16 + l15;
                float v = acc[i][j][q] + bias[gc];
                if (EPI == 1){
                    v = 0.5f * v * (1.f + erff(v * 0.70710678118654752f));
                    Cb[gr * N + gc] = f2bf(v);
                } else if (EPI == 2){
                    Cf[gr * N + gc] = v + Res[gr * N + gc];
                } else if (EPI == 3){
                    Cb[gr * N + gc] = f2bf(v);
                } else {
                    Cf[gr * N + gc] = v;
                }
            }
        }
    }
}

// ============ LayerNorm: wave-per-row (unchanged) ============
__global__ __launch_bounds__(256) void ln_k(const float* __restrict__ x,
    const float* __restrict__ w, const float* __restrict__ b,
    short* __restrict__ y, int M)
{
    const int lane = threadIdx.x & 63, wv = threadIdx.x >> 6;
    const int row = blockIdx.x * 4 + wv;
    if (row >= M) return;
    const float* xr = x + (long)row * 768;
    float v[12];
    float s = 0.f;
#pragma unroll
    for (int j = 0; j < 12; j++){ v[j] = xr[lane + j * 64]; s += v[j]; }
#pragma unroll
    for (int off = 32; off; off >>= 1) s += __shfl_xor(s, off);
    float m = s * (1.f / 768.f);
    float q = 0.f;
#pragma unroll
    for (int j = 0; j < 12; j++){ v[j] -= m; q += v[j] * v[j]; }
#pragma unroll
    for (int off = 32; off; off >>= 1) q += __shfl_xor(q, off);
    float rs = 1.f / sqrtf(q * (1.f / 768.f) + 1e-6f);
    short* yr = y + (long)row * 768;
#pragma unroll
    for (int j = 0; j < 12; j++)
        yr[lane + j * 64] = f2bf(v[j] * rs * w[lane + j * 64] + b[lane + j * 64]);
}

// ============ std MHA via MFMA v4: per-wave 2-subtile P ring (LDS 70KB -> 2 blk/CU) ============
// Same math/order as round-12 verified kernel; P written per kc-pair into a small
// per-wave [16][40] ring (wave-internal LDS write->read, same mechanism as before).
__global__ __launch_bounds__(512) void attn_mfma(
    const short* __restrict__ qkv0, short* __restrict__ o0, int N0, int tb0, int te0,
    const short* __restrict__ qkv1, short* __restrict__ o1, int N1, int tb1, int te1)
{
    __shared__ short Ks[208 * 72];
    __shared__ short Vs[64 * 232];
    __shared__ short Ps[8 * 16 * 40];
    const int bh = blockIdx.x;
    const int b = bh / HEADS_, h = bh % HEADS_;
    const int seg = blockIdx.y;
    const short* qkv = seg ? qkv1 : qkv0;
    short* o = seg ? o1 : o0;
    const int Ntok = seg ? N1 : N0;
    const int tb = seg ? tb1 : tb0;
    const int te = seg ? te1 : te0;
    const int t = threadIdx.x, lane = t & 63, wid = t >> 6;
    const long rb = (long)b * Ntok;

    {
        const int r = t >> 2, c = (t & 3) * 16;
#pragma unroll
        for (int pass = 0; pass < 2; pass++){
            int m = r + pass * 128;
            if (m < 208){
                if (m < Ntok){
                    const short* kr = qkv + (rb + m) * 2304 + 768  + h * 64 + c;
                    const short* vr = qkv + (rb + m) * 2304 + 1536 + h * 64 + c;
                    *(uint4*)(&Ks[m * 72 + c])     = *(const uint4*)(kr);
                    *(uint4*)(&Ks[m * 72 + c + 8]) = *(const uint4*)(kr + 8);
#pragma unroll
                    for (int j = 0; j < 16; j++)
                        Vs[(c + j) * 232 + m] = vr[j];
                } else {
#pragma unroll
                    for (int j = 0; j < 16; j += 2)
                        *(unsigned*)(&Ks[m * 72 + c + j]) = 0u;
#pragma unroll
                    for (int j = 0; j < 16; j++)
                        Vs[(c + j) * 232 + m] = 0;
                }
            }
        }
        for (int i = t; i < 64 * 16; i += 512){
            int d = i >> 4, m = 208 + (i & 15);
            Vs[d * 232 + m] = 0;
        }
    }
    __syncthreads();

    const int l15 = lane & 15, lkg = lane >> 4;
    short* Pw = &Ps[wid * 16 * 40];

    for (int s = tb + wid; s < te; s += 8){
        const int q0 = s * 16;
        short8v a0, a1;
        {
            int qrow = q0 + l15;
            if (qrow < Ntok){
                const short* qp = qkv + (rb + qrow) * 2304 + h * 64;
                a0 = *(const short8v*)(qp + lkg * 8);
                a1 = *(const short8v*)(qp + 32 + lkg * 8);
            } else {
                uint4 z = {0u,0u,0u,0u};
                a0 = __builtin_bit_cast(short8v, z);
                a1 = __builtin_bit_cast(short8v, z);
            }
        }
        f32x4 sacc[13];
#pragma unroll
        for (int j = 0; j < 13; j++){
            short8v b0 = *(const short8v*)(&Ks[(j * 16 + l15) * 72 + lkg * 8]);
            short8v b1 = *(const short8v*)(&Ks[(j * 16 + l15) * 72 + 32 + lkg * 8]);
            f32x4 z = {0.f, 0.f, 0.f, 0.f};
            z = __builtin_amdgcn_mfma_f32_16x16x32_bf16(a0, b0, z, 0, 0, 0);
            z = __builtin_amdgcn_mfma_f32_16x16x32_bf16(a1, b1, z, 0, 0, 0);
            sacc[j][0] = z[0] * 0.125f; sacc[j][1] = z[1] * 0.125f;
            sacc[j][2] = z[2] * 0.125f; sacc[j][3] = z[3] * 0.125f;
        }
#pragma unroll
        for (int j = 0; j < 13; j++){
            if (j * 16 + l15 >= Ntok){
                sacc[j][0] = -1e30f; sacc[j][1] = -1e30f;
                sacc[j][2] = -1e30f; sacc[j][3] = -1e30f;
            }
        }
        // softmax per row; normalized P kept in sacc registers
#pragma unroll
        for (int rr = 0; rr < 4; rr++){
            float mx = sacc[0][rr];
#pragma unroll
            for (int j = 1; j < 13; j++) mx = fmaxf(mx, sacc[j][rr]);
            mx = fmaxf(mx, __shfl_xor(mx, 1));
            mx = fmaxf(mx, __shfl_xor(mx, 2));
            mx = fmaxf(mx, __shfl_xor(mx, 4));
            mx = fmaxf(mx, __shfl_xor(mx, 8));
            float pv[13];
            float sum = 0.f;
#pragma unroll
            for (int j = 0; j < 13; j++){
                float e = expf(sacc[j][rr] - mx);
                pv[j] = e; sum += e;
            }
            sum += __shfl_xor(sum, 1);
            sum += __shfl_xor(sum, 2);
            sum += __shfl_xor(sum, 4);
            sum += __shfl_xor(sum, 8);
            float inv = 1.f / sum;
#pragma unroll
            for (int j = 0; j < 13; j++) sacc[j][rr] = pv[j] * inv;
        }
        // PV: per kc, write the 2 needed P sub-tiles then read pa (wave-internal)
        f32x4 oacc[4];
#pragma unroll
        for (int dj = 0; dj < 4; dj++) oacc[dj] = (f32x4){0.f, 0.f, 0.f, 0.f};
#pragma unroll
        for (int kc = 0; kc < 7; kc++){
            const int j0 = 2 * kc, j1 = 2 * kc + 1;
#pragma unroll
            for (int rr = 0; rr < 4; rr++){
                Pw[(lkg * 4 + rr) * 40 + l15]      = f2bf(sacc[j0][rr]);
                Pw[(lkg * 4 + rr) * 40 + 16 + l15] = (j1 < 13) ? f2bf(sacc[j1][rr]) : (short)0;
            }
            short8v pa = *(const short8v*)(&Pw[l15 * 40 + lkg * 8]);
#pragma unroll
            for (int dj = 0; dj < 4; dj++){
                short8v vb = *(const short8v*)(&Vs[(dj * 16 + l15) * 232 + kc * 32 + lkg * 8]);
                oacc[dj] = __builtin_amdgcn_mfma_f32_16x16x32_bf16(pa, vb, oacc[dj], 0, 0, 0);
            }
        }
#pragma unroll
        for (int dj = 0; dj < 4; dj++){
#pragma unroll
            for (int rr = 0; rr < 4; rr++){
                int q = q0 + lkg * 4 + rr;
                if (q < Ntok)
                    o[(rb + q) * 768 + h * 64 + dj * 16 + l15] = f2bf(oacc[dj][rr]);
            }
        }
    }
}

// ============ deep attention v3 (unchanged) ============
__global__ __launch_bounds__(256) void attn_deep_v3(
    const short* __restrict__ qkv, const float* __restrict__ prompts,
    const int* __restrict__ selm, short* __restrict__ o, int li)
{
    __shared__ float sc[4][208];
    const int b = blockIdx.x, g = blockIdx.y, t = threadIdx.x;
    const int lane = t & 63, w = t >> 6;
    const int n0 = g * 4;

    float4 q0[4], q1[4], q2[4];
#pragma unroll
    for (int qi = 0; qi < 4; qi++){
        int n = n0 + qi;
        int nn = (n < NT_) ? n : (NT_ - 1);
        const short* qr = qkv + (long)(b * NT_ + nn) * 2304;
        q0[qi] = ld4bf(qr + lane * 4);
        q1[qi] = ld4bf(qr + 256 + lane * 4);
        q2[qi] = ld4bf(qr + 512 + lane * 4);
    }

    const float* kp = prompts + ((long)selm[b] * 6 + 2 * li) * 5 * 768;
    const float* vp = kp + 5 * 768;

    for (int m = w; m < 202; m += 4){
        float4 k0, k1, k2;
        if (m < 5){
            const float* kr = kp + (long)m * 768;
            k0 = *(const float4*)(kr + lane * 4);
            k1 = *(const float4*)(kr + 256 + lane * 4);
            k2 = *(const float4*)(kr + 512 + lane * 4);
        } else {
            const short* kr = qkv + (long)(b * NT_ + (m - 5)) * 2304 + 768;
            k0 = ld4bf(kr + lane * 4);
            k1 = ld4bf(kr + 256 + lane * 4);
            k2 = ld4bf(kr + 512 + lane * 4);
        }
        float a[4];
#pragma unroll
        for (int qi = 0; qi < 4; qi++){
            a[qi] = q0[qi].x*k0.x + q0[qi].y*k0.y + q0[qi].z*k0.z + q0[qi].w*k0.w
                  + q1[qi].x*k1.x + q1[qi].y*k1.y + q1[qi].z*k1.z + q1[qi].w*k1.w
                  + q2[qi].x*k2.x + q2[qi].y*k2.y + q2[qi].z*k2.z + q2[qi].w*k2.w;
        }
#pragma unroll
        for (int off = 32; off; off >>= 1){
#pragma unroll
            for (int qi = 0; qi < 4; qi++) a[qi] += __shfl_xor(a[qi], off);
        }
        if (lane == 0){
#pragma unroll
            for (int qi = 0; qi < 4; qi++) sc[qi][m] = a[qi] * 0.125f;
        }
    }
    __syncthreads();

    {
        float v[4];
#pragma unroll
        for (int i = 0; i < 4; i++){
            int m = lane + i * 64;
            v[i] = (m < 202) ? sc[w][m] : -1e30f;
        }
        float mx = fmaxf(fmaxf(v[0], v[1]), fmaxf(v[2], v[3]));
#pragma unroll
        for (int off = 32; off; off >>= 1) mx = fmaxf(mx, __shfl_xor(mx, off));
        float e[4], sum = 0.f;
#pragma unroll
        for (int i = 0; i < 4; i++){
            int m = lane + i * 64;
            e[i] = (m < 202) ? expf(v[i] - mx) : 0.f;
            sum += e[i];
        }
#pragma unroll
        for (int off = 32; off; off >>= 1) sum += __shfl_xor(sum, off);
        float inv = 1.f / sum;
#pragma unroll
        for (int i = 0; i < 4; i++){
            int m = lane + i * 64;
            if (m < 202) sc[w][m] = e[i] * inv;
        }
    }
    __syncthreads();

    float a0[4] = {0.f,0.f,0.f,0.f}, a1[4] = {0.f,0.f,0.f,0.f}, a2[4] = {0.f,0.f,0.f,0.f};
    for (int m = 0; m < 5; m++){
        const float* vr = vp + (long)m * 768;
        float v0 = vr[t], v1 = vr[t + 256], v2 = vr[t + 512];
#pragma unroll
        for (int qi = 0; qi < 4; qi++){
            float pm = sc[qi][m];
            a0[qi] += pm * v0; a1[qi] += pm * v1; a2[qi] += pm * v2;
        }
    }
    for (int m = 5; m < 202; m++){
        const short* vr = qkv + (long)(b * NT_ + (m - 5)) * 2304 + 1536;
        float v0 = bf2f((unsigned short)vr[t]);
        float v1 = bf2f((unsigned short)vr[t + 256]);
        float v2 = bf2f((unsigned short)vr[t + 512]);
#pragma unroll
        for (int qi = 0; qi < 4; qi++){
            float pm = sc[qi][m];
            a0[qi] += pm * v0; a1[qi] += pm * v1; a2[qi] += pm * v2;
        }
    }
#pragma unroll
    for (int qi = 0; qi < 4; qi++){
        int n = n0 + qi;
        if (n < NT_){
            short* ob = o + (long)b * NT_ * 768 + n;
            ob[(long)t * 197]         = f2bf(a0[qi]);
            ob[(long)(t + 256) * 197] = f2bf(a1[qi]);
            ob[(long)(t + 512) * 197] = f2bf(a2[qi]);
        }
    }
}

// ============ tail gathers (unchanged) ============
__device__ __forceinline__ long tail_src_row(int r, int mode){
    if (mode == 1) return (long)r * NT_;
    if (r < 16)    return (long)r * NT_;
    int j = r - 16;
    return (long)MROW_ + (long)(j / 5) * NS_ + 1 + (j % 5);
}
__global__ void gather_tail_f(const float* __restrict__ src, float* __restrict__ dst,
                              int nrows, int mode){
    long i = (long)blockIdx.x * 256 + threadIdx.x;
    long total = (long)nrows * 768;
    if (i >= total) return;
    int r = (int)(i / 768), d = (int)(i % 768);
    dst[i] = src[tail_src_row(r, mode) * 768 + d];
}
__global__ void gather_tail_b(const short* __restrict__ src, short* __restrict__ dst,
                              int nrows, int mode){
    long i = (long)blockIdx.x * 256 + threadIdx.x;
    long total = (long)nrows * 768;
    if (i >= total) return;
    int r = (int)(i / 768), d = (int)(i % 768);
    dst[i] = src[tail_src_row(r, mode) * 768 + d];
}

// ============ patch unfold (f32 -> bf16) ============
__global__ void unfold_k(const float* __restrict__ in, short* __restrict__ out){
    long i = (long)blockIdx.x * 256 + threadIdx.x;
    long total = (long)B_ * 196 * 768;
    if (i >= total) return;
    int f = (int)(i % 768); long rw = i / 768;
    int t = (int)(rw % 196); int b = (int)(rw / 196);
    int gy = t / 14, gx = t % 14;
    int c = f >> 8, rem = f & 255, py = rem >> 4, px = rem & 15;
    out[i] = f2bf(in[(((long)(b * 3 + c) * 224) + gy * 16 + py) * 224 + gx * 16 + px]);
}

// ============ assemble x0 = [cls+pos ; patches+pos] (f32) ============
__global__ void assemble_k(const float* __restrict__ pe, const float* __restrict__ cls,
    const float* __restrict__ pos, float* __restrict__ x0){
    long i = (long)blockIdx.x * 256 + threadIdx.x;
    long total = (long)B_ * NT_ * 768;
    if (i >= total) return;
    int d = (int)(i % 768); long rw = i / 768;
    int n = (int)(rw % NT_); int b = (int)(rw / NT_);
    float v;
    if (n == 0) v = cls[d] + pos[d];
    else        v = pe[((long)b * 196 + (n - 1)) * 768 + d] + pos[(long)n * 768 + d];
    x0[i] = v;
}

__global__ void copy_f(const float* __restrict__ a, float* __restrict__ b, long total){
    long i = (long)blockIdx.x * 256 + threadIdx.x;
    if (i < total) b[i] = a[i];
}

// ============ build sub-branch rows (reads pass-A segment of xC) ============
__global__ void build_sub_k(const float* __restrict__ x0, const float* __restrict__ subp,
    const float* __restrict__ pos, float* __restrict__ xSub){
    long i = (long)blockIdx.x * 256 + threadIdx.x;
    long total = (long)B_ * NS_ * 768;
    if (i >= total) return;
    int d = (int)(i % 768); long rw = i / 768;
    int n = (int)(rw % NS_); int b = (int)(rw / NS_);
    float v;
    if (n == 0)      v = x0[((long)b * NT_) * 768 + d];
    else if (n <= 5) v = subp[(n - 1) * 768 + d] + pos[d];
    else             v = x0[((long)b * NT_ + (n - 5)) * 768 + d];
    xSub[i] = v;
}

// ============ routing (f64 internals) — reads compact tail buffer, row b ============
__global__ __launch_bounds__(256) void select_k(
    const float* __restrict__ xT, const float* __restrict__ norm_w,
    const float* __restrict__ norm_b, const float* __restrict__ main_key,
    const float* __restrict__ sub_key, const int* __restrict__ task_id_p,
    int* __restrict__ selm, int* __restrict__ flag)
{
    __shared__ double red[4];
    int b = blockIdx.x, t = threadIdx.x, lane = t & 63, wid = t >> 6;
    const float* xr = xT + (long)b * 768;
    double v0 = xr[t], v1 = xr[t + 256], v2 = xr[t + 512];
    double S = block_reduce_sum_d(v0 + v1 + v2, red, lane, wid);
    double m = S * (1.0 / 768.0);
    double d0 = v0 - m, d1 = v1 - m, d2 = v2 - m;
    double Q = block_reduce_sum_d(d0*d0 + d1*d1 + d2*d2, red, lane, wid);
    double rs = 1.0 / sqrt(Q * (1.0 / 768.0) + 1e-6);
    double q0 = d0 * rs * (double)norm_w[t]       + (double)norm_b[t];
    double q1 = d1 * rs * (double)norm_w[t + 256] + (double)norm_b[t + 256];
    double q2 = d2 * rs * (double)norm_w[t + 512] + (double)norm_b[t + 512];
    double qn = block_reduce_sum_d(q0*q0 + q1*q1 + q2*q2, red, lane, wid);
    double qinv = 1.0 / sqrt(fmax(qn, 1e-12));

    int tk = *task_id_p;
    int ncand = tk + 2;
    double best = -1e300; int bsel = 0;
    for (int c = 0; c < ncand; c++){
        const float* cr = (c <= tk) ? (main_key + (long)c * 768) : sub_key;
        double c0 = cr[t], c1 = cr[t + 256], c2 = cr[t + 512];
        double dotq = block_reduce_sum_d(q0*c0 + q1*c1 + q2*c2, red, lane, wid);
        double nc   = block_reduce_sum_d(c0*c0 + c1*c1 + c2*c2, red, lane, wid);
        double sim = dotq * qinv * (1.0 / sqrt(fmax(nc, 1e-12)));
        if (sim > best){ best = sim; bsel = c; }
    }
    if (t == 0){
        int isMain = (bsel <= tk) ? 1 : 0;
        selm[b] = isMain ? bsel : 0;
        flag[b] = isMain;
    }
}

// ============ final head (f64 internals) — reads compact tail buffers ============
__global__ __launch_bounds__(256) void head_k(
    const float* __restrict__ xMT, const float* __restrict__ xT,
    const float* __restrict__ norm_w, const float* __restrict__ norm_b,
    const float* __restrict__ fc_w, const float* __restrict__ fc_b,
    const int* __restrict__ flag, float* __restrict__ out)
{
    __shared__ double vec[768];
    __shared__ double red[4];
    int b = blockIdx.x, t = threadIdx.x, lane = t & 63, wid = t >> 6;
    int isMain = flag[b];
    double a0 = 0.0, a1 = 0.0, a2 = 0.0;
    int nrows = isMain ? 1 : 5;
    for (int rI = 0; rI < nrows; rI++){
        const float* xr = isMain ? (xMT + (long)b * 768)
                                 : (xT + (long)(16 + b * 5 + rI) * 768);
        double v0 = xr[t], v1 = xr[t + 256], v2 = xr[t + 512];
        double S = block_reduce_sum_d(v0 + v1 + v2, red, lane, wid);
        double m = S * (1.0 / 768.0);
        double d0 = v0 - m, d1 = v1 - m, d2 = v2 - m;
        double Q = block_reduce_sum_d(d0*d0 + d1*d1 + d2*d2, red, lane, wid);
        double rs = 1.0 / sqrt(Q * (1.0 / 768.0) + 1e-6);
        a0 += d0 * rs * (double)norm_w[t]       + (double)norm_b[t];
        a1 += d1 * rs * (double)norm_w[t + 256] + (double)norm_b[t + 256];
        a2 += d2 * rs * (double)norm_w[t + 512] + (double)norm_b[t + 512];
    }
    double scl = isMain ? 1.0 : 0.2;
    vec[t] = a0 * scl; vec[t + 256] = a1 * scl; vec[t + 512] = a2 * scl;
    __syncthreads();
    if (t < NCLS_){
        const float* wr = fc_w + (long)t * 768;
        double acc = (double)fc_b[t];
#pragma unroll 8
        for (int j = 0; j < 768; j++) acc += vec[j] * (double)wr[j];
        out[b * NCLS_ + t] = (float)acc;
    }
}

// ================= host-side =================
struct Params {
    const float *qkv_w, *qkv_b, *proj_w, *proj_b;
    const float *ln1_w, *ln1_b, *ln2_w, *ln2_b;
    const float *fc1_w, *fc1_b, *fc2_w, *fc2_b;
    const float *prompts; const int* selm;
    short *lnb, *attb, *hidb;
    short *qkvb;
    const short *qkv_wc, *proj_wc, *fc1_wc, *fc2_wc;
    bool cache;
    float *xT, *xMT;
    short *attbT, *lnbT, *hidT;
};

template<int EPI>
static void launch_gemm(hipStream_t st, const short* A, const float* Wf, const short* Wc,
                        bool cache, const float* bias, const float* Res,
                        float* Cf, short* Cb, int M, int K, int N)
{
    dim3 g(N / 128, (M + 127) / 128);
    if (cache)
        gemm_bf16<EPI, 1><<<g, 256, 0, st>>>(A, (const void*)Wc, bias, Res, Cf, Cb, M, K, N);
    else
        gemm_bf16<EPI, 0><<<g, 256, 0, st>>>(A, (const void*)Wf, bias, Res, Cf, Cb, M, K, N);
}

// mode 0: concat (std attn both segments)  mode 1: main std  mode 2: main deep
static void run_layer(hipStream_t st, float* x, int M, int layer, int mode, int li,
                      const Params& P)
{
    int lnGrid = (M + 3) / 4;
    ln_k<<<lnGrid, 256, 0, st>>>(x, P.ln1_w + layer * 768, P.ln1_b + layer * 768, P.lnb, M);
    launch_gemm<3>(st, P.lnb, P.qkv_w + (long)layer * 2304 * 768,
        P.qkv_wc + (P.cache ? (long)layer * 2304 * 768 : 0), P.cache,
        P.qkv_b + layer * 2304, nullptr, nullptr, P.qkvb, M, 768, 2304);
    if (mode == 0){
        attn_mfma<<<dim3(B_ * HEADS_, 2), 512, 0, st>>>(
            P.qkvb, P.attb, NT_, 0, 13,
            P.qkvb + (long)MROW_ * 2304, P.attb + (long)MROW_ * 768, NS_, 0, 13);
    } else if (mode == 1){
        attn_mfma<<<dim3(B_ * HEADS_, 2), 512, 0, st>>>(
            P.qkvb, P.attb, NT_, 0, 7,
            P.qkvb, P.attb, NT_, 7, 13);
    } else {
        attn_deep_v3<<<dim3(B_, 50), 256, 0, st>>>(P.qkvb, P.prompts, P.selm, P.attb, li);
    }
    launch_gemm<2>(st, P.attb, P.proj_w + (long)layer * 768 * 768,
        P.proj_wc + (P.cache ? (long)layer * 768 * 768 : 0), P.cache,
        P.proj_b + layer * 768, x, x, nullptr, M, 768, 768);
    ln_k<<<lnGrid, 256, 0, st>>>(x, P.ln2_w + layer * 768, P.ln2_b + layer * 768, P.lnb, M);
    launch_gemm<1>(st, P.lnb, P.fc1_w + (long)layer * 3072 * 768,
        P.fc1_wc + (P.cache ? (long)layer * 3072 * 768 : 0), P.cache,
        P.fc1_b + layer * 3072, nullptr, nullptr, P.hidb, M, 768, 3072);
    launch_gemm<2>(st, P.hidb, P.fc2_w + (long)layer * 768 * 3072,
        P.fc2_wc + (P.cache ? (long)layer * 768 * 3072 : 0), P.cache,
        P.fc2_b + layer * 768, x, x, nullptr, M, 3072, 768);
}

// last layer: ln1+qkv full, attention q-tile 0 only, then compact tail MLP.
static void run_layer_tail(hipStream_t st, float* x, int M, int layer, int gmode,
                           const Params& P)
{
    int lnGrid = (M + 3) / 4;
    ln_k<<<lnGrid, 256, 0, st>>>(x, P.ln1_w + layer * 768, P.ln1_b + layer * 768, P.lnb, M);
    launch_gemm<3>(st, P.lnb, P.qkv_w + (long)layer * 2304 * 768,
        P.qkv_wc + (P.cache ? (long)layer * 2304 * 768 : 0), P.cache,
        P.qkv_b + layer * 2304, nullptr, nullptr, P.qkvb, M, 768, 2304);
    if (gmode == 0){
        attn_mfma<<<dim3(B_ * HEADS_, 2), 512, 0, st>>>(
            P.qkvb, P.attb, NT_, 0, 1,
            P.qkvb + (long)MROW_ * 2304, P.attb + (long)MROW_ * 768, NS_, 0, 1);
    } else {
        attn_mfma<<<dim3(B_ * HEADS_, 1), 512, 0, st>>>(
            P.qkvb, P.attb, NT_, 0, 1,
            P.qkvb, P.attb, NT_, 0, 1);
    }
    const int Mt = (gmode == 0) ? TAILC_ : TAILM_;
    float* xt = (gmode == 0) ? P.xT : P.xMT;
    long tot = (long)Mt * 768;
    gather_tail_f<<<(int)((tot + 255) / 256), 256, 0, st>>>(x, xt, Mt, gmode);
    gather_tail_b<<<(int)((tot + 255) / 256), 256, 0, st>>>(P.attb, P.attbT, Mt, gmode);
    launch_gemm<2>(st, P.attbT, P.proj_w + (long)layer * 768 * 768,
        P.proj_wc + (P.cache ? (long)layer * 768 * 768 : 0), P.cache,
        P.proj_b + layer * 768, xt, xt, nullptr, Mt, 768, 768);
    ln_k<<<(Mt + 3) / 4, 256, 0, st>>>(xt, P.ln2_w + layer * 768, P.ln2_b + layer * 768,
                                       P.lnbT, Mt);
    launch_gemm<1>(st, P.lnbT, P.fc1_w + (long)layer * 3072 * 768,
        P.fc1_wc + (P.cache ? (long)layer * 3072 * 768 : 0), P.cache,
        P.fc1_b + layer * 3072, nullptr, nullptr, P.hidT, Mt, 768, 3072);
    launch_gemm<2>(st, P.hidT, P.fc2_w + (long)layer * 768 * 3072,
        P.fc2_wc + (P.cache ? (long)layer * 768 * 3072 : 0), P.cache,
        P.fc2_b + layer * 768, xt, xt, nullptr, Mt, 3072, 768);
}

extern "C" void kernel_launch(void* const* d_in, const int* in_sizes, int n_in,
                              void* d_out, int out_size, void* d_ws, size_t ws_size,
                              hipStream_t stream)
{
    (void)in_sizes; (void)n_in; (void)out_size;
    const float* inputs   = (const float*)d_in[0];
    const int*   task_id  = (const int*)  d_in[1];
    const float* patch_w  = (const float*)d_in[2];
    const float* patch_b  = (const float*)d_in[3];
    const float* cls_tok  = (const float*)d_in[4];
    const float* pos      = (const float*)d_in[5];
    const float* qkv_w    = (const float*)d_in[6];
    const float* qkv_b    = (const float*)d_in[7];
    const float* proj_w   = (const float*)d_in[8];
    const float* proj_b   = (const float*)d_in[9];
    const float* ln1_w    = (const float*)d_in[10];
    const float* ln1_b    = (const float*)d_in[11];
    const float* ln2_w    = (const float*)d_in[12];
    const float* ln2_b    = (const float*)d_in[13];
    const float* fc1_w    = (const float*)d_in[14];
    const float* fc1_b    = (const float*)d_in[15];
    const float* fc2_w    = (const float*)d_in[16];
    const float* fc2_b    = (const float*)d_in[17];
    const float* norm_w   = (const float*)d_in[18];
    const float* norm_b   = (const float*)d_in[19];
    const float* fc_w     = (const float*)d_in[20];
    const float* fc_b     = (const float*)d_in[21];
    const float* main_key = (const float*)d_in[22];
    const float* sub_key  = (const float*)d_in[23];
    const float* m_prompts= (const float*)d_in[24];
    const float* s_prompt = (const float*)d_in[25];
    float* out = (float*)d_out;

    char* wsb = (char*)d_ws;
    size_t off = 0;
    auto allocB = [&](size_t bytes) -> void* {
        void* p = (void*)(wsb + off);
        off += (bytes + 255) & ~(size_t)255;
        return p;
    };
    float* xC   = (float*)allocB((size_t)CROW_ * 768 * 4);
    float* xM   = (float*)allocB((size_t)MROW_ * 768 * 4);
    short* lnb  = (short*)allocB((size_t)(CROW_ + PAD_) * 768 * 2);
    short* attb = (short*)allocB((size_t)(CROW_ + PAD_) * 768 * 2);
    short* qkvb = (short*)allocB((size_t)(CROW_ + PAD_) * 2304 * 2);
    short* hidb = (short*)allocB((size_t)(CROW_ + PAD_) * 3072 * 2);
    float* peo  = (float*)allocB((size_t)3136 * 768 * 4);
    float* xT    = (float*)allocB((size_t)TAILC_ * 768 * 4);
    float* xMT   = (float*)allocB((size_t)TAILM_ * 768 * 4);
    short* attbT = (short*)allocB((size_t)(TAILC_ + PAD_) * 768 * 2);
    short* lnbT  = (short*)allocB((size_t)(TAILC_ + PAD_) * 768 * 2);
    short* hidT  = (short*)allocB((size_t)(TAILC_ + PAD_) * 3072 * 2);
    int*   selm = (int*)allocB(64);
    int*   flag = (int*)allocB(64);

    const size_t nQkv = (size_t)DEPTH_ * 2304 * 768;
    const size_t nProj = (size_t)DEPTH_ * 768 * 768;
    const size_t nFc1 = (size_t)DEPTH_ * 3072 * 768;
    const size_t nFc2 = (size_t)DEPTH_ * 768 * 3072;
    const size_t nPatch = (size_t)768 * 768;
    size_t cacheBytes = (nQkv + nProj + nFc1 + nFc2 + nPatch) * 2 + 5 * 256;
    bool cache = (ws_size >= off + cacheBytes + (1u << 20));
    short *qkv_wc = nullptr, *proj_wc = nullptr, *fc1_wc = nullptr, *fc2_wc = nullptr, *patch_wc = nullptr;
    if (cache){
        qkv_wc  = (short*)allocB(nQkv * 2);
        proj_wc = (short*)allocB(nProj * 2);
        fc1_wc  = (short*)allocB(nFc1 * 2);
        fc2_wc  = (short*)allocB(nFc2 * 2);
        patch_wc= (short*)allocB(nPatch * 2);
        convert_w_k<<<2048, 256, 0, stream>>>(qkv_w,  qkv_wc,  (long)nQkv);
        convert_w_k<<<1024, 256, 0, stream>>>(proj_w, proj_wc, (long)nProj);
        convert_w_k<<<2048, 256, 0, stream>>>(fc1_w,  fc1_wc,  (long)nFc1);
        convert_w_k<<<2048, 256, 0, stream>>>(fc2_w,  fc2_wc,  (long)nFc2);
        convert_w_k<<<256,  256, 0, stream>>>(patch_w, patch_wc, (long)nPatch);
    }

    Params P;
    P.qkv_w = qkv_w; P.qkv_b = qkv_b; P.proj_w = proj_w; P.proj_b = proj_b;
    P.ln1_w = ln1_w; P.ln1_b = ln1_b; P.ln2_w = ln2_w; P.ln2_b = ln2_b;
    P.fc1_w = fc1_w; P.fc1_b = fc1_b; P.fc2_w = fc2_w; P.fc2_b = fc2_b;
    P.prompts = m_prompts; P.selm = selm;
    P.lnb = lnb; P.attb = attb; P.hidb = hidb; P.qkvb = qkvb;
    P.qkv_wc = qkv_wc; P.proj_wc = proj_wc; P.fc1_wc = fc1_wc; P.fc2_wc = fc2_wc;
    P.cache = cache;
    P.xT = xT; P.xMT = xMT; P.attbT = attbT; P.lnbT = lnbT; P.hidT = hidT;

    const long XN = (long)MROW_ * 768;

    // -------- patch embed (assemble directly into xC pass-A segment) --------
    {
        long tot = (long)B_ * 196 * 768;
        short* un = hidb;
        unfold_k<<<(int)((tot + 255) / 256), 256, 0, stream>>>(inputs, un);
        launch_gemm<0>(stream, un, patch_w, patch_wc, cache, patch_b, nullptr,
                       peo, nullptr, 3136, 768, 768);
        assemble_k<<<(int)((XN + 255) / 256), 256, 0, stream>>>(peo, cls_tok, pos, xC);
        long st = (long)SROW_ * 768;
        build_sub_k<<<(int)((st + 255) / 256), 256, 0, stream>>>(xC, s_prompt, pos,
                                                                 xC + (long)MROW_ * 768);
    }

    // -------- concatenated pass A + sub branch (last layer: tail-only MLP) --------
    for (int i = 0; i < DEPTH_ - 1; i++){
        run_layer(stream, xC, CROW_, i, 0, 0, P);
        if (i == 1)
            copy_f<<<(int)((XN + 255) / 256), 256, 0, stream>>>(xC, xM, XN);
    }
    run_layer_tail(stream, xC, CROW_, DEPTH_ - 1, 0, P);   // -> xT (96 rows)

    // -------- routing (pass-A CLS from compact tail) --------
    select_k<<<16, 256, 0, stream>>>(xT, norm_w, norm_b, main_key, sub_key,
                                     task_id, selm, flag);

    // -------- main branch layers 2..11 (deep prompts at 2,3,4; last = tail) --------
    for (int i = 2; i < DEPTH_ - 1; i++){
        int mode = (i >= 2 && i <= 4) ? 2 : 1;
        run_layer(stream, xM, MROW_, i, mode, i - 2, P);
    }
    run_layer_tail(stream, xM, MROW_, DEPTH_ - 1, 1, P);   // -> xMT (16 rows)

    // -------- heads + per-sample select --------
    head_k<<<16, 256, 0, stream>>>(xMT, xT, norm_w, norm_b, fc_w, fc_b, flag, out);
}

// Round 18
// 5209.774 us; speedup vs baseline: 1.2182x; 1.0059x over previous
//
#include <hip/hip_runtime.h>
#include <math.h>

// ---------------- constants ----------------
#define B_    16
#define NT_   197
#define NS_   202
#define HEADS_ 12
#define DEPTH_ 12
#define NCLS_ 100
#define MROW_ (B_ * NT_)      // 3152
#define SROW_ (B_ * NS_)      // 3232
#define CROW_ (MROW_ + SROW_) // 6384
#define PAD_  128             // GEMM-A row padding (global_load_lds has no row guard)
#define TAILC_ 96             // concat tail rows: 16 CLS + 16*5 sub-prompt rows
#define TAILM_ 16             // main tail rows: 16 CLS

typedef __attribute__((ext_vector_type(8))) short short8v;
typedef __attribute__((ext_vector_type(4))) float f32x4;

// f32 -> bf16 bits (RNE)
__device__ __forceinline__ short f2bf(float f){
    unsigned u = __builtin_bit_cast(unsigned, f);
    unsigned r = (u + 0x7FFFu + ((u >> 16) & 1u)) >> 16;
    return (short)r;
}
__device__ __forceinline__ unsigned pk2(float a, float b){
    return (unsigned)(unsigned short)f2bf(a) | (((unsigned)(unsigned short)f2bf(b)) << 16);
}
__device__ __forceinline__ float bf2f(unsigned short s){
    unsigned u = ((unsigned)s) << 16;
    return __builtin_bit_cast(float, u);
}
__device__ __forceinline__ float4 ld4bf(const short* p){
    uint2 u = *(const uint2*)p;
    float4 r;
    r.x = bf2f((unsigned short)(u.x & 0xffff));
    r.y = bf2f((unsigned short)(u.x >> 16));
    r.z = bf2f((unsigned short)(u.y & 0xffff));
    r.w = bf2f((unsigned short)(u.y >> 16));
    return r;
}
// async global->LDS, 16B per lane; lds base must be wave-uniform
__device__ __forceinline__ void gld16(const short* g, short* l){
    __builtin_amdgcn_global_load_lds(
        (const __attribute__((address_space(1))) unsigned*)g,
        (__attribute__((address_space(3))) unsigned*)l, 16, 0, 0);
}

// ============ double block reduce (256 thr) — routing/head only ============
__device__ __forceinline__ double block_reduce_sum_d(double s, double* red, int lane, int wid){
#pragma unroll
    for (int off = 32; off; off >>= 1) s += __shfl_xor(s, off);
    if (lane == 0) red[wid] = s;
    __syncthreads();
    double S = red[0] + red[1] + red[2] + red[3];
    __syncthreads();
    return S;
}

// ============ weight convert f32 -> bf16 ============
__global__ void convert_w_k(const float* __restrict__ in, short* __restrict__ out, long n){
    long i = ((long)blockIdx.x * 256 + threadIdx.x) * 8;
    long stride = (long)gridDim.x * 256 * 8;
    for (; i < n; i += stride){
        float4 a = *(const float4*)(in + i);
        float4 b = *(const float4*)(in + i + 4);
        uint4 o4;
        o4.x = pk2(a.x, a.y); o4.y = pk2(a.z, a.w);
        o4.z = pk2(b.x, b.y); o4.w = pk2(b.z, b.w);
        *(uint4*)(out + i) = o4;
    }
}

// ============ bf16 MFMA GEMM, BK=64 (round-15 winner, unchanged) ============
template<int EPI, int WB>
__global__ __launch_bounds__(256) void gemm_bf16(
    const short* __restrict__ A, const void* __restrict__ Wv,
    const float* __restrict__ bias, const float* __restrict__ Res,
    float* __restrict__ Cf, short* __restrict__ Cb, int M, int K, int N)
{
    __shared__ short As0[128 * 32];
    __shared__ short As1[128 * 32];
    __shared__ short Bs0[128 * 32];
    __shared__ short Bs1[128 * 32];
    const int t = threadIdx.x;
    const int lane = t & 63, wid = t >> 6;
    const int wr = wid >> 1, wc = wid & 1;
    const long row0 = (long)blockIdx.y * 128;
    const long col0 = (long)blockIdx.x * 128;

    f32x4 acc[4][4];
#pragma unroll
    for (int i = 0; i < 4; i++)
#pragma unroll
        for (int j = 0; j < 4; j++) acc[i][j] = (f32x4){0.f, 0.f, 0.f, 0.f};

    const int l15 = lane & 15, lkg = lane >> 4;
    const int lrow = lane >> 2;
    const int lcol = (lane & 3) * 8;

    for (int k0 = 0; k0 < K; k0 += 64){
#pragma unroll
        for (int i = 0; i < 2; i++){
            int rb = wid * 32 + i * 16;
            const short* gs = A + (row0 + rb + lrow) * K + k0 + lcol;
            gld16(gs,      &As0[rb * 32]);
            gld16(gs + 32, &As1[rb * 32]);
        }
        if (WB == 1){
            const short* Wb = (const short*)Wv;
#pragma unroll
            for (int i = 0; i < 2; i++){
                int rb = wid * 32 + i * 16;
                const short* gs = Wb + (col0 + rb + lrow) * K + k0 + lcol;
                gld16(gs,      &Bs0[rb * 32]);
                gld16(gs + 32, &Bs1[rb * 32]);
            }
        } else {
            const float* Wf = (const float*)Wv;
            const int bn = t >> 1, bh = t & 1;
#pragma unroll
            for (int half = 0; half < 2; half++){
                const float* Wp = Wf + (col0 + bn) * K + k0 + half * 32 + bh * 16;
                unsigned rr[8];
#pragma unroll
                for (int g = 0; g < 8; g++){
                    float2 f = *(const float2*)(Wp + g * 2);
                    rr[g] = pk2(f.x, f.y);
                }
                uint4 lo = {rr[0], rr[1], rr[2], rr[3]};
                uint4 hi = {rr[4], rr[5], rr[6], rr[7]};
                short* Bsh = half ? Bs1 : Bs0;
                *(uint4*)(&Bsh[bn * 32 + bh * 16])     = lo;
                *(uint4*)(&Bsh[bn * 32 + bh * 16 + 8]) = hi;
            }
        }
        __syncthreads();

        {
            short8v a[4], b[4];
#pragma unroll
            for (int i = 0; i < 4; i++)
                a[i] = *(const short8v*)(&As0[(wr * 64 + i * 16 + l15) * 32 + lkg * 8]);
#pragma unroll
            for (int j = 0; j < 4; j++)
                b[j] = *(const short8v*)(&Bs0[(wc * 64 + j * 16 + l15) * 32 + lkg * 8]);
#pragma unroll
            for (int i = 0; i < 4; i++)
#pragma unroll
                for (int j = 0; j < 4; j++)
                    acc[i][j] = __builtin_amdgcn_mfma_f32_16x16x32_bf16(a[i], b[j], acc[i][j], 0, 0, 0);
        }
        {
            short8v a[4], b[4];
#pragma unroll
            for (int i = 0; i < 4; i++)
                a[i] = *(const short8v*)(&As1[(wr * 64 + i * 16 + l15) * 32 + lkg * 8]);
#pragma unroll
            for (int j = 0; j < 4; j++)
                b[j] = *(const short8v*)(&Bs1[(wc * 64 + j * 16 + l15) * 32 + lkg * 8]);
#pragma unroll
            for (int i = 0; i < 4; i++)
#pragma unroll
                for (int j = 0; j < 4; j++)
                    acc[i][j] = __builtin_amdgcn_mfma_f32_16x16x32_bf16(a[i], b[j], acc[i][j], 0, 0, 0);
        }
        __syncthreads();
    }

#pragma unroll
    for (int i = 0; i < 4; i++){
#pragma unroll
        for (int q = 0; q < 4; q++){
            long gr = row0 + wr * 64 + i * 16 + lkg * 4 + q;
            if (gr >= M) continue;
#pragma unroll
            for (int j = 0; j < 4; j++){
                long gc = col0 + wc * 64 + j * 16 + l15;
                float v = acc[i][j][q] + bias[gc];
                if (EPI == 1){
                    v = 0.5f * v * (1.f + erff(v * 0.70710678118654752f));
                    Cb[gr * N + gc] = f2bf(v);
                } else if (EPI == 2){
                    Cf[gr * N + gc] = v + Res[gr * N + gc];
                } else if (EPI == 3){
                    Cb[gr * N + gc] = f2bf(v);
                } else {
                    Cf[gr * N + gc] = v;
                }
            }
        }
    }
}

// ============ LayerNorm: wave-per-row (unchanged) ============
__global__ __launch_bounds__(256) void ln_k(const float* __restrict__ x,
    const float* __restrict__ w, const float* __restrict__ b,
    short* __restrict__ y, int M)
{
    const int lane = threadIdx.x & 63, wv = threadIdx.x >> 6;
    const int row = blockIdx.x * 4 + wv;
    if (row >= M) return;
    const float* xr = x + (long)row * 768;
    float v[12];
    float s = 0.f;
#pragma unroll
    for (int j = 0; j < 12; j++){ v[j] = xr[lane + j * 64]; s += v[j]; }
#pragma unroll
    for (int off = 32; off; off >>= 1) s += __shfl_xor(s, off);
    float m = s * (1.f / 768.f);
    float q = 0.f;
#pragma unroll
    for (int j = 0; j < 12; j++){ v[j] -= m; q += v[j] * v[j]; }
#pragma unroll
    for (int off = 32; off; off >>= 1) q += __shfl_xor(q, off);
    float rs = 1.f / sqrtf(q * (1.f / 768.f) + 1e-6f);
    short* yr = y + (long)row * 768;
#pragma unroll
    for (int j = 0; j < 12; j++)
        yr[lane + j * 64] = f2bf(v[j] * rs * w[lane + j * 64] + b[lane + j * 64]);
}

// ============ std MHA via MFMA v4 (round-17 winner, unchanged) ============
__global__ __launch_bounds__(512) void attn_mfma(
    const short* __restrict__ qkv0, short* __restrict__ o0, int N0, int tb0, int te0,
    const short* __restrict__ qkv1, short* __restrict__ o1, int N1, int tb1, int te1)
{
    __shared__ short Ks[208 * 72];
    __shared__ short Vs[64 * 232];
    __shared__ short Ps[8 * 16 * 40];
    const int bh = blockIdx.x;
    const int b = bh / HEADS_, h = bh % HEADS_;
    const int seg = blockIdx.y;
    const short* qkv = seg ? qkv1 : qkv0;
    short* o = seg ? o1 : o0;
    const int Ntok = seg ? N1 : N0;
    const int tb = seg ? tb1 : tb0;
    const int te = seg ? te1 : te0;
    const int t = threadIdx.x, lane = t & 63, wid = t >> 6;
    const long rb = (long)b * Ntok;

    {
        const int r = t >> 2, c = (t & 3) * 16;
#pragma unroll
        for (int pass = 0; pass < 2; pass++){
            int m = r + pass * 128;
            if (m < 208){
                if (m < Ntok){
                    const short* kr = qkv + (rb + m) * 2304 + 768  + h * 64 + c;
                    const short* vr = qkv + (rb + m) * 2304 + 1536 + h * 64 + c;
                    *(uint4*)(&Ks[m * 72 + c])     = *(const uint4*)(kr);
                    *(uint4*)(&Ks[m * 72 + c + 8]) = *(const uint4*)(kr + 8);
#pragma unroll
                    for (int j = 0; j < 16; j++)
                        Vs[(c + j) * 232 + m] = vr[j];
                } else {
#pragma unroll
                    for (int j = 0; j < 16; j += 2)
                        *(unsigned*)(&Ks[m * 72 + c + j]) = 0u;
#pragma unroll
                    for (int j = 0; j < 16; j++)
                        Vs[(c + j) * 232 + m] = 0;
                }
            }
        }
        for (int i = t; i < 64 * 16; i += 512){
            int d = i >> 4, m = 208 + (i & 15);
            Vs[d * 232 + m] = 0;
        }
    }
    __syncthreads();

    const int l15 = lane & 15, lkg = lane >> 4;
    short* Pw = &Ps[wid * 16 * 40];

    for (int s = tb + wid; s < te; s += 8){
        const int q0 = s * 16;
        short8v a0, a1;
        {
            int qrow = q0 + l15;
            if (qrow < Ntok){
                const short* qp = qkv + (rb + qrow) * 2304 + h * 64;
                a0 = *(const short8v*)(qp + lkg * 8);
                a1 = *(const short8v*)(qp + 32 + lkg * 8);
            } else {
                uint4 z = {0u,0u,0u,0u};
                a0 = __builtin_bit_cast(short8v, z);
                a1 = __builtin_bit_cast(short8v, z);
            }
        }
        f32x4 sacc[13];
#pragma unroll
        for (int j = 0; j < 13; j++){
            short8v b0 = *(const short8v*)(&Ks[(j * 16 + l15) * 72 + lkg * 8]);
            short8v b1 = *(const short8v*)(&Ks[(j * 16 + l15) * 72 + 32 + lkg * 8]);
            f32x4 z = {0.f, 0.f, 0.f, 0.f};
            z = __builtin_amdgcn_mfma_f32_16x16x32_bf16(a0, b0, z, 0, 0, 0);
            z = __builtin_amdgcn_mfma_f32_16x16x32_bf16(a1, b1, z, 0, 0, 0);
            sacc[j][0] = z[0] * 0.125f; sacc[j][1] = z[1] * 0.125f;
            sacc[j][2] = z[2] * 0.125f; sacc[j][3] = z[3] * 0.125f;
        }
#pragma unroll
        for (int j = 0; j < 13; j++){
            if (j * 16 + l15 >= Ntok){
                sacc[j][0] = -1e30f; sacc[j][1] = -1e30f;
                sacc[j][2] = -1e30f; sacc[j][3] = -1e30f;
            }
        }
#pragma unroll
        for (int rr = 0; rr < 4; rr++){
            float mx = sacc[0][rr];
#pragma unroll
            for (int j = 1; j < 13; j++) mx = fmaxf(mx, sacc[j][rr]);
            mx = fmaxf(mx, __shfl_xor(mx, 1));
            mx = fmaxf(mx, __shfl_xor(mx, 2));
            mx = fmaxf(mx, __shfl_xor(mx, 4));
            mx = fmaxf(mx, __shfl_xor(mx, 8));
            float pv[13];
            float sum = 0.f;
#pragma unroll
            for (int j = 0; j < 13; j++){
                float e = expf(sacc[j][rr] - mx);
                pv[j] = e; sum += e;
            }
            sum += __shfl_xor(sum, 1);
            sum += __shfl_xor(sum, 2);
            sum += __shfl_xor(sum, 4);
            sum += __shfl_xor(sum, 8);
            float inv = 1.f / sum;
#pragma unroll
            for (int j = 0; j < 13; j++) sacc[j][rr] = pv[j] * inv;
        }
        f32x4 oacc[4];
#pragma unroll
        for (int dj = 0; dj < 4; dj++) oacc[dj] = (f32x4){0.f, 0.f, 0.f, 0.f};
#pragma unroll
        for (int kc = 0; kc < 7; kc++){
            const int j0 = 2 * kc, j1 = 2 * kc + 1;
#pragma unroll
            for (int rr = 0; rr < 4; rr++){
                Pw[(lkg * 4 + rr) * 40 + l15]      = f2bf(sacc[j0][rr]);
                Pw[(lkg * 4 + rr) * 40 + 16 + l15] = (j1 < 13) ? f2bf(sacc[j1][rr]) : (short)0;
            }
            short8v pa = *(const short8v*)(&Pw[l15 * 40 + lkg * 8]);
#pragma unroll
            for (int dj = 0; dj < 4; dj++){
                short8v vb = *(const short8v*)(&Vs[(dj * 16 + l15) * 232 + kc * 32 + lkg * 8]);
                oacc[dj] = __builtin_amdgcn_mfma_f32_16x16x32_bf16(pa, vb, oacc[dj], 0, 0, 0);
            }
        }
#pragma unroll
        for (int dj = 0; dj < 4; dj++){
#pragma unroll
            for (int rr = 0; rr < 4; rr++){
                int q = q0 + lkg * 4 + rr;
                if (q < Ntok)
                    o[(rb + q) * 768 + h * 64 + dj * 16 + l15] = f2bf(oacc[dj][rr]);
            }
        }
    }
}

// ============ deep attention v4: 512 threads, QK over 8 waves, PV m-split 2 groups ============
__global__ __launch_bounds__(512) void attn_deep_v4(
    const short* __restrict__ qkv, const float* __restrict__ prompts,
    const int* __restrict__ selm, short* __restrict__ o, int li)
{
    __shared__ float sc[4][208];
    __shared__ float part[12][256];   // group-1 PV partials: [qi*3 + chunk][tt]
    const int b = blockIdx.x, g = blockIdx.y, t = threadIdx.x;
    const int lane = t & 63, w = t >> 6;     // 8 waves
    const int n0 = g * 4;

    // 4 query rows in per-lane register chunks (clamped duplicates; writes guarded)
    float4 q0[4], q1[4], q2[4];
#pragma unroll
    for (int qi = 0; qi < 4; qi++){
        int n = n0 + qi;
        int nn = (n < NT_) ? n : (NT_ - 1);
        const short* qr = qkv + (long)(b * NT_ + nn) * 2304;
        q0[qi] = ld4bf(qr + lane * 4);
        q1[qi] = ld4bf(qr + 256 + lane * 4);
        q2[qi] = ld4bf(qr + 512 + lane * 4);
    }

    const float* kp = prompts + ((long)selm[b] * 6 + 2 * li) * 5 * 768;
    const float* vp = kp + 5 * 768;

    // QK: wave-per-key over 8 waves (half the chain length of v3)
    for (int m = w; m < 202; m += 8){
        float4 k0, k1, k2;
        if (m < 5){
            const float* kr = kp + (long)m * 768;
            k0 = *(const float4*)(kr + lane * 4);
            k1 = *(const float4*)(kr + 256 + lane * 4);
            k2 = *(const float4*)(kr + 512 + lane * 4);
        } else {
            const short* kr = qkv + (long)(b * NT_ + (m - 5)) * 2304 + 768;
            k0 = ld4bf(kr + lane * 4);
            k1 = ld4bf(kr + 256 + lane * 4);
            k2 = ld4bf(kr + 512 + lane * 4);
        }
        float a[4];
#pragma unroll
        for (int qi = 0; qi < 4; qi++){
            a[qi] = q0[qi].x*k0.x + q0[qi].y*k0.y + q0[qi].z*k0.z + q0[qi].w*k0.w
                  + q1[qi].x*k1.x + q1[qi].y*k1.y + q1[qi].z*k1.z + q1[qi].w*k1.w
                  + q2[qi].x*k2.x + q2[qi].y*k2.y + q2[qi].z*k2.z + q2[qi].w*k2.w;
        }
#pragma unroll
        for (int off = 32; off; off >>= 1){
#pragma unroll
            for (int qi = 0; qi < 4; qi++) a[qi] += __shfl_xor(a[qi], off);
        }
        if (lane == 0){
#pragma unroll
            for (int qi = 0; qi < 4; qi++) sc[qi][m] = a[qi] * 0.125f;
        }
    }
    __syncthreads();

    // softmax: wave w (<4) owns query w — identical math to v3
    if (w < 4){
        float v[4];
#pragma unroll
        for (int i = 0; i < 4; i++){
            int m = lane + i * 64;
            v[i] = (m < 202) ? sc[w][m] : -1e30f;
        }
        float mx = fmaxf(fmaxf(v[0], v[1]), fmaxf(v[2], v[3]));
#pragma unroll
        for (int off = 32; off; off >>= 1) mx = fmaxf(mx, __shfl_xor(mx, off));
        float e[4], sum = 0.f;
#pragma unroll
        for (int i = 0; i < 4; i++){
            int m = lane + i * 64;
            e[i] = (m < 202) ? expf(v[i] - mx) : 0.f;
            sum += e[i];
        }
#pragma unroll
        for (int off = 32; off; off >>= 1) sum += __shfl_xor(sum, off);
        float inv = 1.f / sum;
#pragma unroll
        for (int i = 0; i < 4; i++){
            int m = lane + i * 64;
            if (m < 202) sc[w][m] = e[i] * inv;
        }
    }
    __syncthreads();

    // PV: two 256-thread groups split the m-range; tt covers dims (tt, +256, +512)
    const int grp = t >> 8;
    const int tt = t & 255;
    float a0[4] = {0.f,0.f,0.f,0.f}, a1[4] = {0.f,0.f,0.f,0.f}, a2[4] = {0.f,0.f,0.f,0.f};
    if (grp == 0){
        for (int m = 0; m < 5; m++){
            const float* vr = vp + (long)m * 768;
            float v0 = vr[tt], v1 = vr[tt + 256], v2 = vr[tt + 512];
#pragma unroll
            for (int qi = 0; qi < 4; qi++){
                float pm = sc[qi][m];
                a0[qi] += pm * v0; a1[qi] += pm * v1; a2[qi] += pm * v2;
            }
        }
        for (int m = 5; m < 103; m++){
            const short* vr = qkv + (long)(b * NT_ + (m - 5)) * 2304 + 1536;
            float v0 = bf2f((unsigned short)vr[tt]);
            float v1 = bf2f((unsigned short)vr[tt + 256]);
            float v2 = bf2f((unsigned short)vr[tt + 512]);
#pragma unroll
            for (int qi = 0; qi < 4; qi++){
                float pm = sc[qi][m];
                a0[qi] += pm * v0; a1[qi] += pm * v1; a2[qi] += pm * v2;
            }
        }
    } else {
        for (int m = 103; m < 202; m++){
            const short* vr = qkv + (long)(b * NT_ + (m - 5)) * 2304 + 1536;
            float v0 = bf2f((unsigned short)vr[tt]);
            float v1 = bf2f((unsigned short)vr[tt + 256]);
            float v2 = bf2f((unsigned short)vr[tt + 512]);
#pragma unroll
            for (int qi = 0; qi < 4; qi++){
                float pm = sc[qi][m];
                a0[qi] += pm * v0; a1[qi] += pm * v1; a2[qi] += pm * v2;
            }
        }
#pragma unroll
        for (int qi = 0; qi < 4; qi++){
            part[qi * 3 + 0][tt] = a0[qi];
            part[qi * 3 + 1][tt] = a1[qi];
            part[qi * 3 + 2][tt] = a2[qi];
        }
    }
    __syncthreads();
    if (grp == 0){
#pragma unroll
        for (int qi = 0; qi < 4; qi++){
            float f0 = a0[qi] + part[qi * 3 + 0][tt];
            float f1 = a1[qi] + part[qi * 3 + 1][tt];
            float f2 = a2[qi] + part[qi * 3 + 2][tt];
            int n = n0 + qi;
            if (n < NT_){
                short* ob = o + (long)b * NT_ * 768 + n;   // scramble-folded layout
                ob[(long)tt * 197]         = f2bf(f0);
                ob[(long)(tt + 256) * 197] = f2bf(f1);
                ob[(long)(tt + 512) * 197] = f2bf(f2);
            }
        }
    }
}

// ============ tail gathers (unchanged) ============
__device__ __forceinline__ long tail_src_row(int r, int mode){
    if (mode == 1) return (long)r * NT_;
    if (r < 16)    return (long)r * NT_;
    int j = r - 16;
    return (long)MROW_ + (long)(j / 5) * NS_ + 1 + (j % 5);
}
__global__ void gather_tail_f(const float* __restrict__ src, float* __restrict__ dst,
                              int nrows, int mode){
    long i = (long)blockIdx.x * 256 + threadIdx.x;
    long total = (long)nrows * 768;
    if (i >= total) return;
    int r = (int)(i / 768), d = (int)(i % 768);
    dst[i] = src[tail_src_row(r, mode) * 768 + d];
}
__global__ void gather_tail_b(const short* __restrict__ src, short* __restrict__ dst,
                              int nrows, int mode){
    long i = (long)blockIdx.x * 256 + threadIdx.x;
    long total = (long)nrows * 768;
    if (i >= total) return;
    int r = (int)(i / 768), d = (int)(i % 768);
    dst[i] = src[tail_src_row(r, mode) * 768 + d];
}

// ============ patch unfold (f32 -> bf16) ============
__global__ void unfold_k(const float* __restrict__ in, short* __restrict__ out){
    long i = (long)blockIdx.x * 256 + threadIdx.x;
    long total = (long)B_ * 196 * 768;
    if (i >= total) return;
    int f = (int)(i % 768); long rw = i / 768;
    int t = (int)(rw % 196); int b = (int)(rw / 196);
    int gy = t / 14, gx = t % 14;
    int c = f >> 8, rem = f & 255, py = rem >> 4, px = rem & 15;
    out[i] = f2bf(in[(((long)(b * 3 + c) * 224) + gy * 16 + py) * 224 + gx * 16 + px]);
}

// ============ assemble x0 = [cls+pos ; patches+pos] (f32) ============
__global__ void assemble_k(const float* __restrict__ pe, const float* __restrict__ cls,
    const float* __restrict__ pos, float* __restrict__ x0){
    long i = (long)blockIdx.x * 256 + threadIdx.x;
    long total = (long)B_ * NT_ * 768;
    if (i >= total) return;
    int d = (int)(i % 768); long rw = i / 768;
    int n = (int)(rw % NT_); int b = (int)(rw / NT_);
    float v;
    if (n == 0) v = cls[d] + pos[d];
    else        v = pe[((long)b * 196 + (n - 1)) * 768 + d] + pos[(long)n * 768 + d];
    x0[i] = v;
}

__global__ void copy_f(const float* __restrict__ a, float* __restrict__ b, long total){
    long i = (long)blockIdx.x * 256 + threadIdx.x;
    if (i < total) b[i] = a[i];
}

// ============ build sub-branch rows (reads pass-A segment of xC) ============
__global__ void build_sub_k(const float* __restrict__ x0, const float* __restrict__ subp,
    const float* __restrict__ pos, float* __restrict__ xSub){
    long i = (long)blockIdx.x * 256 + threadIdx.x;
    long total = (long)B_ * NS_ * 768;
    if (i >= total) return;
    int d = (int)(i % 768); long rw = i / 768;
    int n = (int)(rw % NS_); int b = (int)(rw / NS_);
    float v;
    if (n == 0)      v = x0[((long)b * NT_) * 768 + d];
    else if (n <= 5) v = subp[(n - 1) * 768 + d] + pos[d];
    else             v = x0[((long)b * NT_ + (n - 5)) * 768 + d];
    xSub[i] = v;
}

// ============ routing (f64 internals) — reads compact tail buffer, row b ============
__global__ __launch_bounds__(256) void select_k(
    const float* __restrict__ xT, const float* __restrict__ norm_w,
    const float* __restrict__ norm_b, const float* __restrict__ main_key,
    const float* __restrict__ sub_key, const int* __restrict__ task_id_p,
    int* __restrict__ selm, int* __restrict__ flag)
{
    __shared__ double red[4];
    int b = blockIdx.x, t = threadIdx.x, lane = t & 63, wid = t >> 6;
    const float* xr = xT + (long)b * 768;
    double v0 = xr[t], v1 = xr[t + 256], v2 = xr[t + 512];
    double S = block_reduce_sum_d(v0 + v1 + v2, red, lane, wid);
    double m = S * (1.0 / 768.0);
    double d0 = v0 - m, d1 = v1 - m, d2 = v2 - m;
    double Q = block_reduce_sum_d(d0*d0 + d1*d1 + d2*d2, red, lane, wid);
    double rs = 1.0 / sqrt(Q * (1.0 / 768.0) + 1e-6);
    double q0 = d0 * rs * (double)norm_w[t]       + (double)norm_b[t];
    double q1 = d1 * rs * (double)norm_w[t + 256] + (double)norm_b[t + 256];
    double q2 = d2 * rs * (double)norm_w[t + 512] + (double)norm_b[t + 512];
    double qn = block_reduce_sum_d(q0*q0 + q1*q1 + q2*q2, red, lane, wid);
    double qinv = 1.0 / sqrt(fmax(qn, 1e-12));

    int tk = *task_id_p;
    int ncand = tk + 2;
    double best = -1e300; int bsel = 0;
    for (int c = 0; c < ncand; c++){
        const float* cr = (c <= tk) ? (main_key + (long)c * 768) : sub_key;
        double c0 = cr[t], c1 = cr[t + 256], c2 = cr[t + 512];
        double dotq = block_reduce_sum_d(q0*c0 + q1*c1 + q2*c2, red, lane, wid);
        double nc   = block_reduce_sum_d(c0*c0 + c1*c1 + c2*c2, red, lane, wid);
        double sim = dotq * qinv * (1.0 / sqrt(fmax(nc, 1e-12)));
        if (sim > best){ best = sim; bsel = c; }
    }
    if (t == 0){
        int isMain = (bsel <= tk) ? 1 : 0;
        selm[b] = isMain ? bsel : 0;
        flag[b] = isMain;
    }
}

// ============ final head (f64 internals) — reads compact tail buffers ============
__global__ __launch_bounds__(256) void head_k(
    const float* __restrict__ xMT, const float* __restrict__ xT,
    const float* __restrict__ norm_w, const float* __restrict__ norm_b,
    const float* __restrict__ fc_w, const float* __restrict__ fc_b,
    const int* __restrict__ flag, float* __restrict__ out)
{
    __shared__ double vec[768];
    __shared__ double red[4];
    int b = blockIdx.x, t = threadIdx.x, lane = t & 63, wid = t >> 6;
    int isMain = flag[b];
    double a0 = 0.0, a1 = 0.0, a2 = 0.0;
    int nrows = isMain ? 1 : 5;
    for (int rI = 0; rI < nrows; rI++){
        const float* xr = isMain ? (xMT + (long)b * 768)
                                 : (xT + (long)(16 + b * 5 + rI) * 768);
        double v0 = xr[t], v1 = xr[t + 256], v2 = xr[t + 512];
        double S = block_reduce_sum_d(v0 + v1 + v2, red, lane, wid);
        double m = S * (1.0 / 768.0);
        double d0 = v0 - m, d1 = v1 - m, d2 = v2 - m;
        double Q = block_reduce_sum_d(d0*d0 + d1*d1 + d2*d2, red, lane, wid);
        double rs = 1.0 / sqrt(Q * (1.0 / 768.0) + 1e-6);
        a0 += d0 * rs * (double)norm_w[t]       + (double)norm_b[t];
        a1 += d1 * rs * (double)norm_w[t + 256] + (double)norm_b[t + 256];
        a2 += d2 * rs * (double)norm_w[t + 512] + (double)norm_b[t + 512];
    }
    double scl = isMain ? 1.0 : 0.2;
    vec[t] = a0 * scl; vec[t + 256] = a1 * scl; vec[t + 512] = a2 * scl;
    __syncthreads();
    if (t < NCLS_){
        const float* wr = fc_w + (long)t * 768;
        double acc = (double)fc_b[t];
#pragma unroll 8
        for (int j = 0; j < 768; j++) acc += vec[j] * (double)wr[j];
        out[b * NCLS_ + t] = (float)acc;
    }
}

// ================= host-side =================
struct Params {
    const float *qkv_w, *qkv_b, *proj_w, *proj_b;
    const float *ln1_w, *ln1_b, *ln2_w, *ln2_b;
    const float *fc1_w, *fc1_b, *fc2_w, *fc2_b;
    const float *prompts; const int* selm;
    short *lnb, *attb, *hidb;
    short *qkvb;
    const short *qkv_wc, *proj_wc, *fc1_wc, *fc2_wc;
    bool cache;
    float *xT, *xMT;
    short *attbT, *lnbT, *hidT;
};

template<int EPI>
static void launch_gemm(hipStream_t st, const short* A, const float* Wf, const short* Wc,
                        bool cache, const float* bias, const float* Res,
                        float* Cf, short* Cb, int M, int K, int N)
{
    dim3 g(N / 128, (M + 127) / 128);
    if (cache)
        gemm_bf16<EPI, 1><<<g, 256, 0, st>>>(A, (const void*)Wc, bias, Res, Cf, Cb, M, K, N);
    else
        gemm_bf16<EPI, 0><<<g, 256, 0, st>>>(A, (const void*)Wf, bias, Res, Cf, Cb, M, K, N);
}

// mode 0: concat (std attn both segments)  mode 1: main std  mode 2: main deep
static void run_layer(hipStream_t st, float* x, int M, int layer, int mode, int li,
                      const Params& P)
{
    int lnGrid = (M + 3) / 4;
    ln_k<<<lnGrid, 256, 0, st>>>(x, P.ln1_w + layer * 768, P.ln1_b + layer * 768, P.lnb, M);
    launch_gemm<3>(st, P.lnb, P.qkv_w + (long)layer * 2304 * 768,
        P.qkv_wc + (P.cache ? (long)layer * 2304 * 768 : 0), P.cache,
        P.qkv_b + layer * 2304, nullptr, nullptr, P.qkvb, M, 768, 2304);
    if (mode == 0){
        attn_mfma<<<dim3(B_ * HEADS_, 2), 512, 0, st>>>(
            P.qkvb, P.attb, NT_, 0, 13,
            P.qkvb + (long)MROW_ * 2304, P.attb + (long)MROW_ * 768, NS_, 0, 13);
    } else if (mode == 1){
        attn_mfma<<<dim3(B_ * HEADS_, 2), 512, 0, st>>>(
            P.qkvb, P.attb, NT_, 0, 7,
            P.qkvb, P.attb, NT_, 7, 13);
    } else {
        attn_deep_v4<<<dim3(B_, 50), 512, 0, st>>>(P.qkvb, P.prompts, P.selm, P.attb, li);
    }
    launch_gemm<2>(st, P.attb, P.proj_w + (long)layer * 768 * 768,
        P.proj_wc + (P.cache ? (long)layer * 768 * 768 : 0), P.cache,
        P.proj_b + layer * 768, x, x, nullptr, M, 768, 768);
    ln_k<<<lnGrid, 256, 0, st>>>(x, P.ln2_w + layer * 768, P.ln2_b + layer * 768, P.lnb, M);
    launch_gemm<1>(st, P.lnb, P.fc1_w + (long)layer * 3072 * 768,
        P.fc1_wc + (P.cache ? (long)layer * 3072 * 768 : 0), P.cache,
        P.fc1_b + layer * 3072, nullptr, nullptr, P.hidb, M, 768, 3072);
    launch_gemm<2>(st, P.hidb, P.fc2_w + (long)layer * 768 * 3072,
        P.fc2_wc + (P.cache ? (long)layer * 768 * 3072 : 0), P.cache,
        P.fc2_b + layer * 768, x, x, nullptr, M, 3072, 768);
}

// last layer: ln1+qkv full, attention q-tile 0 only, then compact tail MLP.
static void run_layer_tail(hipStream_t st, float* x, int M, int layer, int gmode,
                           const Params& P)
{
    int lnGrid = (M + 3) / 4;
    ln_k<<<lnGrid, 256, 0, st>>>(x, P.ln1_w + layer * 768, P.ln1_b + layer * 768, P.lnb, M);
    launch_gemm<3>(st, P.lnb, P.qkv_w + (long)layer * 2304 * 768,
        P.qkv_wc + (P.cache ? (long)layer * 2304 * 768 : 0), P.cache,
        P.qkv_b + layer * 2304, nullptr, nullptr, P.qkvb, M, 768, 2304);
    if (gmode == 0){
        attn_mfma<<<dim3(B_ * HEADS_, 2), 512, 0, st>>>(
            P.qkvb, P.attb, NT_, 0, 1,
            P.qkvb + (long)MROW_ * 2304, P.attb + (long)MROW_ * 768, NS_, 0, 1);
    } else {
        attn_mfma<<<dim3(B_ * HEADS_, 1), 512, 0, st>>>(
            P.qkvb, P.attb, NT_, 0, 1,
            P.qkvb, P.attb, NT_, 0, 1);
    }
    const int Mt = (gmode == 0) ? TAILC_ : TAILM_;
    float* xt = (gmode == 0) ? P.xT : P.xMT;
    long tot = (long)Mt * 768;
    gather_tail_f<<<(int)((tot + 255) / 256), 256, 0, st>>>(x, xt, Mt, gmode);
    gather_tail_b<<<(int)((tot + 255) / 256), 256, 0, st>>>(P.attb, P.attbT, Mt, gmode);
    launch_gemm<2>(st, P.attbT, P.proj_w + (long)layer * 768 * 768,
        P.proj_wc + (P.cache ? (long)layer * 768 * 768 : 0), P.cache,
        P.proj_b + layer * 768, xt, xt, nullptr, Mt, 768, 768);
    ln_k<<<(Mt + 3) / 4, 256, 0, st>>>(xt, P.ln2_w + layer * 768, P.ln2_b + layer * 768,
                                       P.lnbT, Mt);
    launch_gemm<1>(st, P.lnbT, P.fc1_w + (long)layer * 3072 * 768,
        P.fc1_wc + (P.cache ? (long)layer * 3072 * 768 : 0), P.cache,
        P.fc1_b + layer * 3072, nullptr, nullptr, P.hidT, Mt, 768, 3072);
    launch_gemm<2>(st, P.hidT, P.fc2_w + (long)layer * 768 * 3072,
        P.fc2_wc + (P.cache ? (long)layer * 768 * 3072 : 0), P.cache,
        P.fc2_b + layer * 768, xt, xt, nullptr, Mt, 3072, 768);
}

extern "C" void kernel_launch(void* const* d_in, const int* in_sizes, int n_in,
                              void* d_out, int out_size, void* d_ws, size_t ws_size,
                              hipStream_t stream)
{
    (void)in_sizes; (void)n_in; (void)out_size;
    const float* inputs   = (const float*)d_in[0];
    const int*   task_id  = (const int*)  d_in[1];
    const float* patch_w  = (const float*)d_in[2];
    const float* patch_b  = (const float*)d_in[3];
    const float* cls_tok  = (const float*)d_in[4];
    const float* pos      = (const float*)d_in[5];
    const float* qkv_w    = (const float*)d_in[6];
    const float* qkv_b    = (const float*)d_in[7];
    const float* proj_w   = (const float*)d_in[8];
    const float* proj_b   = (const float*)d_in[9];
    const float* ln1_w    = (const float*)d_in[10];
    const float* ln1_b    = (const float*)d_in[11];
    const float* ln2_w    = (const float*)d_in[12];
    const float* ln2_b    = (const float*)d_in[13];
    const float* fc1_w    = (const float*)d_in[14];
    const float* fc1_b    = (const float*)d_in[15];
    const float* fc2_w    = (const float*)d_in[16];
    const float* fc2_b    = (const float*)d_in[17];
    const float* norm_w   = (const float*)d_in[18];
    const float* norm_b   = (const float*)d_in[19];
    const float* fc_w     = (const float*)d_in[20];
    const float* fc_b     = (const float*)d_in[21];
    const float* main_key = (const float*)d_in[22];
    const float* sub_key  = (const float*)d_in[23];
    const float* m_prompts= (const float*)d_in[24];
    const float* s_prompt = (const float*)d_in[25];
    float* out = (float*)d_out;

    char* wsb = (char*)d_ws;
    size_t off = 0;
    auto allocB = [&](size_t bytes) -> void* {
        void* p = (void*)(wsb + off);
        off += (bytes + 255) & ~(size_t)255;
        return p;
    };
    float* xC   = (float*)allocB((size_t)CROW_ * 768 * 4);
    float* xM   = (float*)allocB((size_t)MROW_ * 768 * 4);
    short* lnb  = (short*)allocB((size_t)(CROW_ + PAD_) * 768 * 2);
    short* attb = (short*)allocB((size_t)(CROW_ + PAD_) * 768 * 2);
    short* qkvb = (short*)allocB((size_t)(CROW_ + PAD_) * 2304 * 2);
    short* hidb = (short*)allocB((size_t)(CROW_ + PAD_) * 3072 * 2);
    float* peo  = (float*)allocB((size_t)3136 * 768 * 4);
    float* xT    = (float*)allocB((size_t)TAILC_ * 768 * 4);
    float* xMT   = (float*)allocB((size_t)TAILM_ * 768 * 4);
    short* attbT = (short*)allocB((size_t)(TAILC_ + PAD_) * 768 * 2);
    short* lnbT  = (short*)allocB((size_t)(TAILC_ + PAD_) * 768 * 2);
    short* hidT  = (short*)allocB((size_t)(TAILC_ + PAD_) * 3072 * 2);
    int*   selm = (int*)allocB(64);
    int*   flag = (int*)allocB(64);

    const size_t nQkv = (size_t)DEPTH_ * 2304 * 768;
    const size_t nProj = (size_t)DEPTH_ * 768 * 768;
    const size_t nFc1 = (size_t)DEPTH_ * 3072 * 768;
    const size_t nFc2 = (size_t)DEPTH_ * 768 * 3072;
    const size_t nPatch = (size_t)768 * 768;
    size_t cacheBytes = (nQkv + nProj + nFc1 + nFc2 + nPatch) * 2 + 5 * 256;
    bool cache = (ws_size >= off + cacheBytes + (1u << 20));
    short *qkv_wc = nullptr, *proj_wc = nullptr, *fc1_wc = nullptr, *fc2_wc = nullptr, *patch_wc = nullptr;
    if (cache){
        qkv_wc  = (short*)allocB(nQkv * 2);
        proj_wc = (short*)allocB(nProj * 2);
        fc1_wc  = (short*)allocB(nFc1 * 2);
        fc2_wc  = (short*)allocB(nFc2 * 2);
        patch_wc= (short*)allocB(nPatch * 2);
        convert_w_k<<<2048, 256, 0, stream>>>(qkv_w,  qkv_wc,  (long)nQkv);
        convert_w_k<<<1024, 256, 0, stream>>>(proj_w, proj_wc, (long)nProj);
        convert_w_k<<<2048, 256, 0, stream>>>(fc1_w,  fc1_wc,  (long)nFc1);
        convert_w_k<<<2048, 256, 0, stream>>>(fc2_w,  fc2_wc,  (long)nFc2);
        convert_w_k<<<256,  256, 0, stream>>>(patch_w, patch_wc, (long)nPatch);
    }

    Params P;
    P.qkv_w = qkv_w; P.qkv_b = qkv_b; P.proj_w = proj_w; P.proj_b = proj_b;
    P.ln1_w = ln1_w; P.ln1_b = ln1_b; P.ln2_w = ln2_w; P.ln2_b = ln2_b;
    P.fc1_w = fc1_w; P.fc1_b = fc1_b; P.fc2_w = fc2_w; P.fc2_b = fc2_b;
    P.prompts = m_prompts; P.selm = selm;
    P.lnb = lnb; P.attb = attb; P.hidb = hidb; P.qkvb = qkvb;
    P.qkv_wc = qkv_wc; P.proj_wc = proj_wc; P.fc1_wc = fc1_wc; P.fc2_wc = fc2_wc;
    P.cache = cache;
    P.xT = xT; P.xMT = xMT; P.attbT = attbT; P.lnbT = lnbT; P.hidT = hidT;

    const long XN = (long)MROW_ * 768;

    // -------- patch embed (assemble directly into xC pass-A segment) --------
    {
        long tot = (long)B_ * 196 * 768;
        short* un = hidb;
        unfold_k<<<(int)((tot + 255) / 256), 256, 0, stream>>>(inputs, un);
        launch_gemm<0>(stream, un, patch_w, patch_wc, cache, patch_b, nullptr,
                       peo, nullptr, 3136, 768, 768);
        assemble_k<<<(int)((XN + 255) / 256), 256, 0, stream>>>(peo, cls_tok, pos, xC);
        long st = (long)SROW_ * 768;
        build_sub_k<<<(int)((st + 255) / 256), 256, 0, stream>>>(xC, s_prompt, pos,
                                                                 xC + (long)MROW_ * 768);
    }

    // -------- concatenated pass A + sub branch (last layer: tail-only MLP) --------
    for (int i = 0; i < DEPTH_ - 1; i++){
        run_layer(stream, xC, CROW_, i, 0, 0, P);
        if (i == 1)
            copy_f<<<(int)((XN + 255) / 256), 256, 0, stream>>>(xC, xM, XN);
    }
    run_layer_tail(stream, xC, CROW_, DEPTH_ - 1, 0, P);   // -> xT (96 rows)

    // -------- routing (pass-A CLS from compact tail) --------
    select_k<<<16, 256, 0, stream>>>(xT, norm_w, norm_b, main_key, sub_key,
                                     task_id, selm, flag);

    // -------- main branch layers 2..11 (deep prompts at 2,3,4; last = tail) --------
    for (int i = 2; i < DEPTH_ - 1; i++){
        int mode = (i >= 2 && i <= 4) ? 2 : 1;
        run_layer(stream, xM, MROW_, i, mode, i - 2, P);
    }
    run_layer_tail(stream, xM, MROW_, DEPTH_ - 1, 1, P);   // -> xMT (16 rows)

    // -------- heads + per-sample select --------
    head_k<<<16, 256, 0, stream>>>(xMT, xT, norm_w, norm_b, fc_w, fc_b, flag, out);
}